// Round 6
// baseline (2580.178 us; speedup 1.0000x reference)
//
#include <hip/hip_runtime.h>
#include <cstdint>
#include <cstddef>

#define NNODES 50000
#define NEDGES 800000
#define FIN    100
#define FOUT   200
#define FCAT   300
#define NSTEPS 8
#define NSCANB 196

typedef unsigned short ushort_t;
typedef __bf16 bf16x8 __attribute__((ext_vector_type(8)));
typedef float  floatx4 __attribute__((ext_vector_type(4)));

__device__ __forceinline__ float bf2f(ushort_t u) {
  union { unsigned u; float f; } c; c.u = ((unsigned)u) << 16; return c.f;
}
__device__ __forceinline__ ushort_t f2bf(float f) {
  union { float f; unsigned u; } c; c.f = f;
  unsigned r = c.u + 0x7FFFu + ((c.u >> 16) & 1u);
  return (ushort_t)(r >> 16);
}
__device__ __forceinline__ float inval(const void* p, size_t i, int f32) {
  return f32 ? ((const float*)p)[i] : bf2f(((const ushort_t*)p)[i]);
}

// ---------------------------------------------------------------- dtype probe
__global__ void probe_kernel(const void* xraw, int* flag) {
  const ushort_t* u = (const ushort_t*)xraw;
  int t = threadIdx.x;
  int bad = 0;
  for (int i = t; i < 2048; i += 64) {
    int e = (u[2 * i] >> 7) & 0xFF;
    if (e >= 0x88) bad++;
  }
  for (int off = 32; off; off >>= 1) bad += __shfl_down(bad, off);
  if (t == 0) *flag = (bad > 128) ? 1 : 0;
}

// ---------------------------------------------------------------- utility
__global__ void zero_kernel(int* p, int n) {
  int i = blockIdx.x * 256 + threadIdx.x;
  if (i < n) p[i] = 0;
}

__global__ void sentinel_kernel(ushort_t* out) {
  if (threadIdx.x == 0 && blockIdx.x == 0) {
    out[0] = f2bf(0.123f);
    out[1] = f2bf(0.877f);
  }
}

__global__ void hinit_kernel(const void* __restrict__ x, const int* __restrict__ dflag,
                             ushort_t* __restrict__ h) {
  const int f32 = *dflag;
  int i = blockIdx.x * 256 + threadIdx.x;
  if (i >= NNODES * FOUT) return;
  int n = i / FOUT, c = i % FOUT;
  h[i] = (c < FIN) ? f2bf(inval(x, (size_t)n * FIN + c, f32)) : (ushort_t)0;
}

__global__ void ccat_kernel(const ushort_t* __restrict__ h, const void* __restrict__ x,
                            const int* __restrict__ dflag, ushort_t* __restrict__ cc) {
  const int f32 = *dflag;
  int i = blockIdx.x * 256 + threadIdx.x;
  if (i >= NNODES * FCAT) return;
  int n = i / FCAT, c = i % FCAT;
  cc[i] = (c < FOUT) ? h[n * FOUT + c] : f2bf(inval(x, (size_t)n * FIN + (c - FOUT), f32));
}

// ---------------------------------------------------------------- CSR build
__global__ void hist_kernel(const int* __restrict__ dst, int* __restrict__ cnt) {
  int e = blockIdx.x * 256 + threadIdx.x;
  if (e < NEDGES) atomicAdd(&cnt[dst[e]], 1);
}

// parallel scan: per-block sums -> single-block scan -> per-block rowptr
__global__ void bsum_kernel(const int* __restrict__ cnt, int* __restrict__ bsum) {
  __shared__ int red[4];
  int i = blockIdx.x * 256 + threadIdx.x;
  int v = (i < NNODES) ? cnt[i] : 0;
  for (int off = 32; off; off >>= 1) v += __shfl_down(v, off);
  int w = threadIdx.x >> 6;
  if ((threadIdx.x & 63) == 0) red[w] = v;
  __syncthreads();
  if (threadIdx.x == 0) bsum[blockIdx.x] = red[0] + red[1] + red[2] + red[3];
}

__global__ void bscan_kernel(const int* __restrict__ bsum, int* __restrict__ boff) {
  __shared__ int s[256];
  int t = threadIdx.x;
  int v = (t < NSCANB) ? bsum[t] : 0;
  s[t] = v;
  __syncthreads();
  for (int off = 1; off < 256; off <<= 1) {
    int u = (t >= off) ? s[t - off] : 0;
    __syncthreads();
    s[t] += u;
    __syncthreads();
  }
  if (t < NSCANB) boff[t] = s[t] - v;   // exclusive
}

__global__ void rowptr_kernel(const int* __restrict__ cnt, const int* __restrict__ boff,
                              int* __restrict__ row_ptr, int* __restrict__ cursor) {
  __shared__ int s[256];
  int t = threadIdx.x;
  int i = blockIdx.x * 256 + t;
  int v = (i < NNODES) ? cnt[i] : 0;
  s[t] = v;
  __syncthreads();
  for (int off = 1; off < 256; off <<= 1) {
    int u = (t >= off) ? s[t - off] : 0;
    __syncthreads();
    s[t] += u;
    __syncthreads();
  }
  if (i < NNODES) {
    int e = boff[blockIdx.x] + s[t] - v;
    row_ptr[i] = e; cursor[i] = e;
    if (i == NNODES - 1) row_ptr[NNODES] = boff[blockIdx.x] + s[t];
  }
}

__global__ void fill_kernel(const int* __restrict__ srcv, const int* __restrict__ dstv,
                            int* __restrict__ cursor, int* __restrict__ csr_src) {
  int e = blockIdx.x * 256 + threadIdx.x;
  if (e >= NEDGES) return;
  int p = atomicAdd(&cursor[dstv[e]], 1);
  csr_src[p] = srcv[e];
}

// agg[n] = sum over in-edges of h[src]; writes A = [agg | h] row (400 wide, bf16)
__global__ __launch_bounds__(256) void gather_kernel(
    const int* __restrict__ row_ptr, const int* __restrict__ csr_src,
    const ushort_t* __restrict__ h, ushort_t* __restrict__ Ag) {
  int g = threadIdx.x >> 6;
  int lane = threadIdx.x & 63;
  int n = blockIdx.x * 4 + g;
  if (n >= NNODES) return;
  if (lane >= 50) return;
  int s0 = row_ptr[n], s1 = row_ptr[n + 1];
  float a0 = 0.f, a1 = 0.f, a2 = 0.f, a3 = 0.f;
  int i = s0;
  for (; i + 1 < s1; i += 2) {
    int sa = csr_src[i], sb = csr_src[i + 1];
    ushort4 va = *(const ushort4*)&h[(size_t)sa * FOUT + lane * 4];
    ushort4 vb = *(const ushort4*)&h[(size_t)sb * FOUT + lane * 4];
    a0 += bf2f(va.x) + bf2f(vb.x);
    a1 += bf2f(va.y) + bf2f(vb.y);
    a2 += bf2f(va.z) + bf2f(vb.z);
    a3 += bf2f(va.w) + bf2f(vb.w);
  }
  if (i < s1) {
    int sa = csr_src[i];
    ushort4 va = *(const ushort4*)&h[(size_t)sa * FOUT + lane * 4];
    a0 += bf2f(va.x); a1 += bf2f(va.y); a2 += bf2f(va.z); a3 += bf2f(va.w);
  }
  ushort4 o;
  o.x = f2bf(a0); o.y = f2bf(a1); o.z = f2bf(a2); o.w = f2bf(a3);
  *(ushort4*)&Ag[(size_t)n * 400 + lane * 4] = o;
  *(ushort4*)&Ag[(size_t)n * 400 + FOUT + lane * 4] =
      *(const ushort4*)&h[(size_t)n * FOUT + lane * 4];
}

// ---------------------------------------------------------------- padded bf16 copies
__global__ void pada_kernel(const void* __restrict__ src, const int* __restrict__ dflag,
                            ushort_t* __restrict__ dst, int K, int Kp, int rowsValid,
                            int total) {
  const int f32 = *dflag;
  int i = blockIdx.x * 256 + threadIdx.x;
  if (i >= total) return;
  int r = i / Kp, k = i % Kp;
  float v = (r < rowsValid && k < K) ? inval(src, (size_t)r * K + k, f32) : 0.f;
  dst[i] = f2bf(v);
}

// Bt_gru: [8][896 rows n][416 k] bf16 (B^T, zero-padded rows>=800, k>=400)
__global__ void btgru_kernel(const float* __restrict__ Wp, const void* __restrict__ whh,
                             const int* __restrict__ dflag, ushort_t* __restrict__ Bt) {
  const int f32 = *dflag;
  int i = blockIdx.x * 256 + threadIdx.x;
  if (i >= NSTEPS * 896 * 416) return;
  int l = i / (896 * 416);
  int rem = i % (896 * 416);
  int nn = rem / 416;
  int k = rem % 416;
  int g = nn / 200, c = nn % 200;
  float v = 0.f;
  if (k < 200) {
    const float* wrow = Wp + ((size_t)l * 200 + k) * 600;
    if (g == 0) v = wrow[c];
    else if (g == 1) v = wrow[200 + c];
    else if (g == 2) v = wrow[400 + c];
  } else if (k < 400) {
    int kh = k - 200;
    if (g == 0) v = inval(whh, (size_t)c * 200 + kh, f32);
    else if (g == 1) v = inval(whh, (size_t)(200 + c) * 200 + kh, f32);
    else if (g == 3) v = inval(whh, (size_t)(400 + c) * 200 + kh, f32);
  }
  Bt[((size_t)l * 896 + nn) * 416 + k] = f2bf(v);
}

__global__ void btconv_kernel(const void* __restrict__ w, const int* __restrict__ dflag,
                              ushort_t* __restrict__ Bt, int C, int KT, int Kp,
                              int O, int total) {
  const int f32 = *dflag;
  int i = blockIdx.x * 256 + threadIdx.x;
  if (i >= total) return;
  int o = i / Kp, k = i % Kp;
  float v = 0.f;
  int K = C * KT;
  if (k < K && o < O) {
    int ktap = k / C; int ci = k % C;
    v = inval(w, ((size_t)o * C + ci) * KT + ktap, f32);
  }
  Bt[i] = f2bf(v);
}

// ---------------------------------------------------------------- GEMM (MFMA, 128x128)
// n-tile = blockIdx.x (fastest, for A-tile L2 reuse), m-tile = blockIdx.y.
// LDS: row-major [128][32] with 16B-chunk XOR swizzle (chunk ^= (row>>1)&3)
// -> conflict-free fragment reads (2-way max) and balanced staging writes.
template <bool OUT_BF16>
__global__ __launch_bounds__(256) void gemm128(
    const ushort_t* __restrict__ A, int lda, const ushort_t* __restrict__ Bt,
    void* __restrict__ Cv, int ldc, int M, int N, int Kp,
    const float* __restrict__ bias) {
  __shared__ alignas(16) ushort_t As[128 * 32];
  __shared__ alignas(16) ushort_t Bs[128 * 32];
  const int tid = threadIdx.x;
  const int n0 = blockIdx.x * 128;
  const int m0 = blockIdx.y * 128;
  const int lane = tid & 63;
  const int wv = tid >> 6;
  const int wm = wv & 1;
  const int wn = wv >> 1;
  const int quad = lane >> 4;
  const int l15 = lane & 15;

  floatx4 acc[4][4];
  #pragma unroll
  for (int a = 0; a < 4; a++)
    #pragma unroll
    for (int b = 0; b < 4; b++)
      acc[a][b] = (floatx4){0.f, 0.f, 0.f, 0.f};

  for (int k0 = 0; k0 < Kp; k0 += 32) {
    #pragma unroll
    for (int j = 0; j < 2; j++) {
      int cid = tid + 256 * j;          // 16B chunk id, 0..511
      int r = cid >> 2;                 // tile row 0..127
      int c = cid & 3;                  // k-chunk 0..3
      int cs = c ^ ((r >> 1) & 3);      // swizzled position
      int ar = m0 + r; if (ar >= M) ar = M - 1;
      const ushort_t* ga = A + (size_t)ar * lda + k0 + c * 8;
      int2 x0 = *(const int2*)ga;
      int2 x1 = *(const int2*)(ga + 4);
      int4 bv = *(const int4*)(Bt + (size_t)(n0 + r) * Kp + k0 + c * 8);
      int4 av; av.x = x0.x; av.y = x0.y; av.z = x1.x; av.w = x1.y;
      *(int4*)&As[(r * 4 + cs) * 8] = av;
      *(int4*)&Bs[(r * 4 + cs) * 8] = bv;
    }
    __syncthreads();
    bf16x8 af[4], bfr[4];
    #pragma unroll
    for (int t = 0; t < 4; t++) {
      int ra = wm * 64 + t * 16 + l15;
      int rb = wn * 64 + t * 16 + l15;
      af[t]  = *(const bf16x8*)&As[(ra * 4 + (quad ^ ((ra >> 1) & 3))) * 8];
      bfr[t] = *(const bf16x8*)&Bs[(rb * 4 + (quad ^ ((rb >> 1) & 3))) * 8];
    }
    #pragma unroll
    for (int tm = 0; tm < 4; tm++)
      #pragma unroll
      for (int tn = 0; tn < 4; tn++)
        acc[tm][tn] = __builtin_amdgcn_mfma_f32_16x16x32_bf16(af[tm], bfr[tn], acc[tm][tn], 0, 0, 0);
    __syncthreads();
  }

  #pragma unroll
  for (int tm = 0; tm < 4; tm++) {
    int row = m0 + wm * 64 + tm * 16 + quad * 4;
    #pragma unroll
    for (int tn = 0; tn < 4; tn++) {
      int col = n0 + wn * 64 + tn * 16 + l15;
      if (col < N) {
        float bb = bias ? bias[col] : 0.f;
        #pragma unroll
        for (int r = 0; r < 4; r++) {
          if (row + r < M) {
            float v = acc[tm][tn][r] + bb;
            if (OUT_BF16) ((ushort_t*)Cv)[(size_t)(row + r) * ldc + col] = f2bf(v);
            else          ((float*)Cv)[(size_t)(row + r) * ldc + col] = v;
          }
        }
      }
    }
  }
}

__global__ void bias_kernel(const void* __restrict__ b, const int* __restrict__ dflag,
                            float* __restrict__ out, int n) {
  const int f32 = *dflag;
  int i = blockIdx.x * 256 + threadIdx.x;
  if (i < n) out[i] = inval(b, i, f32);
}

// ---------------------------------------------------------------- GRU elementwise (x4 vec)
__global__ __launch_bounds__(256) void gru_kernel(
    const ushort_t* __restrict__ G, const void* __restrict__ bih,
    const void* __restrict__ bhh, const int* __restrict__ dflag,
    ushort_t* __restrict__ h) {
  const int f32 = *dflag;
  int i = blockIdx.x * 256 + threadIdx.x;
  if (i >= NNODES * 50) return;
  int n = i / 50, q = (i % 50) * 4;
  const ushort_t* g = G + (size_t)n * 800;
  ushort4 gr = *(const ushort4*)&g[q];
  ushort4 gz = *(const ushort4*)&g[200 + q];
  ushort4 gi = *(const ushort4*)&g[400 + q];
  ushort4 gh = *(const ushort4*)&g[600 + q];
  ushort4 hv = *(const ushort4*)&h[(size_t)n * 200 + q];
  const ushort_t* grp = (const ushort_t*)&gr;
  const ushort_t* gzp = (const ushort_t*)&gz;
  const ushort_t* gip = (const ushort_t*)&gi;
  const ushort_t* ghp = (const ushort_t*)&gh;
  const ushort_t* hp  = (const ushort_t*)&hv;
  ushort4 ov; ushort_t* op = (ushort_t*)&ov;
  #pragma unroll
  for (int j = 0; j < 4; j++) {
    int c = q + j;
    float rr = bf2f(grp[j]) + inval(bih, c, f32)       + inval(bhh, c, f32);
    float zz = bf2f(gzp[j]) + inval(bih, 200 + c, f32) + inval(bhh, 200 + c, f32);
    float ic = bf2f(gip[j]) + inval(bih, 400 + c, f32);
    float hc = bf2f(ghp[j]) + inval(bhh, 400 + c, f32);
    float r = 1.f / (1.f + expf(-rr));
    float z = 1.f / (1.f + expf(-zz));
    float nn = tanhf(ic + r * hc);
    op[j] = f2bf((1.f - z) * nn + z * bf2f(hp[j]));
  }
  *(ushort4*)&h[(size_t)n * 200 + q] = ov;
}

// ---------------------------------------------------------------- BN stats + pool
__global__ void stats_kernel(const float* __restrict__ X, int Lrows, int C,
                             float* __restrict__ sums, float* __restrict__ sumsq) {
  int r0 = blockIdx.x * 64;
  int rend = r0 + 64; if (rend > Lrows) rend = Lrows;
  for (int c = threadIdx.x; c < C; c += 256) {
    float s = 0.f, ss = 0.f;
    for (int r = r0; r < rend; r++) {
      float v = X[(size_t)r * C + c];
      s += v; ss += v * v;
    }
    atomicAdd(&sums[c], s);
    atomicAdd(&sumsq[c], ss);
  }
}

__global__ void bnpool_kernel(const float* __restrict__ X, int Lin, int C, int kk, int ss,
                              int Lp, const float* __restrict__ sums,
                              const float* __restrict__ sumsq,
                              const void* __restrict__ g, const void* __restrict__ b,
                              const int* __restrict__ dflag, ushort_t* __restrict__ out) {
  const int f32 = *dflag;
  int i = blockIdx.x * 256 + threadIdx.x;
  if (i >= Lp * C) return;
  int p = i / C, c = i % C;
  float inv = 1.f / (float)Lin;
  float mu = sums[c] * inv;
  float var = sumsq[c] * inv - mu * mu; if (var < 0.f) var = 0.f;
  float scale = inval(g, c, f32) * rsqrtf(var + 1e-5f);
  float shift = inval(b, c, f32) - mu * scale;
  float m = -1e30f;
  int base = p * ss;
  for (int r = 0; r < kk; r++) {
    float v = X[(size_t)(base + r) * C + c] * scale + shift;
    if (v > m) m = v;
  }
  if (m < 0.f) m = 0.f;
  out[(size_t)p * C + c] = f2bf(m);
}

// ---------------------------------------------------------------- head (atomic-free)
__global__ __launch_bounds__(256) void final_kernel(
    const ushort_t* __restrict__ Y2, const ushort_t* __restrict__ Z2,
    const void* __restrict__ wy, const void* __restrict__ by,
    const void* __restrict__ wz, const void* __restrict__ bz,
    const int* __restrict__ dflag, float* __restrict__ pacc) {
  const int f32 = *dflag;
  __shared__ float bl[8];
  int g = threadIdx.x >> 6;
  int lane = threadIdx.x & 63;
  int row = blockIdx.x * 4 + g;
  float y0 = 0.f, y1 = 0.f, z0 = 0.f, z1 = 0.f;
  if (row < 12497) {
    for (int c = lane; c < 200; c += 64) {
      float v = bf2f(Y2[(size_t)row * 200 + c]);
      y0 += v * inval(wy, c, f32);
      y1 += v * inval(wy, 200 + c, f32);
    }
    for (int c = lane; c < 300; c += 64) {
      float v = bf2f(Z2[(size_t)row * 300 + c]);
      z0 += v * inval(wz, c, f32);
      z1 += v * inval(wz, 300 + c, f32);
    }
  }
  for (int off = 32; off > 0; off >>= 1) {
    y0 += __shfl_down(y0, off);
    y1 += __shfl_down(y1, off);
    z0 += __shfl_down(z0, off);
    z1 += __shfl_down(z1, off);
  }
  if (lane == 0) {
    float p0 = 0.f, p1 = 0.f;
    if (row < 12497) {
      p0 = (y0 + inval(by, 0, f32)) * (z0 + inval(bz, 0, f32));
      p1 = (y1 + inval(by, 1, f32)) * (z1 + inval(bz, 1, f32));
    }
    bl[g * 2] = p0; bl[g * 2 + 1] = p1;
  }
  __syncthreads();
  if (threadIdx.x == 0) {
    pacc[(size_t)blockIdx.x * 2]     = bl[0] + bl[2] + bl[4] + bl[6];
    pacc[(size_t)blockIdx.x * 2 + 1] = bl[1] + bl[3] + bl[5] + bl[7];
  }
}

__global__ __launch_bounds__(256) void finalize_kernel(
    const float* __restrict__ pacc, int nblk, const int* __restrict__ dflag,
    void* __restrict__ out) {
  const int f32 = *dflag;
  __shared__ float red[2][4];
  int t = threadIdx.x;
  float s0 = 0.f, s1 = 0.f;
  for (int i = t; i < nblk; i += 256) { s0 += pacc[2 * i]; s1 += pacc[2 * i + 1]; }
  for (int off = 32; off; off >>= 1) { s0 += __shfl_down(s0, off); s1 += __shfl_down(s1, off); }
  int w = t >> 6;
  if ((t & 63) == 0) { red[0][w] = s0; red[1][w] = s1; }
  __syncthreads();
  if (t == 0) {
    float a0 = (red[0][0] + red[0][1] + red[0][2] + red[0][3]) / 12497.f;
    float a1 = (red[1][0] + red[1][1] + red[1][2] + red[1][3]) / 12497.f;
    float mx = fmaxf(a0, a1);
    float e0 = expf(a0 - mx), e1 = expf(a1 - mx);
    float s = e0 + e1;
    if (f32) {
      ((float*)out)[0] = e0 / s;
      ((float*)out)[1] = e1 / s;
    } else {
      ((ushort_t*)out)[0] = f2bf(e0 / s);
      ((ushort_t*)out)[1] = f2bf(e1 / s);
    }
  }
}

// ---------------------------------------------------------------- launch
extern "C" void kernel_launch(void* const* d_in, const int* in_sizes, int n_in,
                              void* d_out, int out_size, void* d_ws, size_t ws_size,
                              hipStream_t stream) {
  const void* x        = d_in[0];
  const int*  edge     = (const int*)d_in[1];
  const void* ggnn_w   = d_in[2];
  const void* gru_wih  = d_in[3];
  const void* gru_whh  = d_in[4];
  const void* gru_bih  = d_in[5];
  const void* gru_bhh  = d_in[6];
  const void* conv1_w  = d_in[7];
  const void* conv1_b  = d_in[8];
  const void* conv2_w  = d_in[9];
  const void* conv2_b  = d_in[10];
  const void* conv1c_w = d_in[11];
  const void* conv1c_b = d_in[12];
  const void* conv2c_w = d_in[13];
  const void* conv2c_b = d_in[14];
  const void* bn_g     = d_in[15];
  const void* bn_b     = d_in[16];
  const void* bnc_g    = d_in[17];
  const void* bnc_b    = d_in[18];
  const void* mlpy_w   = d_in[19];
  const void* mlpy_b   = d_in[20];
  const void* mlpz_w   = d_in[21];
  const void* mlpz_b   = d_in[22];
  const int* srcv = edge;
  const int* dstv = edge + NEDGES;

  // ---- workspace layout (aliased; total ~177 MB) ----
  char* p = (char*)d_ws;
  auto alloc = [&](size_t bytes) -> char* {
    char* r = p; p += (bytes + 255) & ~(size_t)255; return r;
  };
  ushort_t* h    = (ushort_t*)alloc(((size_t)NNODES * FOUT + 64) * 2);
  ushort_t* Ag   = (ushort_t*)alloc(((size_t)NNODES * 400 + 64) * 2);
  ushort_t* cc   = Ag;  // cc[N,300] built AFTER GRU loop, Ag then dead
  char*     R    = alloc((size_t)98 * 1000 * 1000);
  ushort_t* G    = (ushort_t*)R;
  float*    C1   = (float*)R;
  float*    C2   = (float*)R;
  float*    C1c  = (float*)R;
  float*    C2c  = (float*)R;
  ushort_t* pooled1 = (ushort_t*)(R + 60000000);
  ushort_t* pooledc = (ushort_t*)(R + 70000000);
  ushort_t* Y2      = (ushort_t*)(R + 85000000);
  ushort_t* Z2      = (ushort_t*)(R + 90000000);
  ushort_t* BtG  = (ushort_t*)alloc((size_t)8 * 896 * 416 * 2);
  ushort_t* Bt1  = (ushort_t*)alloc((size_t)256 * 800 * 2);
  ushort_t* Bt2  = (ushort_t*)alloc((size_t)256 * 416 * 2);
  ushort_t* Bt1c = (ushort_t*)alloc((size_t)384 * 1216 * 2);
  ushort_t* Bt2c = (ushort_t*)alloc((size_t)384 * 608 * 2);
  ushort_t* gwp  = (ushort_t*)alloc((size_t)1600 * 224 * 2);
  ushort_t* wihp = (ushort_t*)alloc((size_t)640 * 224 * 2);
  float*    Wp   = (float*)alloc((size_t)1600 * 600 * 4);
  int*   csr_src = (int*)alloc((size_t)NEDGES * 4);
  int*   row_ptr = (int*)alloc((size_t)(NNODES + 1) * 4);
  int*   cursor  = (int*)alloc((size_t)NNODES * 4);
  int*   cnt     = (int*)alloc((size_t)NNODES * 4);
  int*   bsum    = (int*)alloc((size_t)(NSCANB + 4) * 4);
  int*   boff    = (int*)alloc((size_t)(NSCANB + 4) * 4);
  float* pacc    = (float*)alloc((size_t)3125 * 2 * 4);
  float* sb      = (float*)alloc((size_t)3300 * 4);
  float *s1 = sb, *ss1 = sb + 200, *s2 = sb + 400, *ss2 = sb + 600;
  float *sc1 = sb + 800, *ssc1 = sb + 1100, *sc2 = sb + 1400, *ssc2 = sb + 1700;
  int*   dflag = (int*)(sb + 2002);
  float* b1f   = sb + 2010;
  float* b2f   = sb + 2210;
  float* b1cf  = sb + 2410;
  float* b2cf  = sb + 2710;

  size_t required = (size_t)(p - (char*)d_ws);
  if (required > ws_size) {
    sentinel_kernel<<<1, 64, 0, stream>>>((ushort_t*)d_out);
    return;
  }

  probe_kernel<<<1, 64, 0, stream>>>(x, dflag);
  zero_kernel<<<(NNODES + 255) / 256, 256, 0, stream>>>(cnt, NNODES);
  zero_kernel<<<(2000 + 255) / 256, 256, 0, stream>>>((int*)sb, 2000);
  hinit_kernel<<<(NNODES * FOUT + 255) / 256, 256, 0, stream>>>(x, dflag, h);

  // wp = ggnn_w @ wih^T as one MFMA GEMM
  pada_kernel<<<(1600 * 224 + 255) / 256, 256, 0, stream>>>(ggnn_w, dflag, gwp, 200, 224, 1600, 1600 * 224);
  pada_kernel<<<(640 * 224 + 255) / 256, 256, 0, stream>>>(gru_wih, dflag, wihp, 200, 224, 600, 640 * 224);
  gemm128<false><<<dim3(5, 13), 256, 0, stream>>>(gwp, 224, wihp, Wp, 600, 1600, 600, 224, nullptr);

  btgru_kernel<<<(NSTEPS * 896 * 416 + 255) / 256, 256, 0, stream>>>(Wp, gru_whh, dflag, BtG);
  btconv_kernel<<<(256 * 800 + 255) / 256, 256, 0, stream>>>(conv1_w, dflag, Bt1, 200, 4, 800, 200, 256 * 800);
  btconv_kernel<<<(256 * 416 + 255) / 256, 256, 0, stream>>>(conv2_w, dflag, Bt2, 200, 2, 416, 200, 256 * 416);
  btconv_kernel<<<(384 * 1216 + 255) / 256, 256, 0, stream>>>(conv1c_w, dflag, Bt1c, 300, 4, 1216, 300, 384 * 1216);
  btconv_kernel<<<(384 * 608 + 255) / 256, 256, 0, stream>>>(conv2c_w, dflag, Bt2c, 300, 2, 608, 300, 384 * 608);
  bias_kernel<<<1, 256, 0, stream>>>(conv1_b, dflag, b1f, 200);
  bias_kernel<<<1, 256, 0, stream>>>(conv2_b, dflag, b2f, 200);
  bias_kernel<<<2, 256, 0, stream>>>(conv1c_b, dflag, b1cf, 300);
  bias_kernel<<<2, 256, 0, stream>>>(conv2c_b, dflag, b2cf, 300);

  hist_kernel<<<(NEDGES + 255) / 256, 256, 0, stream>>>(dstv, cnt);
  bsum_kernel<<<NSCANB, 256, 0, stream>>>(cnt, bsum);
  bscan_kernel<<<1, 256, 0, stream>>>(bsum, boff);
  rowptr_kernel<<<NSCANB, 256, 0, stream>>>(cnt, boff, row_ptr, cursor);
  fill_kernel<<<(NEDGES + 255) / 256, 256, 0, stream>>>(srcv, dstv, cursor, csr_src);

  for (int l = 0; l < NSTEPS; l++) {
    gather_kernel<<<(NNODES + 3) / 4, 256, 0, stream>>>(row_ptr, csr_src, h, Ag);
    gemm128<true><<<dim3(7, 391), 256, 0, stream>>>(Ag, 400, BtG + (size_t)l * 896 * 416,
                                                    G, 800, NNODES, 800, 416, nullptr);
    gru_kernel<<<(NNODES * 50 + 255) / 256, 256, 0, stream>>>(G, gru_bih, gru_bhh, dflag, h);
  }
  ccat_kernel<<<(NNODES * FCAT + 255) / 256, 256, 0, stream>>>(h, x, dflag, cc);

  // branch y
  gemm128<false><<<dim3(2, 391), 256, 0, stream>>>(h, 200, Bt1, C1, 200, 49997, 200, 800, b1f);
  stats_kernel<<<(49997 + 63) / 64, 256, 0, stream>>>(C1, 49997, 200, s1, ss1);
  bnpool_kernel<<<(24997 * 200 + 255) / 256, 256, 0, stream>>>(C1, 49997, 200, 4, 2, 24997,
                                                               s1, ss1, bn_g, bn_b, dflag, pooled1);
  gemm128<false><<<dim3(2, 196), 256, 0, stream>>>(pooled1, 200, Bt2, C2, 200, 24996, 200, 416, b2f);
  stats_kernel<<<(24996 + 63) / 64, 256, 0, stream>>>(C2, 24996, 200, s2, ss2);
  bnpool_kernel<<<(12497 * 200 + 255) / 256, 256, 0, stream>>>(C2, 24996, 200, 3, 2, 12497,
                                                               s2, ss2, bn_g, bn_b, dflag, Y2);
  // branch z
  gemm128<false><<<dim3(3, 391), 256, 0, stream>>>(cc, 300, Bt1c, C1c, 300, 49997, 300, 1216, b1cf);
  stats_kernel<<<(49997 + 63) / 64, 256, 0, stream>>>(C1c, 49997, 300, sc1, ssc1);
  bnpool_kernel<<<(24997 * 300 + 255) / 256, 256, 0, stream>>>(C1c, 49997, 300, 4, 2, 24997,
                                                               sc1, ssc1, bnc_g, bnc_b, dflag, pooledc);
  gemm128<false><<<dim3(3, 196), 256, 0, stream>>>(pooledc, 300, Bt2c, C2c, 300, 24996, 300, 608, b2cf);
  stats_kernel<<<(24996 + 63) / 64, 256, 0, stream>>>(C2c, 24996, 300, sc2, ssc2);
  bnpool_kernel<<<(12497 * 300 + 255) / 256, 256, 0, stream>>>(C2c, 24996, 300, 3, 2, 12497,
                                                               sc2, ssc2, bnc_g, bnc_b, dflag, Z2);

  final_kernel<<<3125, 256, 0, stream>>>(Y2, Z2, mlpy_w, mlpy_b, mlpz_w, mlpz_b, dflag, pacc);
  finalize_kernel<<<1, 256, 0, stream>>>(pacc, 3125, dflag, d_out);
}

// Round 7
// 2515.556 us; speedup vs baseline: 1.0257x; 1.0257x over previous
//
#include <hip/hip_runtime.h>
#include <cstdint>
#include <cstddef>

#define NNODES 50000
#define NEDGES 800000
#define FIN    100
#define FOUT   200
#define FCAT   300
#define NSTEPS 8
#define NSCANB 196

typedef unsigned short ushort_t;
typedef __bf16 bf16x8 __attribute__((ext_vector_type(8)));
typedef float  floatx4 __attribute__((ext_vector_type(4)));

__device__ __forceinline__ float bf2f(ushort_t u) {
  union { unsigned u; float f; } c; c.u = ((unsigned)u) << 16; return c.f;
}
__device__ __forceinline__ ushort_t f2bf(float f) {
  union { float f; unsigned u; } c; c.f = f;
  unsigned r = c.u + 0x7FFFu + ((c.u >> 16) & 1u);
  return (ushort_t)(r >> 16);
}
__device__ __forceinline__ float inval(const void* p, size_t i, int f32) {
  return f32 ? ((const float*)p)[i] : bf2f(((const ushort_t*)p)[i]);
}

// async global->LDS 16B: per-lane global addr, LDS dest = wave-uniform base + lane*16.
// Address-space casts via uintptr_t (CK-proven pattern: LDS generic ptr low 32 bits = LDS offset).
__device__ __forceinline__ void gl2lds16(const ushort_t* g, ushort_t* l) {
  typedef const __attribute__((address_space(1))) unsigned int gu32;
  typedef __attribute__((address_space(3))) unsigned int lu32;
  __builtin_amdgcn_global_load_lds((gu32*)(uintptr_t)g, (lu32*)(uintptr_t)l, 16, 0, 0);
}

// ---------------------------------------------------------------- dtype probe
__global__ void probe_kernel(const void* xraw, int* flag) {
  const ushort_t* u = (const ushort_t*)xraw;
  int t = threadIdx.x;
  int bad = 0;
  for (int i = t; i < 2048; i += 64) {
    int e = (u[2 * i] >> 7) & 0xFF;
    if (e >= 0x88) bad++;
  }
  for (int off = 32; off; off >>= 1) bad += __shfl_down(bad, off);
  if (t == 0) *flag = (bad > 128) ? 1 : 0;
}

// ---------------------------------------------------------------- utility
__global__ void zero_kernel(int* p, int n) {
  int i = blockIdx.x * 256 + threadIdx.x;
  if (i < n) p[i] = 0;
}

__global__ void sentinel_kernel(ushort_t* out) {
  if (threadIdx.x == 0 && blockIdx.x == 0) {
    out[0] = f2bf(0.123f);
    out[1] = f2bf(0.877f);
  }
}

__global__ void hinit_kernel(const void* __restrict__ x, const int* __restrict__ dflag,
                             ushort_t* __restrict__ h) {
  const int f32 = *dflag;
  int i = blockIdx.x * 256 + threadIdx.x;
  if (i >= NNODES * FOUT) return;
  int n = i / FOUT, c = i % FOUT;
  h[i] = (c < FIN) ? f2bf(inval(x, (size_t)n * FIN + c, f32)) : (ushort_t)0;
}

__global__ void ccat_kernel(const ushort_t* __restrict__ h, const void* __restrict__ x,
                            const int* __restrict__ dflag, ushort_t* __restrict__ cc) {
  const int f32 = *dflag;
  int i = blockIdx.x * 256 + threadIdx.x;
  if (i >= NNODES * FCAT) return;
  int n = i / FCAT, c = i % FCAT;
  cc[i] = (c < FOUT) ? h[n * FOUT + c] : f2bf(inval(x, (size_t)n * FIN + (c - FOUT), f32));
}

// ---------------------------------------------------------------- CSR build
__global__ void hist_kernel(const int* __restrict__ dst, int* __restrict__ cnt) {
  int e = blockIdx.x * 256 + threadIdx.x;
  if (e < NEDGES) atomicAdd(&cnt[dst[e]], 1);
}

__global__ void bsum_kernel(const int* __restrict__ cnt, int* __restrict__ bsum) {
  __shared__ int red[4];
  int i = blockIdx.x * 256 + threadIdx.x;
  int v = (i < NNODES) ? cnt[i] : 0;
  for (int off = 32; off; off >>= 1) v += __shfl_down(v, off);
  int w = threadIdx.x >> 6;
  if ((threadIdx.x & 63) == 0) red[w] = v;
  __syncthreads();
  if (threadIdx.x == 0) bsum[blockIdx.x] = red[0] + red[1] + red[2] + red[3];
}

__global__ void bscan_kernel(const int* __restrict__ bsum, int* __restrict__ boff) {
  __shared__ int s[256];
  int t = threadIdx.x;
  int v = (t < NSCANB) ? bsum[t] : 0;
  s[t] = v;
  __syncthreads();
  for (int off = 1; off < 256; off <<= 1) {
    int u = (t >= off) ? s[t - off] : 0;
    __syncthreads();
    s[t] += u;
    __syncthreads();
  }
  if (t < NSCANB) boff[t] = s[t] - v;   // exclusive
}

__global__ void rowptr_kernel(const int* __restrict__ cnt, const int* __restrict__ boff,
                              int* __restrict__ row_ptr, int* __restrict__ cursor) {
  __shared__ int s[256];
  int t = threadIdx.x;
  int i = blockIdx.x * 256 + t;
  int v = (i < NNODES) ? cnt[i] : 0;
  s[t] = v;
  __syncthreads();
  for (int off = 1; off < 256; off <<= 1) {
    int u = (t >= off) ? s[t - off] : 0;
    __syncthreads();
    s[t] += u;
    __syncthreads();
  }
  if (i < NNODES) {
    int e = boff[blockIdx.x] + s[t] - v;
    row_ptr[i] = e; cursor[i] = e;
    if (i == NNODES - 1) row_ptr[NNODES] = boff[blockIdx.x] + s[t];
  }
}

__global__ void fill_kernel(const int* __restrict__ srcv, const int* __restrict__ dstv,
                            int* __restrict__ cursor, int* __restrict__ csr_src) {
  int e = blockIdx.x * 256 + threadIdx.x;
  if (e >= NEDGES) return;
  int p = atomicAdd(&cursor[dstv[e]], 1);
  csr_src[p] = srcv[e];
}

// agg[n] = sum over in-edges of h[src]; writes A = [agg | h] row (400 wide, bf16)
__global__ __launch_bounds__(256) void gather_kernel(
    const int* __restrict__ row_ptr, const int* __restrict__ csr_src,
    const ushort_t* __restrict__ h, ushort_t* __restrict__ Ag) {
  int g = threadIdx.x >> 6;
  int lane = threadIdx.x & 63;
  int n = blockIdx.x * 4 + g;
  if (n >= NNODES) return;
  if (lane >= 50) return;
  int s0 = row_ptr[n], s1 = row_ptr[n + 1];
  float a0 = 0.f, a1 = 0.f, a2 = 0.f, a3 = 0.f;
  int i = s0;
  for (; i + 1 < s1; i += 2) {
    int sa = csr_src[i], sb = csr_src[i + 1];
    ushort4 va = *(const ushort4*)&h[(size_t)sa * FOUT + lane * 4];
    ushort4 vb = *(const ushort4*)&h[(size_t)sb * FOUT + lane * 4];
    a0 += bf2f(va.x) + bf2f(vb.x);
    a1 += bf2f(va.y) + bf2f(vb.y);
    a2 += bf2f(va.z) + bf2f(vb.z);
    a3 += bf2f(va.w) + bf2f(vb.w);
  }
  if (i < s1) {
    int sa = csr_src[i];
    ushort4 va = *(const ushort4*)&h[(size_t)sa * FOUT + lane * 4];
    a0 += bf2f(va.x); a1 += bf2f(va.y); a2 += bf2f(va.z); a3 += bf2f(va.w);
  }
  ushort4 o;
  o.x = f2bf(a0); o.y = f2bf(a1); o.z = f2bf(a2); o.w = f2bf(a3);
  *(ushort4*)&Ag[(size_t)n * 400 + lane * 4] = o;
  *(ushort4*)&Ag[(size_t)n * 400 + FOUT + lane * 4] =
      *(const ushort4*)&h[(size_t)n * FOUT + lane * 4];
}

// ---------------------------------------------------------------- padded bf16 copies
__global__ void pada_kernel(const void* __restrict__ src, const int* __restrict__ dflag,
                            ushort_t* __restrict__ dst, int K, int Kp, int rowsValid,
                            int total) {
  const int f32 = *dflag;
  int i = blockIdx.x * 256 + threadIdx.x;
  if (i >= total) return;
  int r = i / Kp, k = i % Kp;
  float v = (r < rowsValid && k < K) ? inval(src, (size_t)r * K + k, f32) : 0.f;
  dst[i] = f2bf(v);
}

// Bt_gru: [8][896 rows n][416 k] bf16 (B^T, zero-padded rows>=800, k>=400)
__global__ void btgru_kernel(const float* __restrict__ Wp, const void* __restrict__ whh,
                             const int* __restrict__ dflag, ushort_t* __restrict__ Bt) {
  const int f32 = *dflag;
  int i = blockIdx.x * 256 + threadIdx.x;
  if (i >= NSTEPS * 896 * 416) return;
  int l = i / (896 * 416);
  int rem = i % (896 * 416);
  int nn = rem / 416;
  int k = rem % 416;
  int g = nn / 200, c = nn % 200;
  float v = 0.f;
  if (k < 200) {
    const float* wrow = Wp + ((size_t)l * 200 + k) * 600;
    if (g == 0) v = wrow[c];
    else if (g == 1) v = wrow[200 + c];
    else if (g == 2) v = wrow[400 + c];
  } else if (k < 400) {
    int kh = k - 200;
    if (g == 0) v = inval(whh, (size_t)c * 200 + kh, f32);
    else if (g == 1) v = inval(whh, (size_t)(200 + c) * 200 + kh, f32);
    else if (g == 3) v = inval(whh, (size_t)(400 + c) * 200 + kh, f32);
  }
  Bt[((size_t)l * 896 + nn) * 416 + k] = f2bf(v);
}

__global__ void btconv_kernel(const void* __restrict__ w, const int* __restrict__ dflag,
                              ushort_t* __restrict__ Bt, int C, int KT, int Kp,
                              int O, int total) {
  const int f32 = *dflag;
  int i = blockIdx.x * 256 + threadIdx.x;
  if (i >= total) return;
  int o = i / Kp, k = i % Kp;
  float v = 0.f;
  int K = C * KT;
  if (k < K && o < O) {
    int ktap = k / C; int ci = k % C;
    v = inval(w, ((size_t)o * C + ci) * KT + ktap, f32);
  }
  Bt[i] = f2bf(v);
}

// ---------------------------------------------------------------- GEMM (MFMA, 128x128)
// m-tile = blockIdx.x, n-tile = blockIdx.y.
// Staging: global_load_lds width=16 (async, no VGPR round-trip). LDS slot s holds
// (row r=s>>2, pos cs=s&3) with content = source chunk c = cs ^ ((r>>1)&3) — the
// XOR swizzle applied at the global source so fragment ds_read_b128s are 2-way max.
template <bool OUT_BF16>
__global__ __launch_bounds__(256) void gemm128(
    const ushort_t* __restrict__ A, int lda, const ushort_t* __restrict__ Bt,
    void* __restrict__ Cv, int ldc, int M, int N, int Kp,
    const float* __restrict__ bias) {
  __shared__ alignas(16) ushort_t As[128 * 32];
  __shared__ alignas(16) ushort_t Bs[128 * 32];
  const int tid = threadIdx.x;
  const int m0 = blockIdx.x * 128;
  const int n0 = blockIdx.y * 128;
  const int lane = tid & 63;
  const int wv = tid >> 6;
  const int wm = wv & 1;
  const int wn = wv >> 1;
  const int quad = lane >> 4;
  const int l15 = lane & 15;

  // per-lane staging sources (hoisted; only k0 advances in-loop)
  const int s0i = wv * 128 + lane;
  const int s1i = s0i + 64;
  const int r0 = s0i >> 2, c0 = (s0i & 3) ^ ((r0 >> 1) & 3);
  const int r1 = s1i >> 2, c1 = (s1i & 3) ^ ((r1 >> 1) & 3);
  int ar0 = m0 + r0; if (ar0 >= M) ar0 = M - 1;
  int ar1 = m0 + r1; if (ar1 >= M) ar1 = M - 1;
  const ushort_t* gA0 = A + (size_t)ar0 * lda + c0 * 8;
  const ushort_t* gA1 = A + (size_t)ar1 * lda + c1 * 8;
  const ushort_t* gB0 = Bt + (size_t)(n0 + r0) * Kp + c0 * 8;
  const ushort_t* gB1 = Bt + (size_t)(n0 + r1) * Kp + c1 * 8;
  ushort_t* lA0 = &As[(size_t)(wv * 128) * 8];        // wave-uniform LDS bases
  ushort_t* lA1 = &As[(size_t)(wv * 128 + 64) * 8];
  ushort_t* lB0 = &Bs[(size_t)(wv * 128) * 8];
  ushort_t* lB1 = &Bs[(size_t)(wv * 128 + 64) * 8];

  floatx4 acc[4][4];
  #pragma unroll
  for (int a = 0; a < 4; a++)
    #pragma unroll
    for (int b = 0; b < 4; b++)
      acc[a][b] = (floatx4){0.f, 0.f, 0.f, 0.f};

  for (int k0 = 0; k0 < Kp; k0 += 32) {
    gl2lds16(gA0 + k0, lA0);
    gl2lds16(gA1 + k0, lA1);
    gl2lds16(gB0 + k0, lB0);
    gl2lds16(gB1 + k0, lB1);
    __syncthreads();
    bf16x8 af[4], bfr[4];
    #pragma unroll
    for (int t = 0; t < 4; t++) {
      int ra = wm * 64 + t * 16 + l15;
      int rb = wn * 64 + t * 16 + l15;
      af[t]  = *(const bf16x8*)&As[(ra * 4 + (quad ^ ((ra >> 1) & 3))) * 8];
      bfr[t] = *(const bf16x8*)&Bs[(rb * 4 + (quad ^ ((rb >> 1) & 3))) * 8];
    }
    #pragma unroll
    for (int tm = 0; tm < 4; tm++)
      #pragma unroll
      for (int tn = 0; tn < 4; tn++)
        acc[tm][tn] = __builtin_amdgcn_mfma_f32_16x16x32_bf16(af[tm], bfr[tn], acc[tm][tn], 0, 0, 0);
    __syncthreads();
  }

  #pragma unroll
  for (int tm = 0; tm < 4; tm++) {
    int row = m0 + wm * 64 + tm * 16 + quad * 4;
    #pragma unroll
    for (int tn = 0; tn < 4; tn++) {
      int col = n0 + wn * 64 + tn * 16 + l15;
      if (col < N) {
        float bb = bias ? bias[col] : 0.f;
        #pragma unroll
        for (int r = 0; r < 4; r++) {
          if (row + r < M) {
            float v = acc[tm][tn][r] + bb;
            if (OUT_BF16) ((ushort_t*)Cv)[(size_t)(row + r) * ldc + col] = f2bf(v);
            else          ((float*)Cv)[(size_t)(row + r) * ldc + col] = v;
          }
        }
      }
    }
  }
}

__global__ void bias_kernel(const void* __restrict__ b, const int* __restrict__ dflag,
                            float* __restrict__ out, int n) {
  const int f32 = *dflag;
  int i = blockIdx.x * 256 + threadIdx.x;
  if (i < n) out[i] = inval(b, i, f32);
}

// ---------------------------------------------------------------- GRU elementwise (x4 vec)
__global__ __launch_bounds__(256) void gru_kernel(
    const ushort_t* __restrict__ G, const void* __restrict__ bih,
    const void* __restrict__ bhh, const int* __restrict__ dflag,
    ushort_t* __restrict__ h) {
  const int f32 = *dflag;
  int i = blockIdx.x * 256 + threadIdx.x;
  if (i >= NNODES * 50) return;
  int n = i / 50, q = (i % 50) * 4;
  const ushort_t* g = G + (size_t)n * 800;
  ushort4 gr = *(const ushort4*)&g[q];
  ushort4 gz = *(const ushort4*)&g[200 + q];
  ushort4 gi = *(const ushort4*)&g[400 + q];
  ushort4 gh = *(const ushort4*)&g[600 + q];
  ushort4 hv = *(const ushort4*)&h[(size_t)n * 200 + q];
  const ushort_t* grp = (const ushort_t*)&gr;
  const ushort_t* gzp = (const ushort_t*)&gz;
  const ushort_t* gip = (const ushort_t*)&gi;
  const ushort_t* ghp = (const ushort_t*)&gh;
  const ushort_t* hp  = (const ushort_t*)&hv;
  ushort4 ov; ushort_t* op = (ushort_t*)&ov;
  #pragma unroll
  for (int j = 0; j < 4; j++) {
    int c = q + j;
    float rr = bf2f(grp[j]) + inval(bih, c, f32)       + inval(bhh, c, f32);
    float zz = bf2f(gzp[j]) + inval(bih, 200 + c, f32) + inval(bhh, 200 + c, f32);
    float ic = bf2f(gip[j]) + inval(bih, 400 + c, f32);
    float hc = bf2f(ghp[j]) + inval(bhh, 400 + c, f32);
    float r = 1.f / (1.f + expf(-rr));
    float z = 1.f / (1.f + expf(-zz));
    float nn = tanhf(ic + r * hc);
    op[j] = f2bf((1.f - z) * nn + z * bf2f(hp[j]));
  }
  *(ushort4*)&h[(size_t)n * 200 + q] = ov;
}

// ---------------------------------------------------------------- BN stats + pool
__global__ void stats_kernel(const float* __restrict__ X, int Lrows, int C,
                             float* __restrict__ sums, float* __restrict__ sumsq) {
  int r0 = blockIdx.x * 64;
  int rend = r0 + 64; if (rend > Lrows) rend = Lrows;
  for (int c = threadIdx.x; c < C; c += 256) {
    float s = 0.f, ss = 0.f;
    for (int r = r0; r < rend; r++) {
      float v = X[(size_t)r * C + c];
      s += v; ss += v * v;
    }
    atomicAdd(&sums[c], s);
    atomicAdd(&sumsq[c], ss);
  }
}

__global__ void bnpool_kernel(const float* __restrict__ X, int Lin, int C, int kk, int ss,
                              int Lp, const float* __restrict__ sums,
                              const float* __restrict__ sumsq,
                              const void* __restrict__ g, const void* __restrict__ b,
                              const int* __restrict__ dflag, ushort_t* __restrict__ out) {
  const int f32 = *dflag;
  int i = blockIdx.x * 256 + threadIdx.x;
  if (i >= Lp * C) return;
  int p = i / C, c = i % C;
  float inv = 1.f / (float)Lin;
  float mu = sums[c] * inv;
  float var = sumsq[c] * inv - mu * mu; if (var < 0.f) var = 0.f;
  float scale = inval(g, c, f32) * rsqrtf(var + 1e-5f);
  float shift = inval(b, c, f32) - mu * scale;
  float m = -1e30f;
  int base = p * ss;
  for (int r = 0; r < kk; r++) {
    float v = X[(size_t)(base + r) * C + c] * scale + shift;
    if (v > m) m = v;
  }
  if (m < 0.f) m = 0.f;
  out[(size_t)p * C + c] = f2bf(m);
}

// ---------------------------------------------------------------- head (atomic-free)
__global__ __launch_bounds__(256) void final_kernel(
    const ushort_t* __restrict__ Y2, const ushort_t* __restrict__ Z2,
    const void* __restrict__ wy, const void* __restrict__ by,
    const void* __restrict__ wz, const void* __restrict__ bz,
    const int* __restrict__ dflag, float* __restrict__ pacc) {
  const int f32 = *dflag;
  __shared__ float bl[8];
  int g = threadIdx.x >> 6;
  int lane = threadIdx.x & 63;
  int row = blockIdx.x * 4 + g;
  float y0 = 0.f, y1 = 0.f, z0 = 0.f, z1 = 0.f;
  if (row < 12497) {
    for (int c = lane; c < 200; c += 64) {
      float v = bf2f(Y2[(size_t)row * 200 + c]);
      y0 += v * inval(wy, c, f32);
      y1 += v * inval(wy, 200 + c, f32);
    }
    for (int c = lane; c < 300; c += 64) {
      float v = bf2f(Z2[(size_t)row * 300 + c]);
      z0 += v * inval(wz, c, f32);
      z1 += v * inval(wz, 300 + c, f32);
    }
  }
  for (int off = 32; off > 0; off >>= 1) {
    y0 += __shfl_down(y0, off);
    y1 += __shfl_down(y1, off);
    z0 += __shfl_down(z0, off);
    z1 += __shfl_down(z1, off);
  }
  if (lane == 0) {
    float p0 = 0.f, p1 = 0.f;
    if (row < 12497) {
      p0 = (y0 + inval(by, 0, f32)) * (z0 + inval(bz, 0, f32));
      p1 = (y1 + inval(by, 1, f32)) * (z1 + inval(bz, 1, f32));
    }
    bl[g * 2] = p0; bl[g * 2 + 1] = p1;
  }
  __syncthreads();
  if (threadIdx.x == 0) {
    pacc[(size_t)blockIdx.x * 2]     = bl[0] + bl[2] + bl[4] + bl[6];
    pacc[(size_t)blockIdx.x * 2 + 1] = bl[1] + bl[3] + bl[5] + bl[7];
  }
}

__global__ __launch_bounds__(256) void finalize_kernel(
    const float* __restrict__ pacc, int nblk, const int* __restrict__ dflag,
    void* __restrict__ out) {
  const int f32 = *dflag;
  __shared__ float red[2][4];
  int t = threadIdx.x;
  float s0 = 0.f, s1 = 0.f;
  for (int i = t; i < nblk; i += 256) { s0 += pacc[2 * i]; s1 += pacc[2 * i + 1]; }
  for (int off = 32; off; off >>= 1) { s0 += __shfl_down(s0, off); s1 += __shfl_down(s1, off); }
  int w = t >> 6;
  if ((t & 63) == 0) { red[0][w] = s0; red[1][w] = s1; }
  __syncthreads();
  if (t == 0) {
    float a0 = (red[0][0] + red[0][1] + red[0][2] + red[0][3]) / 12497.f;
    float a1 = (red[1][0] + red[1][1] + red[1][2] + red[1][3]) / 12497.f;
    float mx = fmaxf(a0, a1);
    float e0 = expf(a0 - mx), e1 = expf(a1 - mx);
    float s = e0 + e1;
    if (f32) {
      ((float*)out)[0] = e0 / s;
      ((float*)out)[1] = e1 / s;
    } else {
      ((ushort_t*)out)[0] = f2bf(e0 / s);
      ((ushort_t*)out)[1] = f2bf(e1 / s);
    }
  }
}

// ---------------------------------------------------------------- launch
extern "C" void kernel_launch(void* const* d_in, const int* in_sizes, int n_in,
                              void* d_out, int out_size, void* d_ws, size_t ws_size,
                              hipStream_t stream) {
  const void* x        = d_in[0];
  const int*  edge     = (const int*)d_in[1];
  const void* ggnn_w   = d_in[2];
  const void* gru_wih  = d_in[3];
  const void* gru_whh  = d_in[4];
  const void* gru_bih  = d_in[5];
  const void* gru_bhh  = d_in[6];
  const void* conv1_w  = d_in[7];
  const void* conv1_b  = d_in[8];
  const void* conv2_w  = d_in[9];
  const void* conv2_b  = d_in[10];
  const void* conv1c_w = d_in[11];
  const void* conv1c_b = d_in[12];
  const void* conv2c_w = d_in[13];
  const void* conv2c_b = d_in[14];
  const void* bn_g     = d_in[15];
  const void* bn_b     = d_in[16];
  const void* bnc_g    = d_in[17];
  const void* bnc_b    = d_in[18];
  const void* mlpy_w   = d_in[19];
  const void* mlpy_b   = d_in[20];
  const void* mlpz_w   = d_in[21];
  const void* mlpz_b   = d_in[22];
  const int* srcv = edge;
  const int* dstv = edge + NEDGES;

  // ---- workspace layout (aliased; total ~177 MB) ----
  char* p = (char*)d_ws;
  auto alloc = [&](size_t bytes) -> char* {
    char* r = p; p += (bytes + 255) & ~(size_t)255; return r;
  };
  ushort_t* h    = (ushort_t*)alloc(((size_t)NNODES * FOUT + 64) * 2);
  ushort_t* Ag   = (ushort_t*)alloc(((size_t)NNODES * 400 + 64) * 2);
  ushort_t* cc   = Ag;  // cc[N,300] built AFTER GRU loop, Ag then dead
  char*     R    = alloc((size_t)98 * 1000 * 1000);
  ushort_t* G    = (ushort_t*)R;
  float*    C1   = (float*)R;
  float*    C2   = (float*)R;
  float*    C1c  = (float*)R;
  float*    C2c  = (float*)R;
  ushort_t* pooled1 = (ushort_t*)(R + 60000000);
  ushort_t* pooledc = (ushort_t*)(R + 70000000);
  ushort_t* Y2      = (ushort_t*)(R + 85000000);
  ushort_t* Z2      = (ushort_t*)(R + 90000000);
  ushort_t* BtG  = (ushort_t*)alloc((size_t)8 * 896 * 416 * 2);
  ushort_t* Bt1  = (ushort_t*)alloc((size_t)256 * 800 * 2);
  ushort_t* Bt2  = (ushort_t*)alloc((size_t)256 * 416 * 2);
  ushort_t* Bt1c = (ushort_t*)alloc((size_t)384 * 1216 * 2);
  ushort_t* Bt2c = (ushort_t*)alloc((size_t)384 * 608 * 2);
  ushort_t* gwp  = (ushort_t*)alloc((size_t)1600 * 224 * 2);
  ushort_t* wihp = (ushort_t*)alloc((size_t)640 * 224 * 2);
  float*    Wp   = (float*)alloc((size_t)1600 * 600 * 4);
  int*   csr_src = (int*)alloc((size_t)NEDGES * 4);
  int*   row_ptr = (int*)alloc((size_t)(NNODES + 1) * 4);
  int*   cursor  = (int*)alloc((size_t)NNODES * 4);
  int*   cnt     = (int*)alloc((size_t)NNODES * 4);
  int*   bsum    = (int*)alloc((size_t)(NSCANB + 4) * 4);
  int*   boff    = (int*)alloc((size_t)(NSCANB + 4) * 4);
  float* pacc    = (float*)alloc((size_t)3125 * 2 * 4);
  float* sb      = (float*)alloc((size_t)3300 * 4);
  float *s1 = sb, *ss1 = sb + 200, *s2 = sb + 400, *ss2 = sb + 600;
  float *sc1 = sb + 800, *ssc1 = sb + 1100, *sc2 = sb + 1400, *ssc2 = sb + 1700;
  int*   dflag = (int*)(sb + 2002);
  float* b1f   = sb + 2010;
  float* b2f   = sb + 2210;
  float* b1cf  = sb + 2410;
  float* b2cf  = sb + 2710;

  size_t required = (size_t)(p - (char*)d_ws);
  if (required > ws_size) {
    sentinel_kernel<<<1, 64, 0, stream>>>((ushort_t*)d_out);
    return;
  }

  probe_kernel<<<1, 64, 0, stream>>>(x, dflag);
  zero_kernel<<<(NNODES + 255) / 256, 256, 0, stream>>>(cnt, NNODES);
  zero_kernel<<<(2000 + 255) / 256, 256, 0, stream>>>((int*)sb, 2000);
  hinit_kernel<<<(NNODES * FOUT + 255) / 256, 256, 0, stream>>>(x, dflag, h);

  // wp = ggnn_w @ wih^T as one MFMA GEMM
  pada_kernel<<<(1600 * 224 + 255) / 256, 256, 0, stream>>>(ggnn_w, dflag, gwp, 200, 224, 1600, 1600 * 224);
  pada_kernel<<<(640 * 224 + 255) / 256, 256, 0, stream>>>(gru_wih, dflag, wihp, 200, 224, 600, 640 * 224);
  gemm128<false><<<dim3(13, 5), 256, 0, stream>>>(gwp, 224, wihp, Wp, 600, 1600, 600, 224, nullptr);

  btgru_kernel<<<(NSTEPS * 896 * 416 + 255) / 256, 256, 0, stream>>>(Wp, gru_whh, dflag, BtG);
  btconv_kernel<<<(256 * 800 + 255) / 256, 256, 0, stream>>>(conv1_w, dflag, Bt1, 200, 4, 800, 200, 256 * 800);
  btconv_kernel<<<(256 * 416 + 255) / 256, 256, 0, stream>>>(conv2_w, dflag, Bt2, 200, 2, 416, 200, 256 * 416);
  btconv_kernel<<<(384 * 1216 + 255) / 256, 256, 0, stream>>>(conv1c_w, dflag, Bt1c, 300, 4, 1216, 300, 384 * 1216);
  btconv_kernel<<<(384 * 608 + 255) / 256, 256, 0, stream>>>(conv2c_w, dflag, Bt2c, 300, 2, 608, 300, 384 * 608);
  bias_kernel<<<1, 256, 0, stream>>>(conv1_b, dflag, b1f, 200);
  bias_kernel<<<1, 256, 0, stream>>>(conv2_b, dflag, b2f, 200);
  bias_kernel<<<2, 256, 0, stream>>>(conv1c_b, dflag, b1cf, 300);
  bias_kernel<<<2, 256, 0, stream>>>(conv2c_b, dflag, b2cf, 300);

  hist_kernel<<<(NEDGES + 255) / 256, 256, 0, stream>>>(dstv, cnt);
  bsum_kernel<<<NSCANB, 256, 0, stream>>>(cnt, bsum);
  bscan_kernel<<<1, 256, 0, stream>>>(bsum, boff);
  rowptr_kernel<<<NSCANB, 256, 0, stream>>>(cnt, boff, row_ptr, cursor);
  fill_kernel<<<(NEDGES + 255) / 256, 256, 0, stream>>>(srcv, dstv, cursor, csr_src);

  for (int l = 0; l < NSTEPS; l++) {
    gather_kernel<<<(NNODES + 3) / 4, 256, 0, stream>>>(row_ptr, csr_src, h, Ag);
    gemm128<true><<<dim3(391, 7), 256, 0, stream>>>(Ag, 400, BtG + (size_t)l * 896 * 416,
                                                    G, 800, NNODES, 800, 416, nullptr);
    gru_kernel<<<(NNODES * 50 + 255) / 256, 256, 0, stream>>>(G, gru_bih, gru_bhh, dflag, h);
  }
  ccat_kernel<<<(NNODES * FCAT + 255) / 256, 256, 0, stream>>>(h, x, dflag, cc);

  // branch y
  gemm128<false><<<dim3(391, 2), 256, 0, stream>>>(h, 200, Bt1, C1, 200, 49997, 200, 800, b1f);
  stats_kernel<<<(49997 + 63) / 64, 256, 0, stream>>>(C1, 49997, 200, s1, ss1);
  bnpool_kernel<<<(24997 * 200 + 255) / 256, 256, 0, stream>>>(C1, 49997, 200, 4, 2, 24997,
                                                               s1, ss1, bn_g, bn_b, dflag, pooled1);
  gemm128<false><<<dim3(196, 2), 256, 0, stream>>>(pooled1, 200, Bt2, C2, 200, 24996, 200, 416, b2f);
  stats_kernel<<<(24996 + 63) / 64, 256, 0, stream>>>(C2, 24996, 200, s2, ss2);
  bnpool_kernel<<<(12497 * 200 + 255) / 256, 256, 0, stream>>>(C2, 24996, 200, 3, 2, 12497,
                                                               s2, ss2, bn_g, bn_b, dflag, Y2);
  // branch z
  gemm128<false><<<dim3(391, 3), 256, 0, stream>>>(cc, 300, Bt1c, C1c, 300, 49997, 300, 1216, b1cf);
  stats_kernel<<<(49997 + 63) / 64, 256, 0, stream>>>(C1c, 49997, 300, sc1, ssc1);
  bnpool_kernel<<<(24997 * 300 + 255) / 256, 256, 0, stream>>>(C1c, 49997, 300, 4, 2, 24997,
                                                               sc1, ssc1, bnc_g, bnc_b, dflag, pooledc);
  gemm128<false><<<dim3(196, 3), 256, 0, stream>>>(pooledc, 300, Bt2c, C2c, 300, 24996, 300, 608, b2cf);
  stats_kernel<<<(24996 + 63) / 64, 256, 0, stream>>>(C2c, 24996, 300, sc2, ssc2);
  bnpool_kernel<<<(12497 * 300 + 255) / 256, 256, 0, stream>>>(C2c, 24996, 300, 3, 2, 12497,
                                                               sc2, ssc2, bnc_g, bnc_b, dflag, Z2);

  final_kernel<<<3125, 256, 0, stream>>>(Y2, Z2, mlpy_w, mlpy_b, mlpz_w, mlpz_b, dflag, pacc);
  finalize_kernel<<<1, 256, 0, stream>>>(pacc, 3125, dflag, d_out);
}

// Round 8
// 2298.424 us; speedup vs baseline: 1.1226x; 1.0945x over previous
//
#include <hip/hip_runtime.h>
#include <cstdint>
#include <cstddef>

#define NNODES 50000
#define NEDGES 800000
#define FIN    100
#define FOUT   200
#define FCAT   300
#define NSTEPS 8
#define NSCANB 196

typedef unsigned short ushort_t;
typedef __bf16 bf16x8 __attribute__((ext_vector_type(8)));
typedef float  floatx4 __attribute__((ext_vector_type(4)));

__device__ __forceinline__ float bf2f(ushort_t u) {
  union { unsigned u; float f; } c; c.u = ((unsigned)u) << 16; return c.f;
}
__device__ __forceinline__ ushort_t f2bf(float f) {
  union { float f; unsigned u; } c; c.f = f;
  unsigned r = c.u + 0x7FFFu + ((c.u >> 16) & 1u);
  return (ushort_t)(r >> 16);
}
__device__ __forceinline__ float inval(const void* p, size_t i, int f32) {
  return f32 ? ((const float*)p)[i] : bf2f(((const ushort_t*)p)[i]);
}

// async global->LDS 16B
__device__ __forceinline__ void gl2lds16(const ushort_t* g, ushort_t* l) {
  typedef const __attribute__((address_space(1))) unsigned int gu32;
  typedef __attribute__((address_space(3))) unsigned int lu32;
  __builtin_amdgcn_global_load_lds((gu32*)(uintptr_t)g, (lu32*)(uintptr_t)l, 16, 0, 0);
}

// ---------------------------------------------------------------- dtype probe
__global__ void probe_kernel(const void* xraw, int* flag) {
  const ushort_t* u = (const ushort_t*)xraw;
  int t = threadIdx.x;
  int bad = 0;
  for (int i = t; i < 2048; i += 64) {
    int e = (u[2 * i] >> 7) & 0xFF;
    if (e >= 0x88) bad++;
  }
  for (int off = 32; off; off >>= 1) bad += __shfl_down(bad, off);
  if (t == 0) *flag = (bad > 128) ? 1 : 0;
}

// ---------------------------------------------------------------- utility
__global__ void zero_kernel(int* p, int n) {
  int i = blockIdx.x * 256 + threadIdx.x;
  if (i < n) p[i] = 0;
}

__global__ void sentinel_kernel(ushort_t* out) {
  if (threadIdx.x == 0 && blockIdx.x == 0) {
    out[0] = f2bf(0.123f);
    out[1] = f2bf(0.877f);
  }
}

__global__ void hinit_kernel(const void* __restrict__ x, const int* __restrict__ dflag,
                             ushort_t* __restrict__ h) {
  const int f32 = *dflag;
  int i = blockIdx.x * 256 + threadIdx.x;
  if (i >= NNODES * FOUT) return;
  int n = i / FOUT, c = i % FOUT;
  h[i] = (c < FIN) ? f2bf(inval(x, (size_t)n * FIN + c, f32)) : (ushort_t)0;
}

__global__ void ccat_kernel(const ushort_t* __restrict__ h, const void* __restrict__ x,
                            const int* __restrict__ dflag, ushort_t* __restrict__ cc) {
  const int f32 = *dflag;
  int i = blockIdx.x * 256 + threadIdx.x;
  if (i >= NNODES * FCAT) return;
  int n = i / FCAT, c = i % FCAT;
  cc[i] = (c < FOUT) ? h[n * FOUT + c] : f2bf(inval(x, (size_t)n * FIN + (c - FOUT), f32));
}

// ---------------------------------------------------------------- CSR build
__global__ void hist_kernel(const int* __restrict__ dst, int* __restrict__ cnt) {
  int e = blockIdx.x * 256 + threadIdx.x;
  if (e < NEDGES) atomicAdd(&cnt[dst[e]], 1);
}

__global__ void bsum_kernel(const int* __restrict__ cnt, int* __restrict__ bsum) {
  __shared__ int red[4];
  int i = blockIdx.x * 256 + threadIdx.x;
  int v = (i < NNODES) ? cnt[i] : 0;
  for (int off = 32; off; off >>= 1) v += __shfl_down(v, off);
  int w = threadIdx.x >> 6;
  if ((threadIdx.x & 63) == 0) red[w] = v;
  __syncthreads();
  if (threadIdx.x == 0) bsum[blockIdx.x] = red[0] + red[1] + red[2] + red[3];
}

__global__ void bscan_kernel(const int* __restrict__ bsum, int* __restrict__ boff) {
  __shared__ int s[256];
  int t = threadIdx.x;
  int v = (t < NSCANB) ? bsum[t] : 0;
  s[t] = v;
  __syncthreads();
  for (int off = 1; off < 256; off <<= 1) {
    int u = (t >= off) ? s[t - off] : 0;
    __syncthreads();
    s[t] += u;
    __syncthreads();
  }
  if (t < NSCANB) boff[t] = s[t] - v;   // exclusive
}

__global__ void rowptr_kernel(const int* __restrict__ cnt, const int* __restrict__ boff,
                              int* __restrict__ row_ptr, int* __restrict__ cursor) {
  __shared__ int s[256];
  int t = threadIdx.x;
  int i = blockIdx.x * 256 + t;
  int v = (i < NNODES) ? cnt[i] : 0;
  s[t] = v;
  __syncthreads();
  for (int off = 1; off < 256; off <<= 1) {
    int u = (t >= off) ? s[t - off] : 0;
    __syncthreads();
    s[t] += u;
    __syncthreads();
  }
  if (i < NNODES) {
    int e = boff[blockIdx.x] + s[t] - v;
    row_ptr[i] = e; cursor[i] = e;
    if (i == NNODES - 1) row_ptr[NNODES] = boff[blockIdx.x] + s[t];
  }
}

__global__ void fill_kernel(const int* __restrict__ srcv, const int* __restrict__ dstv,
                            int* __restrict__ cursor, int* __restrict__ csr_src) {
  int e = blockIdx.x * 256 + threadIdx.x;
  if (e >= NEDGES) return;
  int p = atomicAdd(&cursor[dstv[e]], 1);
  csr_src[p] = srcv[e];
}

// agg[n] = sum over in-edges of h[src]; writes A = [agg | h] row (400 wide, bf16)
// wave per node, lane covers 4 channels (ushort4), 4-edge unroll for latency hiding
__global__ __launch_bounds__(256) void gather_kernel(
    const int* __restrict__ row_ptr, const int* __restrict__ csr_src,
    const ushort_t* __restrict__ h, ushort_t* __restrict__ Ag) {
  int g = threadIdx.x >> 6;
  int lane = threadIdx.x & 63;
  int n = blockIdx.x * 4 + g;
  if (n >= NNODES) return;
  if (lane >= 50) return;
  int s0 = row_ptr[n], s1 = row_ptr[n + 1];
  float a0 = 0.f, a1 = 0.f, a2 = 0.f, a3 = 0.f;
  int i = s0;
  for (; i + 3 < s1; i += 4) {
    int sa = csr_src[i], sb = csr_src[i + 1], sc = csr_src[i + 2], sd = csr_src[i + 3];
    ushort4 va = *(const ushort4*)&h[(size_t)sa * FOUT + lane * 4];
    ushort4 vb = *(const ushort4*)&h[(size_t)sb * FOUT + lane * 4];
    ushort4 vc = *(const ushort4*)&h[(size_t)sc * FOUT + lane * 4];
    ushort4 vd = *(const ushort4*)&h[(size_t)sd * FOUT + lane * 4];
    a0 += (bf2f(va.x) + bf2f(vb.x)) + (bf2f(vc.x) + bf2f(vd.x));
    a1 += (bf2f(va.y) + bf2f(vb.y)) + (bf2f(vc.y) + bf2f(vd.y));
    a2 += (bf2f(va.z) + bf2f(vb.z)) + (bf2f(vc.z) + bf2f(vd.z));
    a3 += (bf2f(va.w) + bf2f(vb.w)) + (bf2f(vc.w) + bf2f(vd.w));
  }
  for (; i < s1; i++) {
    int sa = csr_src[i];
    ushort4 va = *(const ushort4*)&h[(size_t)sa * FOUT + lane * 4];
    a0 += bf2f(va.x); a1 += bf2f(va.y); a2 += bf2f(va.z); a3 += bf2f(va.w);
  }
  ushort4 o;
  o.x = f2bf(a0); o.y = f2bf(a1); o.z = f2bf(a2); o.w = f2bf(a3);
  *(ushort4*)&Ag[(size_t)n * 400 + lane * 4] = o;
  *(ushort4*)&Ag[(size_t)n * 400 + FOUT + lane * 4] =
      *(const ushort4*)&h[(size_t)n * FOUT + lane * 4];
}

// ---------------------------------------------------------------- padded bf16 copies
__global__ void pada_kernel(const void* __restrict__ src, const int* __restrict__ dflag,
                            ushort_t* __restrict__ dst, int K, int Kp, int rowsValid,
                            int total) {
  const int f32 = *dflag;
  int i = blockIdx.x * 256 + threadIdx.x;
  if (i >= total) return;
  int r = i / Kp, k = i % Kp;
  float v = (r < rowsValid && k < K) ? inval(src, (size_t)r * K + k, f32) : 0.f;
  dst[i] = f2bf(v);
}

// Bt_gru packed: [8][896 rows][416 k], row nn = 4*c + gate (r,z,ic,hc), c<200 valid.
// A k-layout: k<200 -> agg part (through Wp), 200<=k<400 -> h part (through whh).
__global__ void btgruq_kernel(const float* __restrict__ Wp, const void* __restrict__ whh,
                              const int* __restrict__ dflag, ushort_t* __restrict__ Bt) {
  const int f32 = *dflag;
  int i = blockIdx.x * 256 + threadIdx.x;
  if (i >= NSTEPS * 896 * 416) return;
  int l = i / (896 * 416);
  int rem = i % (896 * 416);
  int nn = rem / 416;
  int k = rem % 416;
  int c = nn >> 2, g = nn & 3;
  float v = 0.f;
  if (c < 200) {
    if (k < 200) {
      const float* wrow = Wp + ((size_t)l * 200 + k) * 600;
      if (g == 0) v = wrow[c];
      else if (g == 1) v = wrow[200 + c];
      else if (g == 2) v = wrow[400 + c];
    } else if (k < 400) {
      int kh = k - 200;
      if (g == 0) v = inval(whh, (size_t)c * 200 + kh, f32);
      else if (g == 1) v = inval(whh, (size_t)(200 + c) * 200 + kh, f32);
      else if (g == 3) v = inval(whh, (size_t)(400 + c) * 200 + kh, f32);
    }
  }
  Bt[((size_t)nn + 896 * (size_t)l) * 416 + k] = f2bf(v);
}

__global__ void btconv_kernel(const void* __restrict__ w, const int* __restrict__ dflag,
                              ushort_t* __restrict__ Bt, int C, int KT, int Kp,
                              int O, int total) {
  const int f32 = *dflag;
  int i = blockIdx.x * 256 + threadIdx.x;
  if (i >= total) return;
  int o = i / Kp, k = i % Kp;
  float v = 0.f;
  int K = C * KT;
  if (k < K && o < O) {
    int ktap = k / C; int ci = k % C;
    v = inval(w, ((size_t)o * C + ci) * KT + ktap, f32);
  }
  Bt[i] = f2bf(v);
}

// gru bias precombine: rb=bih_r+bhh_r, zb=..., ib=bih_n, hb=bhh_n  (gb[800] fp32)
__global__ void gbias_kernel(const void* __restrict__ bih, const void* __restrict__ bhh,
                             const int* __restrict__ dflag, float* __restrict__ gb) {
  const int f32 = *dflag;
  int c = blockIdx.x * 256 + threadIdx.x;
  if (c >= 200) return;
  gb[c]       = inval(bih, c, f32)       + inval(bhh, c, f32);
  gb[200 + c] = inval(bih, 200 + c, f32) + inval(bhh, 200 + c, f32);
  gb[400 + c] = inval(bih, 400 + c, f32);
  gb[600 + c] = inval(bhh, 400 + c, f32);
}

// ---------------------------------------------------------------- GEMM (MFMA, 128x128)
// Staging via global_load_lds width=16, XOR swizzle at the global source.
template <bool OUT_BF16>
__global__ __launch_bounds__(256) void gemm128(
    const ushort_t* __restrict__ A, int lda, const ushort_t* __restrict__ Bt,
    void* __restrict__ Cv, int ldc, int M, int N, int Kp,
    const float* __restrict__ bias) {
  __shared__ alignas(16) ushort_t As[128 * 32];
  __shared__ alignas(16) ushort_t Bs[128 * 32];
  const int tid = threadIdx.x;
  const int m0 = blockIdx.x * 128;
  const int n0 = blockIdx.y * 128;
  const int lane = tid & 63;
  const int wv = tid >> 6;
  const int wm = wv & 1;
  const int wn = wv >> 1;
  const int quad = lane >> 4;
  const int l15 = lane & 15;

  const int s0i = wv * 128 + lane;
  const int s1i = s0i + 64;
  const int r0 = s0i >> 2, c0 = (s0i & 3) ^ ((r0 >> 1) & 3);
  const int r1 = s1i >> 2, c1 = (s1i & 3) ^ ((r1 >> 1) & 3);
  int ar0 = m0 + r0; if (ar0 >= M) ar0 = M - 1;
  int ar1 = m0 + r1; if (ar1 >= M) ar1 = M - 1;
  const ushort_t* gA0 = A + (size_t)ar0 * lda + c0 * 8;
  const ushort_t* gA1 = A + (size_t)ar1 * lda + c1 * 8;
  const ushort_t* gB0 = Bt + (size_t)(n0 + r0) * Kp + c0 * 8;
  const ushort_t* gB1 = Bt + (size_t)(n0 + r1) * Kp + c1 * 8;
  ushort_t* lA0 = &As[(size_t)(wv * 128) * 8];
  ushort_t* lA1 = &As[(size_t)(wv * 128 + 64) * 8];
  ushort_t* lB0 = &Bs[(size_t)(wv * 128) * 8];
  ushort_t* lB1 = &Bs[(size_t)(wv * 128 + 64) * 8];

  floatx4 acc[4][4];
  #pragma unroll
  for (int a = 0; a < 4; a++)
    #pragma unroll
    for (int b = 0; b < 4; b++)
      acc[a][b] = (floatx4){0.f, 0.f, 0.f, 0.f};

  for (int k0 = 0; k0 < Kp; k0 += 32) {
    gl2lds16(gA0 + k0, lA0);
    gl2lds16(gA1 + k0, lA1);
    gl2lds16(gB0 + k0, lB0);
    gl2lds16(gB1 + k0, lB1);
    __syncthreads();
    bf16x8 af[4], bfr[4];
    #pragma unroll
    for (int t = 0; t < 4; t++) {
      int ra = wm * 64 + t * 16 + l15;
      int rb = wn * 64 + t * 16 + l15;
      af[t]  = *(const bf16x8*)&As[(ra * 4 + (quad ^ ((ra >> 1) & 3))) * 8];
      bfr[t] = *(const bf16x8*)&Bs[(rb * 4 + (quad ^ ((rb >> 1) & 3))) * 8];
    }
    #pragma unroll
    for (int tm = 0; tm < 4; tm++)
      #pragma unroll
      for (int tn = 0; tn < 4; tn++)
        acc[tm][tn] = __builtin_amdgcn_mfma_f32_16x16x32_bf16(af[tm], bfr[tn], acc[tm][tn], 0, 0, 0);
    __syncthreads();
  }

  #pragma unroll
  for (int tm = 0; tm < 4; tm++) {
    int row = m0 + wm * 64 + tm * 16 + quad * 4;
    #pragma unroll
    for (int tn = 0; tn < 4; tn++) {
      int col = n0 + wn * 64 + tn * 16 + l15;
      if (col < N) {
        float bb = bias ? bias[col] : 0.f;
        #pragma unroll
        for (int r = 0; r < 4; r++) {
          if (row + r < M) {
            float v = acc[tm][tn][r] + bb;
            if (OUT_BF16) ((ushort_t*)Cv)[(size_t)(row + r) * ldc + col] = f2bf(v);
            else          ((float*)Cv)[(size_t)(row + r) * ldc + col] = v;
          }
        }
      }
    }
  }
}

// ---------------------------------------------------------------- fused GRU GEMM
// Same k-loop as gemm128 on packed B (col = 4*c+gate). Epilogue: acc -> LDS
// (reusing the dead staging buffers; 64 KB), per-(row,channel) GRU math, h
// updated in place. Each block touches only its own rows of h -> race-free.
__global__ __launch_bounds__(256) void gemm_gru(
    const ushort_t* __restrict__ A, int lda, const ushort_t* __restrict__ Bt,
    ushort_t* __restrict__ h, int M, int Kp, const float* __restrict__ gb) {
  __shared__ alignas(16) char smem[65536];
  ushort_t* As = (ushort_t*)smem;
  ushort_t* Bs = (ushort_t*)(smem + 8192);
  const int tid = threadIdx.x;
  const int m0 = blockIdx.x * 128;
  const int n0 = blockIdx.y * 128;
  const int lane = tid & 63;
  const int wv = tid >> 6;
  const int wm = wv & 1;
  const int wn = wv >> 1;
  const int quad = lane >> 4;
  const int l15 = lane & 15;

  const int s0i = wv * 128 + lane;
  const int s1i = s0i + 64;
  const int r0 = s0i >> 2, c0 = (s0i & 3) ^ ((r0 >> 1) & 3);
  const int r1 = s1i >> 2, c1 = (s1i & 3) ^ ((r1 >> 1) & 3);
  int ar0 = m0 + r0; if (ar0 >= M) ar0 = M - 1;
  int ar1 = m0 + r1; if (ar1 >= M) ar1 = M - 1;
  const ushort_t* gA0 = A + (size_t)ar0 * lda + c0 * 8;
  const ushort_t* gA1 = A + (size_t)ar1 * lda + c1 * 8;
  const ushort_t* gB0 = Bt + (size_t)(n0 + r0) * Kp + c0 * 8;
  const ushort_t* gB1 = Bt + (size_t)(n0 + r1) * Kp + c1 * 8;
  ushort_t* lA0 = &As[(size_t)(wv * 128) * 8];
  ushort_t* lA1 = &As[(size_t)(wv * 128 + 64) * 8];
  ushort_t* lB0 = &Bs[(size_t)(wv * 128) * 8];
  ushort_t* lB1 = &Bs[(size_t)(wv * 128 + 64) * 8];

  floatx4 acc[4][4];
  #pragma unroll
  for (int a = 0; a < 4; a++)
    #pragma unroll
    for (int b = 0; b < 4; b++)
      acc[a][b] = (floatx4){0.f, 0.f, 0.f, 0.f};

  for (int k0 = 0; k0 < Kp; k0 += 32) {
    gl2lds16(gA0 + k0, lA0);
    gl2lds16(gA1 + k0, lA1);
    gl2lds16(gB0 + k0, lB0);
    gl2lds16(gB1 + k0, lB1);
    __syncthreads();
    bf16x8 af[4], bfr[4];
    #pragma unroll
    for (int t = 0; t < 4; t++) {
      int ra = wm * 64 + t * 16 + l15;
      int rb = wn * 64 + t * 16 + l15;
      af[t]  = *(const bf16x8*)&As[(ra * 4 + (quad ^ ((ra >> 1) & 3))) * 8];
      bfr[t] = *(const bf16x8*)&Bs[(rb * 4 + (quad ^ ((rb >> 1) & 3))) * 8];
    }
    #pragma unroll
    for (int tm = 0; tm < 4; tm++)
      #pragma unroll
      for (int tn = 0; tn < 4; tn++)
        acc[tm][tn] = __builtin_amdgcn_mfma_f32_16x16x32_bf16(af[tm], bfr[tn], acc[tm][tn], 0, 0, 0);
    __syncthreads();   // also protects smem reuse below
  }

  // epilogue: acc -> LDS fp32 [128][128]
  float* sC = (float*)smem;
  #pragma unroll
  for (int tm = 0; tm < 4; tm++) {
    int rl = wm * 64 + tm * 16 + quad * 4;
    #pragma unroll
    for (int tn = 0; tn < 4; tn++) {
      int cl = wn * 64 + tn * 16 + l15;
      #pragma unroll
      for (int r = 0; r < 4; r++)
        sC[(rl + r) * 128 + cl] = acc[tm][tn][r];
    }
  }
  __syncthreads();

  const int cbase = n0 >> 2;          // channel base of this tile (32 channels)
  const float* rbv = gb;
  const float* zbv = gb + 200;
  const float* ibv = gb + 400;
  const float* hbv = gb + 600;
  #pragma unroll
  for (int t4 = 0; t4 < 4; t4++) {
    int task = tid + t4 * 256;        // 0..1023 : 128 rows x 8 channel-quads
    int rowl = task >> 3;
    int cg = task & 7;
    int grow = m0 + rowl;
    if (grow >= M) continue;
    int cb = cbase + cg * 4;
    ushort_t hn[4];
    bool all = (cb + 3 < 200);
    #pragma unroll
    for (int jj = 0; jj < 4; jj++) {
      int c = cb + jj;
      if (c < 200) {
        float4 q = *(const float4*)&sC[rowl * 128 + cg * 16 + jj * 4];
        // replicate old G bf16 round-trip for bit-parity
        float Sr = bf2f(f2bf(q.x));
        float Sz = bf2f(f2bf(q.y));
        float Si = bf2f(f2bf(q.z));
        float Sh = bf2f(f2bf(q.w));
        float r_ = 1.f / (1.f + expf(-(Sr + rbv[c])));
        float z_ = 1.f / (1.f + expf(-(Sz + zbv[c])));
        float n_ = tanhf(Si + ibv[c] + r_ * (Sh + hbv[c]));
        float ho = bf2f(h[(size_t)grow * 200 + c]);
        hn[jj] = f2bf((1.f - z_) * n_ + z_ * ho);
      }
    }
    if (all) {
      *(ushort4*)&h[(size_t)grow * 200 + cb] = *(ushort4*)hn;
    } else {
      for (int jj = 0; jj < 4; jj++)
        if (cb + jj < 200) h[(size_t)grow * 200 + cb + jj] = hn[jj];
    }
  }
}

__global__ void bias_kernel(const void* __restrict__ b, const int* __restrict__ dflag,
                            float* __restrict__ out, int n) {
  const int f32 = *dflag;
  int i = blockIdx.x * 256 + threadIdx.x;
  if (i < n) out[i] = inval(b, i, f32);
}

// ---------------------------------------------------------------- BN stats + pool
__global__ void stats_kernel(const float* __restrict__ X, int Lrows, int C,
                             float* __restrict__ sums, float* __restrict__ sumsq) {
  int r0 = blockIdx.x * 64;
  int rend = r0 + 64; if (rend > Lrows) rend = Lrows;
  for (int c = threadIdx.x; c < C; c += 256) {
    float s = 0.f, ss = 0.f;
    for (int r = r0; r < rend; r++) {
      float v = X[(size_t)r * C + c];
      s += v; ss += v * v;
    }
    atomicAdd(&sums[c], s);
    atomicAdd(&sumsq[c], ss);
  }
}

__global__ void bnpool_kernel(const float* __restrict__ X, int Lin, int C, int kk, int ss,
                              int Lp, const float* __restrict__ sums,
                              const float* __restrict__ sumsq,
                              const void* __restrict__ g, const void* __restrict__ b,
                              const int* __restrict__ dflag, ushort_t* __restrict__ out) {
  const int f32 = *dflag;
  int i = blockIdx.x * 256 + threadIdx.x;
  if (i >= Lp * C) return;
  int p = i / C, c = i % C;
  float inv = 1.f / (float)Lin;
  float mu = sums[c] * inv;
  float var = sumsq[c] * inv - mu * mu; if (var < 0.f) var = 0.f;
  float scale = inval(g, c, f32) * rsqrtf(var + 1e-5f);
  float shift = inval(b, c, f32) - mu * scale;
  float m = -1e30f;
  int base = p * ss;
  for (int r = 0; r < kk; r++) {
    float v = X[(size_t)(base + r) * C + c] * scale + shift;
    if (v > m) m = v;
  }
  if (m < 0.f) m = 0.f;
  out[(size_t)p * C + c] = f2bf(m);
}

// ---------------------------------------------------------------- head (atomic-free)
__global__ __launch_bounds__(256) void final_kernel(
    const ushort_t* __restrict__ Y2, const ushort_t* __restrict__ Z2,
    const void* __restrict__ wy, const void* __restrict__ by,
    const void* __restrict__ wz, const void* __restrict__ bz,
    const int* __restrict__ dflag, float* __restrict__ pacc) {
  const int f32 = *dflag;
  __shared__ float bl[8];
  int g = threadIdx.x >> 6;
  int lane = threadIdx.x & 63;
  int row = blockIdx.x * 4 + g;
  float y0 = 0.f, y1 = 0.f, z0 = 0.f, z1 = 0.f;
  if (row < 12497) {
    for (int c = lane; c < 200; c += 64) {
      float v = bf2f(Y2[(size_t)row * 200 + c]);
      y0 += v * inval(wy, c, f32);
      y1 += v * inval(wy, 200 + c, f32);
    }
    for (int c = lane; c < 300; c += 64) {
      float v = bf2f(Z2[(size_t)row * 300 + c]);
      z0 += v * inval(wz, c, f32);
      z1 += v * inval(wz, 300 + c, f32);
    }
  }
  for (int off = 32; off > 0; off >>= 1) {
    y0 += __shfl_down(y0, off);
    y1 += __shfl_down(y1, off);
    z0 += __shfl_down(z0, off);
    z1 += __shfl_down(z1, off);
  }
  if (lane == 0) {
    float p0 = 0.f, p1 = 0.f;
    if (row < 12497) {
      p0 = (y0 + inval(by, 0, f32)) * (z0 + inval(bz, 0, f32));
      p1 = (y1 + inval(by, 1, f32)) * (z1 + inval(bz, 1, f32));
    }
    bl[g * 2] = p0; bl[g * 2 + 1] = p1;
  }
  __syncthreads();
  if (threadIdx.x == 0) {
    pacc[(size_t)blockIdx.x * 2]     = bl[0] + bl[2] + bl[4] + bl[6];
    pacc[(size_t)blockIdx.x * 2 + 1] = bl[1] + bl[3] + bl[5] + bl[7];
  }
}

__global__ __launch_bounds__(256) void finalize_kernel(
    const float* __restrict__ pacc, int nblk, const int* __restrict__ dflag,
    void* __restrict__ out) {
  const int f32 = *dflag;
  __shared__ float red[2][4];
  int t = threadIdx.x;
  float s0 = 0.f, s1 = 0.f;
  for (int i = t; i < nblk; i += 256) { s0 += pacc[2 * i]; s1 += pacc[2 * i + 1]; }
  for (int off = 32; off; off >>= 1) { s0 += __shfl_down(s0, off); s1 += __shfl_down(s1, off); }
  int w = t >> 6;
  if ((t & 63) == 0) { red[0][w] = s0; red[1][w] = s1; }
  __syncthreads();
  if (t == 0) {
    float a0 = (red[0][0] + red[0][1] + red[0][2] + red[0][3]) / 12497.f;
    float a1 = (red[1][0] + red[1][1] + red[1][2] + red[1][3]) / 12497.f;
    float mx = fmaxf(a0, a1);
    float e0 = expf(a0 - mx), e1 = expf(a1 - mx);
    float s = e0 + e1;
    if (f32) {
      ((float*)out)[0] = e0 / s;
      ((float*)out)[1] = e1 / s;
    } else {
      ((ushort_t*)out)[0] = f2bf(e0 / s);
      ((ushort_t*)out)[1] = f2bf(e1 / s);
    }
  }
}

// ---------------------------------------------------------------- launch
extern "C" void kernel_launch(void* const* d_in, const int* in_sizes, int n_in,
                              void* d_out, int out_size, void* d_ws, size_t ws_size,
                              hipStream_t stream) {
  const void* x        = d_in[0];
  const int*  edge     = (const int*)d_in[1];
  const void* ggnn_w   = d_in[2];
  const void* gru_wih  = d_in[3];
  const void* gru_whh  = d_in[4];
  const void* gru_bih  = d_in[5];
  const void* gru_bhh  = d_in[6];
  const void* conv1_w  = d_in[7];
  const void* conv1_b  = d_in[8];
  const void* conv2_w  = d_in[9];
  const void* conv2_b  = d_in[10];
  const void* conv1c_w = d_in[11];
  const void* conv1c_b = d_in[12];
  const void* conv2c_w = d_in[13];
  const void* conv2c_b = d_in[14];
  const void* bn_g     = d_in[15];
  const void* bn_b     = d_in[16];
  const void* bnc_g    = d_in[17];
  const void* bnc_b    = d_in[18];
  const void* mlpy_w   = d_in[19];
  const void* mlpy_b   = d_in[20];
  const void* mlpz_w   = d_in[21];
  const void* mlpz_b   = d_in[22];
  const int* srcv = edge;
  const int* dstv = edge + NEDGES;

  // ---- workspace layout (aliased; total ~177 MB) ----
  char* p = (char*)d_ws;
  auto alloc = [&](size_t bytes) -> char* {
    char* r = p; p += (bytes + 255) & ~(size_t)255; return r;
  };
  ushort_t* h    = (ushort_t*)alloc(((size_t)NNODES * FOUT + 64) * 2);
  ushort_t* Ag   = (ushort_t*)alloc(((size_t)NNODES * 400 + 64) * 2);
  ushort_t* cc   = Ag;  // cc[N,300] built AFTER GRU loop, Ag then dead
  char*     R    = alloc((size_t)98 * 1000 * 1000);
  float*    C1   = (float*)R;
  float*    C2   = (float*)R;
  float*    C1c  = (float*)R;
  float*    C2c  = (float*)R;
  ushort_t* pooled1 = (ushort_t*)(R + 60000000);
  ushort_t* pooledc = (ushort_t*)(R + 70000000);
  ushort_t* Y2      = (ushort_t*)(R + 85000000);
  ushort_t* Z2      = (ushort_t*)(R + 90000000);
  ushort_t* BtG  = (ushort_t*)alloc((size_t)8 * 896 * 416 * 2);
  ushort_t* Bt1  = (ushort_t*)alloc((size_t)256 * 800 * 2);
  ushort_t* Bt2  = (ushort_t*)alloc((size_t)256 * 416 * 2);
  ushort_t* Bt1c = (ushort_t*)alloc((size_t)384 * 1216 * 2);
  ushort_t* Bt2c = (ushort_t*)alloc((size_t)384 * 608 * 2);
  ushort_t* gwp  = (ushort_t*)alloc((size_t)1600 * 224 * 2);
  ushort_t* wihp = (ushort_t*)alloc((size_t)640 * 224 * 2);
  float*    Wp   = (float*)alloc((size_t)1600 * 600 * 4);
  int*   csr_src = (int*)alloc((size_t)NEDGES * 4);
  int*   row_ptr = (int*)alloc((size_t)(NNODES + 1) * 4);
  int*   cursor  = (int*)alloc((size_t)NNODES * 4);
  int*   cnt     = (int*)alloc((size_t)NNODES * 4);
  int*   bsum    = (int*)alloc((size_t)(NSCANB + 4) * 4);
  int*   boff    = (int*)alloc((size_t)(NSCANB + 4) * 4);
  float* pacc    = (float*)alloc((size_t)3125 * 2 * 4);
  float* sb      = (float*)alloc((size_t)4300 * 4);
  float *s1 = sb, *ss1 = sb + 200, *s2 = sb + 400, *ss2 = sb + 600;
  float *sc1 = sb + 800, *ssc1 = sb + 1100, *sc2 = sb + 1400, *ssc2 = sb + 1700;
  int*   dflag = (int*)(sb + 2002);
  float* b1f   = sb + 2010;
  float* b2f   = sb + 2210;
  float* b1cf  = sb + 2410;
  float* b2cf  = sb + 2710;
  float* gb    = sb + 3100;   // 800 fp32 gru bias combos

  size_t required = (size_t)(p - (char*)d_ws);
  if (required > ws_size) {
    sentinel_kernel<<<1, 64, 0, stream>>>((ushort_t*)d_out);
    return;
  }

  probe_kernel<<<1, 64, 0, stream>>>(x, dflag);
  zero_kernel<<<(NNODES + 255) / 256, 256, 0, stream>>>(cnt, NNODES);
  zero_kernel<<<(2000 + 255) / 256, 256, 0, stream>>>((int*)sb, 2000);
  hinit_kernel<<<(NNODES * FOUT + 255) / 256, 256, 0, stream>>>(x, dflag, h);

  // wp = ggnn_w @ wih^T as one MFMA GEMM
  pada_kernel<<<(1600 * 224 + 255) / 256, 256, 0, stream>>>(ggnn_w, dflag, gwp, 200, 224, 1600, 1600 * 224);
  pada_kernel<<<(640 * 224 + 255) / 256, 256, 0, stream>>>(gru_wih, dflag, wihp, 200, 224, 600, 640 * 224);
  gemm128<false><<<dim3(13, 5), 256, 0, stream>>>(gwp, 224, wihp, Wp, 600, 1600, 600, 224, nullptr);

  btgruq_kernel<<<(NSTEPS * 896 * 416 + 255) / 256, 256, 0, stream>>>(Wp, gru_whh, dflag, BtG);
  gbias_kernel<<<1, 256, 0, stream>>>(gru_bih, gru_bhh, dflag, gb);
  btconv_kernel<<<(256 * 800 + 255) / 256, 256, 0, stream>>>(conv1_w, dflag, Bt1, 200, 4, 800, 200, 256 * 800);
  btconv_kernel<<<(256 * 416 + 255) / 256, 256, 0, stream>>>(conv2_w, dflag, Bt2, 200, 2, 416, 200, 256 * 416);
  btconv_kernel<<<(384 * 1216 + 255) / 256, 256, 0, stream>>>(conv1c_w, dflag, Bt1c, 300, 4, 1216, 300, 384 * 1216);
  btconv_kernel<<<(384 * 608 + 255) / 256, 256, 0, stream>>>(conv2c_w, dflag, Bt2c, 300, 2, 608, 300, 384 * 608);
  bias_kernel<<<1, 256, 0, stream>>>(conv1_b, dflag, b1f, 200);
  bias_kernel<<<1, 256, 0, stream>>>(conv2_b, dflag, b2f, 200);
  bias_kernel<<<2, 256, 0, stream>>>(conv1c_b, dflag, b1cf, 300);
  bias_kernel<<<2, 256, 0, stream>>>(conv2c_b, dflag, b2cf, 300);

  hist_kernel<<<(NEDGES + 255) / 256, 256, 0, stream>>>(dstv, cnt);
  bsum_kernel<<<NSCANB, 256, 0, stream>>>(cnt, bsum);
  bscan_kernel<<<1, 256, 0, stream>>>(bsum, boff);
  rowptr_kernel<<<NSCANB, 256, 0, stream>>>(cnt, boff, row_ptr, cursor);
  fill_kernel<<<(NEDGES + 255) / 256, 256, 0, stream>>>(srcv, dstv, cursor, csr_src);

  for (int l = 0; l < NSTEPS; l++) {
    gather_kernel<<<(NNODES + 3) / 4, 256, 0, stream>>>(row_ptr, csr_src, h, Ag);
    gemm_gru<<<dim3(391, 7), 256, 0, stream>>>(Ag, 400, BtG + (size_t)l * 896 * 416,
                                               h, NNODES, 416, gb);
  }
  ccat_kernel<<<(NNODES * FCAT + 255) / 256, 256, 0, stream>>>(h, x, dflag, cc);

  // branch y
  gemm128<false><<<dim3(391, 2), 256, 0, stream>>>(h, 200, Bt1, C1, 200, 49997, 200, 800, b1f);
  stats_kernel<<<(49997 + 63) / 64, 256, 0, stream>>>(C1, 49997, 200, s1, ss1);
  bnpool_kernel<<<(24997 * 200 + 255) / 256, 256, 0, stream>>>(C1, 49997, 200, 4, 2, 24997,
                                                               s1, ss1, bn_g, bn_b, dflag, pooled1);
  gemm128<false><<<dim3(196, 2), 256, 0, stream>>>(pooled1, 200, Bt2, C2, 200, 24996, 200, 416, b2f);
  stats_kernel<<<(24996 + 63) / 64, 256, 0, stream>>>(C2, 24996, 200, s2, ss2);
  bnpool_kernel<<<(12497 * 200 + 255) / 256, 256, 0, stream>>>(C2, 24996, 200, 3, 2, 12497,
                                                               s2, ss2, bn_g, bn_b, dflag, Y2);
  // branch z
  gemm128<false><<<dim3(391, 3), 256, 0, stream>>>(cc, 300, Bt1c, C1c, 300, 49997, 300, 1216, b1cf);
  stats_kernel<<<(49997 + 63) / 64, 256, 0, stream>>>(C1c, 49997, 300, sc1, ssc1);
  bnpool_kernel<<<(24997 * 300 + 255) / 256, 256, 0, stream>>>(C1c, 49997, 300, 4, 2, 24997,
                                                               sc1, ssc1, bnc_g, bnc_b, dflag, pooledc);
  gemm128<false><<<dim3(196, 3), 256, 0, stream>>>(pooledc, 300, Bt2c, C2c, 300, 24996, 300, 608, b2cf);
  stats_kernel<<<(24996 + 63) / 64, 256, 0, stream>>>(C2c, 24996, 300, sc2, ssc2);
  bnpool_kernel<<<(12497 * 300 + 255) / 256, 256, 0, stream>>>(C2c, 24996, 300, 3, 2, 12497,
                                                               sc2, ssc2, bnc_g, bnc_b, dflag, Z2);

  final_kernel<<<3125, 256, 0, stream>>>(Y2, Z2, mlpy_w, mlpy_b, mlpz_w, mlpz_b, dflag, pacc);
  finalize_kernel<<<1, 256, 0, stream>>>(pacc, 3125, dflag, d_out);
}

// Round 9
// 2097.309 us; speedup vs baseline: 1.2302x; 1.0959x over previous
//
#include <hip/hip_runtime.h>
#include <cstdint>
#include <cstddef>

#define NNODES 50000
#define NEDGES 800000
#define FIN    100
#define FOUT   200
#define FCAT   300
#define NSTEPS 8
#define NSCANB 196

typedef unsigned short ushort_t;
typedef __bf16 bf16x8 __attribute__((ext_vector_type(8)));
typedef float  floatx4 __attribute__((ext_vector_type(4)));

__device__ __forceinline__ float bf2f(ushort_t u) {
  union { unsigned u; float f; } c; c.u = ((unsigned)u) << 16; return c.f;
}
__device__ __forceinline__ ushort_t f2bf(float f) {
  union { float f; unsigned u; } c; c.f = f;
  unsigned r = c.u + 0x7FFFu + ((c.u >> 16) & 1u);
  return (ushort_t)(r >> 16);
}
__device__ __forceinline__ float inval(const void* p, size_t i, int f32) {
  return f32 ? ((const float*)p)[i] : bf2f(((const ushort_t*)p)[i]);
}

// async global->LDS 16B
__device__ __forceinline__ void gl2lds16(const ushort_t* g, ushort_t* l) {
  typedef const __attribute__((address_space(1))) unsigned int gu32;
  typedef __attribute__((address_space(3))) unsigned int lu32;
  __builtin_amdgcn_global_load_lds((gu32*)(uintptr_t)g, (lu32*)(uintptr_t)l, 16, 0, 0);
}

// ---------------------------------------------------------------- dtype probe
__global__ void probe_kernel(const void* xraw, int* flag) {
  const ushort_t* u = (const ushort_t*)xraw;
  int t = threadIdx.x;
  int bad = 0;
  for (int i = t; i < 2048; i += 64) {
    int e = (u[2 * i] >> 7) & 0xFF;
    if (e >= 0x88) bad++;
  }
  for (int off = 32; off; off >>= 1) bad += __shfl_down(bad, off);
  if (t == 0) *flag = (bad > 128) ? 1 : 0;
}

// ---------------------------------------------------------------- utility
__global__ void zero_kernel(int* p, int n) {
  int i = blockIdx.x * 256 + threadIdx.x;
  if (i < n) p[i] = 0;
}

__global__ void sentinel_kernel(ushort_t* out) {
  if (threadIdx.x == 0 && blockIdx.x == 0) {
    out[0] = f2bf(0.123f);
    out[1] = f2bf(0.877f);
  }
}

__global__ void hinit_kernel(const void* __restrict__ x, const int* __restrict__ dflag,
                             ushort_t* __restrict__ h) {
  const int f32 = *dflag;
  int i = blockIdx.x * 256 + threadIdx.x;
  if (i >= NNODES * FOUT) return;
  int n = i / FOUT, c = i % FOUT;
  h[i] = (c < FIN) ? f2bf(inval(x, (size_t)n * FIN + c, f32)) : (ushort_t)0;
}

__global__ void ccat_kernel(const ushort_t* __restrict__ h, const void* __restrict__ x,
                            const int* __restrict__ dflag, ushort_t* __restrict__ cc) {
  const int f32 = *dflag;
  int i = blockIdx.x * 256 + threadIdx.x;
  if (i >= NNODES * FCAT) return;
  int n = i / FCAT, c = i % FCAT;
  cc[i] = (c < FOUT) ? h[n * FOUT + c] : f2bf(inval(x, (size_t)n * FIN + (c - FOUT), f32));
}

// ---------------------------------------------------------------- CSR build
__global__ void hist_kernel(const int* __restrict__ dst, int* __restrict__ cnt) {
  int e = blockIdx.x * 256 + threadIdx.x;
  if (e < NEDGES) atomicAdd(&cnt[dst[e]], 1);
}

__global__ void bsum_kernel(const int* __restrict__ cnt, int* __restrict__ bsum) {
  __shared__ int red[4];
  int i = blockIdx.x * 256 + threadIdx.x;
  int v = (i < NNODES) ? cnt[i] : 0;
  for (int off = 32; off; off >>= 1) v += __shfl_down(v, off);
  int w = threadIdx.x >> 6;
  if ((threadIdx.x & 63) == 0) red[w] = v;
  __syncthreads();
  if (threadIdx.x == 0) bsum[blockIdx.x] = red[0] + red[1] + red[2] + red[3];
}

__global__ void bscan_kernel(const int* __restrict__ bsum, int* __restrict__ boff) {
  __shared__ int s[256];
  int t = threadIdx.x;
  int v = (t < NSCANB) ? bsum[t] : 0;
  s[t] = v;
  __syncthreads();
  for (int off = 1; off < 256; off <<= 1) {
    int u = (t >= off) ? s[t - off] : 0;
    __syncthreads();
    s[t] += u;
    __syncthreads();
  }
  if (t < NSCANB) boff[t] = s[t] - v;   // exclusive
}

__global__ void rowptr_kernel(const int* __restrict__ cnt, const int* __restrict__ boff,
                              int* __restrict__ row_ptr, int* __restrict__ cursor) {
  __shared__ int s[256];
  int t = threadIdx.x;
  int i = blockIdx.x * 256 + t;
  int v = (i < NNODES) ? cnt[i] : 0;
  s[t] = v;
  __syncthreads();
  for (int off = 1; off < 256; off <<= 1) {
    int u = (t >= off) ? s[t - off] : 0;
    __syncthreads();
    s[t] += u;
    __syncthreads();
  }
  if (i < NNODES) {
    int e = boff[blockIdx.x] + s[t] - v;
    row_ptr[i] = e; cursor[i] = e;
    if (i == NNODES - 1) row_ptr[NNODES] = boff[blockIdx.x] + s[t];
  }
}

__global__ void fill_kernel(const int* __restrict__ srcv, const int* __restrict__ dstv,
                            int* __restrict__ cursor, int* __restrict__ csr_src) {
  int e = blockIdx.x * 256 + threadIdx.x;
  if (e >= NEDGES) return;
  int p = atomicAdd(&cursor[dstv[e]], 1);
  csr_src[p] = srcv[e];
}

// agg[n] = sum over in-edges of h[src]; writes A = [agg | h] row (400 wide, bf16)
__global__ __launch_bounds__(256) void gather_kernel(
    const int* __restrict__ row_ptr, const int* __restrict__ csr_src,
    const ushort_t* __restrict__ h, ushort_t* __restrict__ Ag) {
  int g = threadIdx.x >> 6;
  int lane = threadIdx.x & 63;
  int n = blockIdx.x * 4 + g;
  if (n >= NNODES) return;
  if (lane >= 50) return;
  int s0 = row_ptr[n], s1 = row_ptr[n + 1];
  float a0 = 0.f, a1 = 0.f, a2 = 0.f, a3 = 0.f;
  int i = s0;
  for (; i + 3 < s1; i += 4) {
    int sa = csr_src[i], sb = csr_src[i + 1], sc = csr_src[i + 2], sd = csr_src[i + 3];
    ushort4 va = *(const ushort4*)&h[(size_t)sa * FOUT + lane * 4];
    ushort4 vb = *(const ushort4*)&h[(size_t)sb * FOUT + lane * 4];
    ushort4 vc = *(const ushort4*)&h[(size_t)sc * FOUT + lane * 4];
    ushort4 vd = *(const ushort4*)&h[(size_t)sd * FOUT + lane * 4];
    a0 += (bf2f(va.x) + bf2f(vb.x)) + (bf2f(vc.x) + bf2f(vd.x));
    a1 += (bf2f(va.y) + bf2f(vb.y)) + (bf2f(vc.y) + bf2f(vd.y));
    a2 += (bf2f(va.z) + bf2f(vb.z)) + (bf2f(vc.z) + bf2f(vd.z));
    a3 += (bf2f(va.w) + bf2f(vb.w)) + (bf2f(vc.w) + bf2f(vd.w));
  }
  for (; i < s1; i++) {
    int sa = csr_src[i];
    ushort4 va = *(const ushort4*)&h[(size_t)sa * FOUT + lane * 4];
    a0 += bf2f(va.x); a1 += bf2f(va.y); a2 += bf2f(va.z); a3 += bf2f(va.w);
  }
  ushort4 o;
  o.x = f2bf(a0); o.y = f2bf(a1); o.z = f2bf(a2); o.w = f2bf(a3);
  *(ushort4*)&Ag[(size_t)n * 400 + lane * 4] = o;
  *(ushort4*)&Ag[(size_t)n * 400 + FOUT + lane * 4] =
      *(const ushort4*)&h[(size_t)n * FOUT + lane * 4];
}

// ---------------------------------------------------------------- padded bf16 copies
__global__ void pada_kernel(const void* __restrict__ src, const int* __restrict__ dflag,
                            ushort_t* __restrict__ dst, int K, int Kp, int rowsValid,
                            int total) {
  const int f32 = *dflag;
  int i = blockIdx.x * 256 + threadIdx.x;
  if (i >= total) return;
  int r = i / Kp, k = i % Kp;
  float v = (r < rowsValid && k < K) ? inval(src, (size_t)r * K + k, f32) : 0.f;
  dst[i] = f2bf(v);
}

// Bt_gru packed: [8][896 rows][416 k], row nn = 4*c + gate (r,z,ic,hc), c<200 valid.
__global__ void btgruq_kernel(const float* __restrict__ Wp, const void* __restrict__ whh,
                              const int* __restrict__ dflag, ushort_t* __restrict__ Bt) {
  const int f32 = *dflag;
  int i = blockIdx.x * 256 + threadIdx.x;
  if (i >= NSTEPS * 896 * 416) return;
  int l = i / (896 * 416);
  int rem = i % (896 * 416);
  int nn = rem / 416;
  int k = rem % 416;
  int c = nn >> 2, g = nn & 3;
  float v = 0.f;
  if (c < 200) {
    if (k < 200) {
      const float* wrow = Wp + ((size_t)l * 200 + k) * 600;
      if (g == 0) v = wrow[c];
      else if (g == 1) v = wrow[200 + c];
      else if (g == 2) v = wrow[400 + c];
    } else if (k < 400) {
      int kh = k - 200;
      if (g == 0) v = inval(whh, (size_t)c * 200 + kh, f32);
      else if (g == 1) v = inval(whh, (size_t)(200 + c) * 200 + kh, f32);
      else if (g == 3) v = inval(whh, (size_t)(400 + c) * 200 + kh, f32);
    }
  }
  Bt[((size_t)nn + 896 * (size_t)l) * 416 + k] = f2bf(v);
}

__global__ void btconv_kernel(const void* __restrict__ w, const int* __restrict__ dflag,
                              ushort_t* __restrict__ Bt, int C, int KT, int Kp,
                              int O, int total) {
  const int f32 = *dflag;
  int i = blockIdx.x * 256 + threadIdx.x;
  if (i >= total) return;
  int o = i / Kp, k = i % Kp;
  float v = 0.f;
  int K = C * KT;
  if (k < K && o < O) {
    int ktap = k / C; int ci = k % C;
    v = inval(w, ((size_t)o * C + ci) * KT + ktap, f32);
  }
  Bt[i] = f2bf(v);
}

// gru bias precombine
__global__ void gbias_kernel(const void* __restrict__ bih, const void* __restrict__ bhh,
                             const int* __restrict__ dflag, float* __restrict__ gb) {
  const int f32 = *dflag;
  int c = blockIdx.x * 256 + threadIdx.x;
  if (c >= 200) return;
  gb[c]       = inval(bih, c, f32)       + inval(bhh, c, f32);
  gb[200 + c] = inval(bih, 200 + c, f32) + inval(bhh, 200 + c, f32);
  gb[400 + c] = inval(bih, 400 + c, f32);
  gb[600 + c] = inval(bhh, 400 + c, f32);
}

// ---------------------------------------------------------------- GEMM (MFMA, 128x128)
template <bool OUT_BF16>
__global__ __launch_bounds__(256) void gemm128(
    const ushort_t* __restrict__ A, int lda, const ushort_t* __restrict__ Bt,
    void* __restrict__ Cv, int ldc, int M, int N, int Kp,
    const float* __restrict__ bias) {
  __shared__ alignas(16) ushort_t As[128 * 32];
  __shared__ alignas(16) ushort_t Bs[128 * 32];
  const int tid = threadIdx.x;
  const int m0 = blockIdx.x * 128;
  const int n0 = blockIdx.y * 128;
  const int lane = tid & 63;
  const int wv = tid >> 6;
  const int wm = wv & 1;
  const int wn = wv >> 1;
  const int quad = lane >> 4;
  const int l15 = lane & 15;

  const int s0i = wv * 128 + lane;
  const int s1i = s0i + 64;
  const int r0 = s0i >> 2, c0 = (s0i & 3) ^ ((r0 >> 1) & 3);
  const int r1 = s1i >> 2, c1 = (s1i & 3) ^ ((r1 >> 1) & 3);
  int ar0 = m0 + r0; if (ar0 >= M) ar0 = M - 1;
  int ar1 = m0 + r1; if (ar1 >= M) ar1 = M - 1;
  const ushort_t* gA0 = A + (size_t)ar0 * lda + c0 * 8;
  const ushort_t* gA1 = A + (size_t)ar1 * lda + c1 * 8;
  const ushort_t* gB0 = Bt + (size_t)(n0 + r0) * Kp + c0 * 8;
  const ushort_t* gB1 = Bt + (size_t)(n0 + r1) * Kp + c1 * 8;
  ushort_t* lA0 = &As[(size_t)(wv * 128) * 8];
  ushort_t* lA1 = &As[(size_t)(wv * 128 + 64) * 8];
  ushort_t* lB0 = &Bs[(size_t)(wv * 128) * 8];
  ushort_t* lB1 = &Bs[(size_t)(wv * 128 + 64) * 8];

  floatx4 acc[4][4];
  #pragma unroll
  for (int a = 0; a < 4; a++)
    #pragma unroll
    for (int b = 0; b < 4; b++)
      acc[a][b] = (floatx4){0.f, 0.f, 0.f, 0.f};

  for (int k0 = 0; k0 < Kp; k0 += 32) {
    gl2lds16(gA0 + k0, lA0);
    gl2lds16(gA1 + k0, lA1);
    gl2lds16(gB0 + k0, lB0);
    gl2lds16(gB1 + k0, lB1);
    __syncthreads();
    bf16x8 af[4], bfr[4];
    #pragma unroll
    for (int t = 0; t < 4; t++) {
      int ra = wm * 64 + t * 16 + l15;
      int rb = wn * 64 + t * 16 + l15;
      af[t]  = *(const bf16x8*)&As[(ra * 4 + (quad ^ ((ra >> 1) & 3))) * 8];
      bfr[t] = *(const bf16x8*)&Bs[(rb * 4 + (quad ^ ((rb >> 1) & 3))) * 8];
    }
    #pragma unroll
    for (int tm = 0; tm < 4; tm++)
      #pragma unroll
      for (int tn = 0; tn < 4; tn++)
        acc[tm][tn] = __builtin_amdgcn_mfma_f32_16x16x32_bf16(af[tm], bfr[tn], acc[tm][tn], 0, 0, 0);
    __syncthreads();
  }

  #pragma unroll
  for (int tm = 0; tm < 4; tm++) {
    int row = m0 + wm * 64 + tm * 16 + quad * 4;
    #pragma unroll
    for (int tn = 0; tn < 4; tn++) {
      int col = n0 + wn * 64 + tn * 16 + l15;
      if (col < N) {
        float bb = bias ? bias[col] : 0.f;
        #pragma unroll
        for (int r = 0; r < 4; r++) {
          if (row + r < M) {
            float v = acc[tm][tn][r] + bb;
            if (OUT_BF16) ((ushort_t*)Cv)[(size_t)(row + r) * ldc + col] = f2bf(v);
            else          ((float*)Cv)[(size_t)(row + r) * ldc + col] = v;
          }
        }
      }
    }
  }
}

// ---------------------------------------------------------------- fused GRU GEMM
// K-loop identical to gemm128 on gate-packed B (col = 4*c+gate). Epilogue is
// wave-private: each wave transposes its 64x64 acc subtile through its own
// 8448 B LDS region (stride-33 transposed layout -> conflict-free), in two
// 32-row chunks. No __syncthreads after the k-loop; 33 KB LDS total.
__global__ __launch_bounds__(256) void gemm_gru(
    const ushort_t* __restrict__ A, int lda, const ushort_t* __restrict__ Bt,
    ushort_t* __restrict__ h, int M, int Kp, const float* __restrict__ gb) {
  __shared__ alignas(16) char smem[4 * 8448];   // 33792 B
  ushort_t* As = (ushort_t*)smem;               // 8 KB (k-loop only)
  ushort_t* Bs = (ushort_t*)(smem + 8192);      // 8 KB (k-loop only)
  const int tid = threadIdx.x;
  const int m0 = blockIdx.x * 128;
  const int n0 = blockIdx.y * 128;
  const int lane = tid & 63;
  const int wv = tid >> 6;
  const int wm = wv & 1;
  const int wn = wv >> 1;
  const int quad = lane >> 4;
  const int l15 = lane & 15;

  const int s0i = wv * 128 + lane;
  const int s1i = s0i + 64;
  const int r0 = s0i >> 2, c0 = (s0i & 3) ^ ((r0 >> 1) & 3);
  const int r1 = s1i >> 2, c1 = (s1i & 3) ^ ((r1 >> 1) & 3);
  int ar0 = m0 + r0; if (ar0 >= M) ar0 = M - 1;
  int ar1 = m0 + r1; if (ar1 >= M) ar1 = M - 1;
  const ushort_t* gA0 = A + (size_t)ar0 * lda + c0 * 8;
  const ushort_t* gA1 = A + (size_t)ar1 * lda + c1 * 8;
  const ushort_t* gB0 = Bt + (size_t)(n0 + r0) * Kp + c0 * 8;
  const ushort_t* gB1 = Bt + (size_t)(n0 + r1) * Kp + c1 * 8;
  ushort_t* lA0 = &As[(size_t)(wv * 128) * 8];
  ushort_t* lA1 = &As[(size_t)(wv * 128 + 64) * 8];
  ushort_t* lB0 = &Bs[(size_t)(wv * 128) * 8];
  ushort_t* lB1 = &Bs[(size_t)(wv * 128 + 64) * 8];

  floatx4 acc[4][4];
  #pragma unroll
  for (int a = 0; a < 4; a++)
    #pragma unroll
    for (int b = 0; b < 4; b++)
      acc[a][b] = (floatx4){0.f, 0.f, 0.f, 0.f};

  for (int k0 = 0; k0 < Kp; k0 += 32) {
    gl2lds16(gA0 + k0, lA0);
    gl2lds16(gA1 + k0, lA1);
    gl2lds16(gB0 + k0, lB0);
    gl2lds16(gB1 + k0, lB1);
    __syncthreads();
    bf16x8 af[4], bfr[4];
    #pragma unroll
    for (int t = 0; t < 4; t++) {
      int ra = wm * 64 + t * 16 + l15;
      int rb = wn * 64 + t * 16 + l15;
      af[t]  = *(const bf16x8*)&As[(ra * 4 + (quad ^ ((ra >> 1) & 3))) * 8];
      bfr[t] = *(const bf16x8*)&Bs[(rb * 4 + (quad ^ ((rb >> 1) & 3))) * 8];
    }
    #pragma unroll
    for (int tm = 0; tm < 4; tm++)
      #pragma unroll
      for (int tn = 0; tn < 4; tn++)
        acc[tm][tn] = __builtin_amdgcn_mfma_f32_16x16x32_bf16(af[tm], bfr[tn], acc[tm][tn], 0, 0, 0);
    __syncthreads();   // last one also guarantees staging LDS is dead for all waves
  }

  // wave-private epilogue
  float* swC = (float*)(smem + (size_t)wv * 8448);   // [64 cols][stride 33]
  const int chbase = blockIdx.y * 32 + wn * 16;      // wave's channel base
  const float* rbv = gb;
  const float* zbv = gb + 200;
  const float* ibv = gb + 400;
  const float* hbv = gb + 600;

  #pragma unroll
  for (int chunk = 0; chunk < 2; chunk++) {
    // store 32 rows x 64 cols transposed: swC[cl*33 + rl]
    #pragma unroll
    for (int tmh = 0; tmh < 2; tmh++) {
      int tm = chunk * 2 + tmh;
      int rl = tmh * 16 + quad * 4;
      #pragma unroll
      for (int tn = 0; tn < 4; tn++) {
        int cl = tn * 16 + l15;
        #pragma unroll
        for (int r = 0; r < 4; r++)
          swC[cl * 33 + rl + r] = acc[tm][tn][r];
      }
    }
    // compute: 512 tasks = 32 rows x 16 channels, 8 per lane
    #pragma unroll
    for (int it = 0; it < 8; it++) {
      int task = it * 64 + lane;
      int rl = task >> 4;           // 0..31
      int c  = task & 15;           // wave-local channel
      int grow = m0 + wm * 64 + chunk * 32 + rl;
      int cglob = chbase + c;
      if (grow < M && cglob < 200) {
        float Sr = bf2f(f2bf(swC[(4 * c + 0) * 33 + rl]));
        float Sz = bf2f(f2bf(swC[(4 * c + 1) * 33 + rl]));
        float Si = bf2f(f2bf(swC[(4 * c + 2) * 33 + rl]));
        float Sh = bf2f(f2bf(swC[(4 * c + 3) * 33 + rl]));
        float r_ = 1.f / (1.f + expf(-(Sr + rbv[cglob])));
        float z_ = 1.f / (1.f + expf(-(Sz + zbv[cglob])));
        float n_ = tanhf(Si + ibv[cglob] + r_ * (Sh + hbv[cglob]));
        float ho = bf2f(h[(size_t)grow * 200 + cglob]);
        h[(size_t)grow * 200 + cglob] = f2bf((1.f - z_) * n_ + z_ * ho);
      }
    }
  }
}

__global__ void bias_kernel(const void* __restrict__ b, const int* __restrict__ dflag,
                            float* __restrict__ out, int n) {
  const int f32 = *dflag;
  int i = blockIdx.x * 256 + threadIdx.x;
  if (i < n) out[i] = inval(b, i, f32);
}

// ---------------------------------------------------------------- BN stats + pool
__global__ void stats_kernel(const float* __restrict__ X, int Lrows, int C,
                             float* __restrict__ sums, float* __restrict__ sumsq) {
  int r0 = blockIdx.x * 64;
  int rend = r0 + 64; if (rend > Lrows) rend = Lrows;
  for (int c = threadIdx.x; c < C; c += 256) {
    float s = 0.f, ss = 0.f;
    for (int r = r0; r < rend; r++) {
      float v = X[(size_t)r * C + c];
      s += v; ss += v * v;
    }
    atomicAdd(&sums[c], s);
    atomicAdd(&sumsq[c], ss);
  }
}

__global__ void bnpool_kernel(const float* __restrict__ X, int Lin, int C, int kk, int ss,
                              int Lp, const float* __restrict__ sums,
                              const float* __restrict__ sumsq,
                              const void* __restrict__ g, const void* __restrict__ b,
                              const int* __restrict__ dflag, ushort_t* __restrict__ out) {
  const int f32 = *dflag;
  int i = blockIdx.x * 256 + threadIdx.x;
  if (i >= Lp * C) return;
  int p = i / C, c = i % C;
  float inv = 1.f / (float)Lin;
  float mu = sums[c] * inv;
  float var = sumsq[c] * inv - mu * mu; if (var < 0.f) var = 0.f;
  float scale = inval(g, c, f32) * rsqrtf(var + 1e-5f);
  float shift = inval(b, c, f32) - mu * scale;
  float m = -1e30f;
  int base = p * ss;
  for (int r = 0; r < kk; r++) {
    float v = X[(size_t)(base + r) * C + c] * scale + shift;
    if (v > m) m = v;
  }
  if (m < 0.f) m = 0.f;
  out[(size_t)p * C + c] = f2bf(m);
}

// ---------------------------------------------------------------- head (atomic-free)
__global__ __launch_bounds__(256) void final_kernel(
    const ushort_t* __restrict__ Y2, const ushort_t* __restrict__ Z2,
    const void* __restrict__ wy, const void* __restrict__ by,
    const void* __restrict__ wz, const void* __restrict__ bz,
    const int* __restrict__ dflag, float* __restrict__ pacc) {
  const int f32 = *dflag;
  __shared__ float bl[8];
  int g = threadIdx.x >> 6;
  int lane = threadIdx.x & 63;
  int row = blockIdx.x * 4 + g;
  float y0 = 0.f, y1 = 0.f, z0 = 0.f, z1 = 0.f;
  if (row < 12497) {
    for (int c = lane; c < 200; c += 64) {
      float v = bf2f(Y2[(size_t)row * 200 + c]);
      y0 += v * inval(wy, c, f32);
      y1 += v * inval(wy, 200 + c, f32);
    }
    for (int c = lane; c < 300; c += 64) {
      float v = bf2f(Z2[(size_t)row * 300 + c]);
      z0 += v * inval(wz, c, f32);
      z1 += v * inval(wz, 300 + c, f32);
    }
  }
  for (int off = 32; off > 0; off >>= 1) {
    y0 += __shfl_down(y0, off);
    y1 += __shfl_down(y1, off);
    z0 += __shfl_down(z0, off);
    z1 += __shfl_down(z1, off);
  }
  if (lane == 0) {
    float p0 = 0.f, p1 = 0.f;
    if (row < 12497) {
      p0 = (y0 + inval(by, 0, f32)) * (z0 + inval(bz, 0, f32));
      p1 = (y1 + inval(by, 1, f32)) * (z1 + inval(bz, 1, f32));
    }
    bl[g * 2] = p0; bl[g * 2 + 1] = p1;
  }
  __syncthreads();
  if (threadIdx.x == 0) {
    pacc[(size_t)blockIdx.x * 2]     = bl[0] + bl[2] + bl[4] + bl[6];
    pacc[(size_t)blockIdx.x * 2 + 1] = bl[1] + bl[3] + bl[5] + bl[7];
  }
}

__global__ __launch_bounds__(256) void finalize_kernel(
    const float* __restrict__ pacc, int nblk, const int* __restrict__ dflag,
    void* __restrict__ out) {
  const int f32 = *dflag;
  __shared__ float red[2][4];
  int t = threadIdx.x;
  float s0 = 0.f, s1 = 0.f;
  for (int i = t; i < nblk; i += 256) { s0 += pacc[2 * i]; s1 += pacc[2 * i + 1]; }
  for (int off = 32; off; off >>= 1) { s0 += __shfl_down(s0, off); s1 += __shfl_down(s1, off); }
  int w = t >> 6;
  if ((t & 63) == 0) { red[0][w] = s0; red[1][w] = s1; }
  __syncthreads();
  if (t == 0) {
    float a0 = (red[0][0] + red[0][1] + red[0][2] + red[0][3]) / 12497.f;
    float a1 = (red[1][0] + red[1][1] + red[1][2] + red[1][3]) / 12497.f;
    float mx = fmaxf(a0, a1);
    float e0 = expf(a0 - mx), e1 = expf(a1 - mx);
    float s = e0 + e1;
    if (f32) {
      ((float*)out)[0] = e0 / s;
      ((float*)out)[1] = e1 / s;
    } else {
      ((ushort_t*)out)[0] = f2bf(e0 / s);
      ((ushort_t*)out)[1] = f2bf(e1 / s);
    }
  }
}

// ---------------------------------------------------------------- launch
extern "C" void kernel_launch(void* const* d_in, const int* in_sizes, int n_in,
                              void* d_out, int out_size, void* d_ws, size_t ws_size,
                              hipStream_t stream) {
  const void* x        = d_in[0];
  const int*  edge     = (const int*)d_in[1];
  const void* ggnn_w   = d_in[2];
  const void* gru_wih  = d_in[3];
  const void* gru_whh  = d_in[4];
  const void* gru_bih  = d_in[5];
  const void* gru_bhh  = d_in[6];
  const void* conv1_w  = d_in[7];
  const void* conv1_b  = d_in[8];
  const void* conv2_w  = d_in[9];
  const void* conv2_b  = d_in[10];
  const void* conv1c_w = d_in[11];
  const void* conv1c_b = d_in[12];
  const void* conv2c_w = d_in[13];
  const void* conv2c_b = d_in[14];
  const void* bn_g     = d_in[15];
  const void* bn_b     = d_in[16];
  const void* bnc_g    = d_in[17];
  const void* bnc_b    = d_in[18];
  const void* mlpy_w   = d_in[19];
  const void* mlpy_b   = d_in[20];
  const void* mlpz_w   = d_in[21];
  const void* mlpz_b   = d_in[22];
  const int* srcv = edge;
  const int* dstv = edge + NEDGES;

  // ---- workspace layout (aliased; total ~177 MB) ----
  char* p = (char*)d_ws;
  auto alloc = [&](size_t bytes) -> char* {
    char* r = p; p += (bytes + 255) & ~(size_t)255; return r;
  };
  ushort_t* h    = (ushort_t*)alloc(((size_t)NNODES * FOUT + 64) * 2);
  ushort_t* Ag   = (ushort_t*)alloc(((size_t)NNODES * 400 + 64) * 2);
  ushort_t* cc   = Ag;  // cc[N,300] built AFTER GRU loop, Ag then dead
  char*     R    = alloc((size_t)98 * 1000 * 1000);
  float*    C1   = (float*)R;
  float*    C2   = (float*)R;
  float*    C1c  = (float*)R;
  float*    C2c  = (float*)R;
  ushort_t* pooled1 = (ushort_t*)(R + 60000000);
  ushort_t* pooledc = (ushort_t*)(R + 70000000);
  ushort_t* Y2      = (ushort_t*)(R + 85000000);
  ushort_t* Z2      = (ushort_t*)(R + 90000000);
  ushort_t* BtG  = (ushort_t*)alloc((size_t)8 * 896 * 416 * 2);
  ushort_t* Bt1  = (ushort_t*)alloc((size_t)256 * 800 * 2);
  ushort_t* Bt2  = (ushort_t*)alloc((size_t)256 * 416 * 2);
  ushort_t* Bt1c = (ushort_t*)alloc((size_t)384 * 1216 * 2);
  ushort_t* Bt2c = (ushort_t*)alloc((size_t)384 * 608 * 2);
  ushort_t* gwp  = (ushort_t*)alloc((size_t)1600 * 224 * 2);
  ushort_t* wihp = (ushort_t*)alloc((size_t)640 * 224 * 2);
  float*    Wp   = (float*)alloc((size_t)1600 * 600 * 4);
  int*   csr_src = (int*)alloc((size_t)NEDGES * 4);
  int*   row_ptr = (int*)alloc((size_t)(NNODES + 1) * 4);
  int*   cursor  = (int*)alloc((size_t)NNODES * 4);
  int*   cnt     = (int*)alloc((size_t)NNODES * 4);
  int*   bsum    = (int*)alloc((size_t)(NSCANB + 4) * 4);
  int*   boff    = (int*)alloc((size_t)(NSCANB + 4) * 4);
  float* pacc    = (float*)alloc((size_t)3125 * 2 * 4);
  float* sb      = (float*)alloc((size_t)4300 * 4);
  float *s1 = sb, *ss1 = sb + 200, *s2 = sb + 400, *ss2 = sb + 600;
  float *sc1 = sb + 800, *ssc1 = sb + 1100, *sc2 = sb + 1400, *ssc2 = sb + 1700;
  int*   dflag = (int*)(sb + 2002);
  float* b1f   = sb + 2010;
  float* b2f   = sb + 2210;
  float* b1cf  = sb + 2410;
  float* b2cf  = sb + 2710;
  float* gb    = sb + 3100;   // 800 fp32 gru bias combos

  size_t required = (size_t)(p - (char*)d_ws);
  if (required > ws_size) {
    sentinel_kernel<<<1, 64, 0, stream>>>((ushort_t*)d_out);
    return;
  }

  probe_kernel<<<1, 64, 0, stream>>>(x, dflag);
  zero_kernel<<<(NNODES + 255) / 256, 256, 0, stream>>>(cnt, NNODES);
  zero_kernel<<<(2000 + 255) / 256, 256, 0, stream>>>((int*)sb, 2000);
  hinit_kernel<<<(NNODES * FOUT + 255) / 256, 256, 0, stream>>>(x, dflag, h);

  // wp = ggnn_w @ wih^T as one MFMA GEMM
  pada_kernel<<<(1600 * 224 + 255) / 256, 256, 0, stream>>>(ggnn_w, dflag, gwp, 200, 224, 1600, 1600 * 224);
  pada_kernel<<<(640 * 224 + 255) / 256, 256, 0, stream>>>(gru_wih, dflag, wihp, 200, 224, 600, 640 * 224);
  gemm128<false><<<dim3(13, 5), 256, 0, stream>>>(gwp, 224, wihp, Wp, 600, 1600, 600, 224, nullptr);

  btgruq_kernel<<<(NSTEPS * 896 * 416 + 255) / 256, 256, 0, stream>>>(Wp, gru_whh, dflag, BtG);
  gbias_kernel<<<1, 256, 0, stream>>>(gru_bih, gru_bhh, dflag, gb);
  btconv_kernel<<<(256 * 800 + 255) / 256, 256, 0, stream>>>(conv1_w, dflag, Bt1, 200, 4, 800, 200, 256 * 800);
  btconv_kernel<<<(256 * 416 + 255) / 256, 256, 0, stream>>>(conv2_w, dflag, Bt2, 200, 2, 416, 200, 256 * 416);
  btconv_kernel<<<(384 * 1216 + 255) / 256, 256, 0, stream>>>(conv1c_w, dflag, Bt1c, 300, 4, 1216, 300, 384 * 1216);
  btconv_kernel<<<(384 * 608 + 255) / 256, 256, 0, stream>>>(conv2c_w, dflag, Bt2c, 300, 2, 608, 300, 384 * 608);
  bias_kernel<<<1, 256, 0, stream>>>(conv1_b, dflag, b1f, 200);
  bias_kernel<<<1, 256, 0, stream>>>(conv2_b, dflag, b2f, 200);
  bias_kernel<<<2, 256, 0, stream>>>(conv1c_b, dflag, b1cf, 300);
  bias_kernel<<<2, 256, 0, stream>>>(conv2c_b, dflag, b2cf, 300);

  hist_kernel<<<(NEDGES + 255) / 256, 256, 0, stream>>>(dstv, cnt);
  bsum_kernel<<<NSCANB, 256, 0, stream>>>(cnt, bsum);
  bscan_kernel<<<1, 256, 0, stream>>>(bsum, boff);
  rowptr_kernel<<<NSCANB, 256, 0, stream>>>(cnt, boff, row_ptr, cursor);
  fill_kernel<<<(NEDGES + 255) / 256, 256, 0, stream>>>(srcv, dstv, cursor, csr_src);

  for (int l = 0; l < NSTEPS; l++) {
    gather_kernel<<<(NNODES + 3) / 4, 256, 0, stream>>>(row_ptr, csr_src, h, Ag);
    gemm_gru<<<dim3(391, 7), 256, 0, stream>>>(Ag, 400, BtG + (size_t)l * 896 * 416,
                                               h, NNODES, 416, gb);
  }
  ccat_kernel<<<(NNODES * FCAT + 255) / 256, 256, 0, stream>>>(h, x, dflag, cc);

  // branch y
  gemm128<false><<<dim3(391, 2), 256, 0, stream>>>(h, 200, Bt1, C1, 200, 49997, 200, 800, b1f);
  stats_kernel<<<(49997 + 63) / 64, 256, 0, stream>>>(C1, 49997, 200, s1, ss1);
  bnpool_kernel<<<(24997 * 200 + 255) / 256, 256, 0, stream>>>(C1, 49997, 200, 4, 2, 24997,
                                                               s1, ss1, bn_g, bn_b, dflag, pooled1);
  gemm128<false><<<dim3(196, 2), 256, 0, stream>>>(pooled1, 200, Bt2, C2, 200, 24996, 200, 416, b2f);
  stats_kernel<<<(24996 + 63) / 64, 256, 0, stream>>>(C2, 24996, 200, s2, ss2);
  bnpool_kernel<<<(12497 * 200 + 255) / 256, 256, 0, stream>>>(C2, 24996, 200, 3, 2, 12497,
                                                               s2, ss2, bn_g, bn_b, dflag, Y2);
  // branch z
  gemm128<false><<<dim3(391, 3), 256, 0, stream>>>(cc, 300, Bt1c, C1c, 300, 49997, 300, 1216, b1cf);
  stats_kernel<<<(49997 + 63) / 64, 256, 0, stream>>>(C1c, 49997, 300, sc1, ssc1);
  bnpool_kernel<<<(24997 * 300 + 255) / 256, 256, 0, stream>>>(C1c, 49997, 300, 4, 2, 24997,
                                                               sc1, ssc1, bnc_g, bnc_b, dflag, pooledc);
  gemm128<false><<<dim3(196, 3), 256, 0, stream>>>(pooledc, 300, Bt2c, C2c, 300, 24996, 300, 608, b2cf);
  stats_kernel<<<(24996 + 63) / 64, 256, 0, stream>>>(C2c, 24996, 300, sc2, ssc2);
  bnpool_kernel<<<(12497 * 300 + 255) / 256, 256, 0, stream>>>(C2c, 24996, 300, 3, 2, 12497,
                                                               sc2, ssc2, bnc_g, bnc_b, dflag, Z2);

  final_kernel<<<3125, 256, 0, stream>>>(Y2, Z2, mlpy_w, mlpy_b, mlpz_w, mlpz_b, dflag, pacc);
  finalize_kernel<<<1, 256, 0, stream>>>(pacc, 3125, dflag, d_out);
}

// Round 10
// 2059.708 us; speedup vs baseline: 1.2527x; 1.0183x over previous
//
#include <hip/hip_runtime.h>
#include <cstdint>
#include <cstddef>

#define NNODES 50000
#define NEDGES 800000
#define FIN    100
#define FOUT   200
#define FCAT   300
#define NSTEPS 8
#define NSCANB 196

typedef unsigned short ushort_t;
typedef __bf16 bf16x8 __attribute__((ext_vector_type(8)));
typedef float  floatx4 __attribute__((ext_vector_type(4)));

__device__ __forceinline__ float bf2f(ushort_t u) {
  union { unsigned u; float f; } c; c.u = ((unsigned)u) << 16; return c.f;
}
__device__ __forceinline__ ushort_t f2bf(float f) {
  union { float f; unsigned u; } c; c.f = f;
  unsigned r = c.u + 0x7FFFu + ((c.u >> 16) & 1u);
  return (ushort_t)(r >> 16);
}
__device__ __forceinline__ float inval(const void* p, size_t i, int f32) {
  return f32 ? ((const float*)p)[i] : bf2f(((const ushort_t*)p)[i]);
}

// async global->LDS 16B
__device__ __forceinline__ void gl2lds16(const ushort_t* g, ushort_t* l) {
  typedef const __attribute__((address_space(1))) unsigned int gu32;
  typedef __attribute__((address_space(3))) unsigned int lu32;
  __builtin_amdgcn_global_load_lds((gu32*)(uintptr_t)g, (lu32*)(uintptr_t)l, 16, 0, 0);
}

// ---------------------------------------------------------------- dtype probe
__global__ void probe_kernel(const void* xraw, int* flag) {
  const ushort_t* u = (const ushort_t*)xraw;
  int t = threadIdx.x;
  int bad = 0;
  for (int i = t; i < 2048; i += 64) {
    int e = (u[2 * i] >> 7) & 0xFF;
    if (e >= 0x88) bad++;
  }
  for (int off = 32; off; off >>= 1) bad += __shfl_down(bad, off);
  if (t == 0) *flag = (bad > 128) ? 1 : 0;
}

// ---------------------------------------------------------------- utility
__global__ void zero_kernel(int* p, int n) {
  int i = blockIdx.x * 256 + threadIdx.x;
  if (i < n) p[i] = 0;
}

__global__ void sentinel_kernel(ushort_t* out) {
  if (threadIdx.x == 0 && blockIdx.x == 0) {
    out[0] = f2bf(0.123f);
    out[1] = f2bf(0.877f);
  }
}

__global__ void hinit_kernel(const void* __restrict__ x, const int* __restrict__ dflag,
                             ushort_t* __restrict__ h) {
  const int f32 = *dflag;
  int i = blockIdx.x * 256 + threadIdx.x;
  if (i >= NNODES * FOUT) return;
  int n = i / FOUT, c = i % FOUT;
  h[i] = (c < FIN) ? f2bf(inval(x, (size_t)n * FIN + c, f32)) : (ushort_t)0;
}

__global__ void ccat_kernel(const ushort_t* __restrict__ h, const void* __restrict__ x,
                            const int* __restrict__ dflag, ushort_t* __restrict__ cc) {
  const int f32 = *dflag;
  int i = blockIdx.x * 256 + threadIdx.x;
  if (i >= NNODES * FCAT) return;
  int n = i / FCAT, c = i % FCAT;
  cc[i] = (c < FOUT) ? h[n * FOUT + c] : f2bf(inval(x, (size_t)n * FIN + (c - FOUT), f32));
}

// ---------------------------------------------------------------- CSR build
__global__ void hist_kernel(const int* __restrict__ dst, int* __restrict__ cnt) {
  int e = blockIdx.x * 256 + threadIdx.x;
  if (e < NEDGES) atomicAdd(&cnt[dst[e]], 1);
}

__global__ void bsum_kernel(const int* __restrict__ cnt, int* __restrict__ bsum) {
  __shared__ int red[4];
  int i = blockIdx.x * 256 + threadIdx.x;
  int v = (i < NNODES) ? cnt[i] : 0;
  for (int off = 32; off; off >>= 1) v += __shfl_down(v, off);
  int w = threadIdx.x >> 6;
  if ((threadIdx.x & 63) == 0) red[w] = v;
  __syncthreads();
  if (threadIdx.x == 0) bsum[blockIdx.x] = red[0] + red[1] + red[2] + red[3];
}

__global__ void bscan_kernel(const int* __restrict__ bsum, int* __restrict__ boff) {
  __shared__ int s[256];
  int t = threadIdx.x;
  int v = (t < NSCANB) ? bsum[t] : 0;
  s[t] = v;
  __syncthreads();
  for (int off = 1; off < 256; off <<= 1) {
    int u = (t >= off) ? s[t - off] : 0;
    __syncthreads();
    s[t] += u;
    __syncthreads();
  }
  if (t < NSCANB) boff[t] = s[t] - v;   // exclusive
}

__global__ void rowptr_kernel(const int* __restrict__ cnt, const int* __restrict__ boff,
                              int* __restrict__ row_ptr, int* __restrict__ cursor) {
  __shared__ int s[256];
  int t = threadIdx.x;
  int i = blockIdx.x * 256 + t;
  int v = (i < NNODES) ? cnt[i] : 0;
  s[t] = v;
  __syncthreads();
  for (int off = 1; off < 256; off <<= 1) {
    int u = (t >= off) ? s[t - off] : 0;
    __syncthreads();
    s[t] += u;
    __syncthreads();
  }
  if (i < NNODES) {
    int e = boff[blockIdx.x] + s[t] - v;
    row_ptr[i] = e; cursor[i] = e;
    if (i == NNODES - 1) row_ptr[NNODES] = boff[blockIdx.x] + s[t];
  }
}

__global__ void fill_kernel(const int* __restrict__ srcv, const int* __restrict__ dstv,
                            int* __restrict__ cursor, int* __restrict__ csr_src) {
  int e = blockIdx.x * 256 + threadIdx.x;
  if (e >= NEDGES) return;
  int p = atomicAdd(&cursor[dstv[e]], 1);
  csr_src[p] = srcv[e];
}

// agg[n] = sum over in-edges of h[src]; writes A = [agg | h] row (400 wide, bf16)
__global__ __launch_bounds__(256) void gather_kernel(
    const int* __restrict__ row_ptr, const int* __restrict__ csr_src,
    const ushort_t* __restrict__ h, ushort_t* __restrict__ Ag) {
  int g = threadIdx.x >> 6;
  int lane = threadIdx.x & 63;
  int n = blockIdx.x * 4 + g;
  if (n >= NNODES) return;
  if (lane >= 50) return;
  int s0 = row_ptr[n], s1 = row_ptr[n + 1];
  float a0 = 0.f, a1 = 0.f, a2 = 0.f, a3 = 0.f;
  int i = s0;
  for (; i + 3 < s1; i += 4) {
    int sa = csr_src[i], sb = csr_src[i + 1], sc = csr_src[i + 2], sd = csr_src[i + 3];
    ushort4 va = *(const ushort4*)&h[(size_t)sa * FOUT + lane * 4];
    ushort4 vb = *(const ushort4*)&h[(size_t)sb * FOUT + lane * 4];
    ushort4 vc = *(const ushort4*)&h[(size_t)sc * FOUT + lane * 4];
    ushort4 vd = *(const ushort4*)&h[(size_t)sd * FOUT + lane * 4];
    a0 += (bf2f(va.x) + bf2f(vb.x)) + (bf2f(vc.x) + bf2f(vd.x));
    a1 += (bf2f(va.y) + bf2f(vb.y)) + (bf2f(vc.y) + bf2f(vd.y));
    a2 += (bf2f(va.z) + bf2f(vb.z)) + (bf2f(vc.z) + bf2f(vd.z));
    a3 += (bf2f(va.w) + bf2f(vb.w)) + (bf2f(vc.w) + bf2f(vd.w));
  }
  for (; i < s1; i++) {
    int sa = csr_src[i];
    ushort4 va = *(const ushort4*)&h[(size_t)sa * FOUT + lane * 4];
    a0 += bf2f(va.x); a1 += bf2f(va.y); a2 += bf2f(va.z); a3 += bf2f(va.w);
  }
  ushort4 o;
  o.x = f2bf(a0); o.y = f2bf(a1); o.z = f2bf(a2); o.w = f2bf(a3);
  *(ushort4*)&Ag[(size_t)n * 400 + lane * 4] = o;
  *(ushort4*)&Ag[(size_t)n * 400 + FOUT + lane * 4] =
      *(const ushort4*)&h[(size_t)n * FOUT + lane * 4];
}

// ---------------------------------------------------------------- padded bf16 copies
__global__ void pada_kernel(const void* __restrict__ src, const int* __restrict__ dflag,
                            ushort_t* __restrict__ dst, int K, int Kp, int rowsValid,
                            int total) {
  const int f32 = *dflag;
  int i = blockIdx.x * 256 + threadIdx.x;
  if (i >= total) return;
  int r = i / Kp, k = i % Kp;
  float v = (r < rowsValid && k < K) ? inval(src, (size_t)r * K + k, f32) : 0.f;
  dst[i] = f2bf(v);
}

// Bt_gru packed: [8][896 rows][416 k], row nn = 4*c + gate (r,z,ic,hc), c<200 valid.
__global__ void btgruq_kernel(const float* __restrict__ Wp, const void* __restrict__ whh,
                              const int* __restrict__ dflag, ushort_t* __restrict__ Bt) {
  const int f32 = *dflag;
  int i = blockIdx.x * 256 + threadIdx.x;
  if (i >= NSTEPS * 896 * 416) return;
  int l = i / (896 * 416);
  int rem = i % (896 * 416);
  int nn = rem / 416;
  int k = rem % 416;
  int c = nn >> 2, g = nn & 3;
  float v = 0.f;
  if (c < 200) {
    if (k < 200) {
      const float* wrow = Wp + ((size_t)l * 200 + k) * 600;
      if (g == 0) v = wrow[c];
      else if (g == 1) v = wrow[200 + c];
      else if (g == 2) v = wrow[400 + c];
    } else if (k < 400) {
      int kh = k - 200;
      if (g == 0) v = inval(whh, (size_t)c * 200 + kh, f32);
      else if (g == 1) v = inval(whh, (size_t)(200 + c) * 200 + kh, f32);
      else if (g == 3) v = inval(whh, (size_t)(400 + c) * 200 + kh, f32);
    }
  }
  Bt[((size_t)nn + 896 * (size_t)l) * 416 + k] = f2bf(v);
}

__global__ void btconv_kernel(const void* __restrict__ w, const int* __restrict__ dflag,
                              ushort_t* __restrict__ Bt, int C, int KT, int Kp,
                              int O, int total) {
  const int f32 = *dflag;
  int i = blockIdx.x * 256 + threadIdx.x;
  if (i >= total) return;
  int o = i / Kp, k = i % Kp;
  float v = 0.f;
  int K = C * KT;
  if (k < K && o < O) {
    int ktap = k / C; int ci = k % C;
    v = inval(w, ((size_t)o * C + ci) * KT + ktap, f32);
  }
  Bt[i] = f2bf(v);
}

// gru bias precombine
__global__ void gbias_kernel(const void* __restrict__ bih, const void* __restrict__ bhh,
                             const int* __restrict__ dflag, float* __restrict__ gb) {
  const int f32 = *dflag;
  int c = blockIdx.x * 256 + threadIdx.x;
  if (c >= 200) return;
  gb[c]       = inval(bih, c, f32)       + inval(bhh, c, f32);
  gb[200 + c] = inval(bih, 200 + c, f32) + inval(bhh, 200 + c, f32);
  gb[400 + c] = inval(bih, 400 + c, f32);
  gb[600 + c] = inval(bhh, 400 + c, f32);
}

// ---------------------------------------------------------------- GEMM (MFMA, 128x128)
template <bool OUT_BF16>
__global__ __launch_bounds__(256) void gemm128(
    const ushort_t* __restrict__ A, int lda, const ushort_t* __restrict__ Bt,
    void* __restrict__ Cv, int ldc, int M, int N, int Kp,
    const float* __restrict__ bias) {
  __shared__ alignas(16) ushort_t As[128 * 32];
  __shared__ alignas(16) ushort_t Bs[128 * 32];
  const int tid = threadIdx.x;
  const int m0 = blockIdx.x * 128;
  const int n0 = blockIdx.y * 128;
  const int lane = tid & 63;
  const int wv = tid >> 6;
  const int wm = wv & 1;
  const int wn = wv >> 1;
  const int quad = lane >> 4;
  const int l15 = lane & 15;

  const int s0i = wv * 128 + lane;
  const int s1i = s0i + 64;
  const int r0 = s0i >> 2, c0 = (s0i & 3) ^ ((r0 >> 1) & 3);
  const int r1 = s1i >> 2, c1 = (s1i & 3) ^ ((r1 >> 1) & 3);
  int ar0 = m0 + r0; if (ar0 >= M) ar0 = M - 1;
  int ar1 = m0 + r1; if (ar1 >= M) ar1 = M - 1;
  const ushort_t* gA0 = A + (size_t)ar0 * lda + c0 * 8;
  const ushort_t* gA1 = A + (size_t)ar1 * lda + c1 * 8;
  const ushort_t* gB0 = Bt + (size_t)(n0 + r0) * Kp + c0 * 8;
  const ushort_t* gB1 = Bt + (size_t)(n0 + r1) * Kp + c1 * 8;
  ushort_t* lA0 = &As[(size_t)(wv * 128) * 8];
  ushort_t* lA1 = &As[(size_t)(wv * 128 + 64) * 8];
  ushort_t* lB0 = &Bs[(size_t)(wv * 128) * 8];
  ushort_t* lB1 = &Bs[(size_t)(wv * 128 + 64) * 8];

  floatx4 acc[4][4];
  #pragma unroll
  for (int a = 0; a < 4; a++)
    #pragma unroll
    for (int b = 0; b < 4; b++)
      acc[a][b] = (floatx4){0.f, 0.f, 0.f, 0.f};

  for (int k0 = 0; k0 < Kp; k0 += 32) {
    gl2lds16(gA0 + k0, lA0);
    gl2lds16(gA1 + k0, lA1);
    gl2lds16(gB0 + k0, lB0);
    gl2lds16(gB1 + k0, lB1);
    __syncthreads();
    bf16x8 af[4], bfr[4];
    #pragma unroll
    for (int t = 0; t < 4; t++) {
      int ra = wm * 64 + t * 16 + l15;
      int rb = wn * 64 + t * 16 + l15;
      af[t]  = *(const bf16x8*)&As[(ra * 4 + (quad ^ ((ra >> 1) & 3))) * 8];
      bfr[t] = *(const bf16x8*)&Bs[(rb * 4 + (quad ^ ((rb >> 1) & 3))) * 8];
    }
    #pragma unroll
    for (int tm = 0; tm < 4; tm++)
      #pragma unroll
      for (int tn = 0; tn < 4; tn++)
        acc[tm][tn] = __builtin_amdgcn_mfma_f32_16x16x32_bf16(af[tm], bfr[tn], acc[tm][tn], 0, 0, 0);
    __syncthreads();
  }

  #pragma unroll
  for (int tm = 0; tm < 4; tm++) {
    int row = m0 + wm * 64 + tm * 16 + quad * 4;
    #pragma unroll
    for (int tn = 0; tn < 4; tn++) {
      int col = n0 + wn * 64 + tn * 16 + l15;
      if (col < N) {
        float bb = bias ? bias[col] : 0.f;
        #pragma unroll
        for (int r = 0; r < 4; r++) {
          if (row + r < M) {
            float v = acc[tm][tn][r] + bb;
            if (OUT_BF16) ((ushort_t*)Cv)[(size_t)(row + r) * ldc + col] = f2bf(v);
            else          ((float*)Cv)[(size_t)(row + r) * ldc + col] = v;
          }
        }
      }
    }
  }
}

// ---------------------------------------------------------------- fused GRU GEMM
// K-loop identical to gemm128 on gate-packed B (col = 4*c+gate). Epilogue is
// fully in-register: for each 16x16 C-tile, the 4 gates of a channel live in
// the 4 lanes of a quad (l15&3 = gate) and the 4 rows in the 4 acc regs; a
// 4-shfl_xor butterfly transposes (reg=row, lane=gate) -> (lane=row, reg=gate),
// then each lane does the GRU math for one (row, channel). No epilogue LDS,
// no barriers, LDS stays 16 KB.
__global__ __launch_bounds__(256) void gemm_gru(
    const ushort_t* __restrict__ A, int lda, const ushort_t* __restrict__ Bt,
    ushort_t* __restrict__ h, int M, int Kp, const float* __restrict__ gb) {
  __shared__ alignas(16) ushort_t As[128 * 32];
  __shared__ alignas(16) ushort_t Bs[128 * 32];
  const int tid = threadIdx.x;
  const int m0 = blockIdx.x * 128;
  const int n0 = blockIdx.y * 128;
  const int lane = tid & 63;
  const int wv = tid >> 6;
  const int wm = wv & 1;
  const int wn = wv >> 1;
  const int quad = lane >> 4;
  const int l15 = lane & 15;

  const int s0i = wv * 128 + lane;
  const int s1i = s0i + 64;
  const int r0 = s0i >> 2, c0 = (s0i & 3) ^ ((r0 >> 1) & 3);
  const int r1 = s1i >> 2, c1 = (s1i & 3) ^ ((r1 >> 1) & 3);
  int ar0 = m0 + r0; if (ar0 >= M) ar0 = M - 1;
  int ar1 = m0 + r1; if (ar1 >= M) ar1 = M - 1;
  const ushort_t* gA0 = A + (size_t)ar0 * lda + c0 * 8;
  const ushort_t* gA1 = A + (size_t)ar1 * lda + c1 * 8;
  const ushort_t* gB0 = Bt + (size_t)(n0 + r0) * Kp + c0 * 8;
  const ushort_t* gB1 = Bt + (size_t)(n0 + r1) * Kp + c1 * 8;
  ushort_t* lA0 = &As[(size_t)(wv * 128) * 8];
  ushort_t* lA1 = &As[(size_t)(wv * 128 + 64) * 8];
  ushort_t* lB0 = &Bs[(size_t)(wv * 128) * 8];
  ushort_t* lB1 = &Bs[(size_t)(wv * 128 + 64) * 8];

  floatx4 acc[4][4];
  #pragma unroll
  for (int a = 0; a < 4; a++)
    #pragma unroll
    for (int b = 0; b < 4; b++)
      acc[a][b] = (floatx4){0.f, 0.f, 0.f, 0.f};

  for (int k0 = 0; k0 < Kp; k0 += 32) {
    gl2lds16(gA0 + k0, lA0);
    gl2lds16(gA1 + k0, lA1);
    gl2lds16(gB0 + k0, lB0);
    gl2lds16(gB1 + k0, lB1);
    __syncthreads();
    bf16x8 af[4], bfr[4];
    #pragma unroll
    for (int t = 0; t < 4; t++) {
      int ra = wm * 64 + t * 16 + l15;
      int rb = wn * 64 + t * 16 + l15;
      af[t]  = *(const bf16x8*)&As[(ra * 4 + (quad ^ ((ra >> 1) & 3))) * 8];
      bfr[t] = *(const bf16x8*)&Bs[(rb * 4 + (quad ^ ((rb >> 1) & 3))) * 8];
    }
    #pragma unroll
    for (int tm = 0; tm < 4; tm++)
      #pragma unroll
      for (int tn = 0; tn < 4; tn++)
        acc[tm][tn] = __builtin_amdgcn_mfma_f32_16x16x32_bf16(af[tm], bfr[tn], acc[tm][tn], 0, 0, 0);
    __syncthreads();
  }

  // in-register epilogue
  const int sb0 = l15 & 1;          // gate bit0 (lane bit0)
  const int sb1 = (l15 >> 1) & 1;   // gate bit1 (lane bit1)
  const int jch = l15 >> 2;         // channel-within-tile
  const int chb = blockIdx.y * 32 + wn * 16;
  #pragma unroll
  for (int tm = 0; tm < 4; tm++) {
    #pragma unroll
    for (int tn = 0; tn < 4; tn++) {
      float v0 = acc[tm][tn][0], v1 = acc[tm][tn][1];
      float v2 = acc[tm][tn][2], v3 = acc[tm][tn][3];
      float t;
      // butterfly transpose over (lane-gate, reg-row)
      t = __shfl_xor(sb0 ? v0 : v1, 1); if (sb0) v0 = t; else v1 = t;
      t = __shfl_xor(sb0 ? v2 : v3, 1); if (sb0) v2 = t; else v3 = t;
      t = __shfl_xor(sb1 ? v0 : v2, 2); if (sb1) v0 = t; else v2 = t;
      t = __shfl_xor(sb1 ? v1 : v3, 2); if (sb1) v1 = t; else v3 = t;
      int row = m0 + wm * 64 + tm * 16 + quad * 4 + (l15 & 3);
      int chan = chb + tn * 4 + jch;
      if (row < M && chan < 200) {
        float Sr = bf2f(f2bf(v0));
        float Sz = bf2f(f2bf(v1));
        float Si = bf2f(f2bf(v2));
        float Sh = bf2f(f2bf(v3));
        float r_ = 1.f / (1.f + expf(-(Sr + gb[chan])));
        float z_ = 1.f / (1.f + expf(-(Sz + gb[200 + chan])));
        float n_ = tanhf(Si + gb[400 + chan] + r_ * (Sh + gb[600 + chan]));
        float ho = bf2f(h[(size_t)row * 200 + chan]);
        h[(size_t)row * 200 + chan] = f2bf((1.f - z_) * n_ + z_ * ho);
      }
    }
  }
}

__global__ void bias_kernel(const void* __restrict__ b, const int* __restrict__ dflag,
                            float* __restrict__ out, int n) {
  const int f32 = *dflag;
  int i = blockIdx.x * 256 + threadIdx.x;
  if (i < n) out[i] = inval(b, i, f32);
}

// ---------------------------------------------------------------- BN stats + pool
__global__ void stats_kernel(const float* __restrict__ X, int Lrows, int C,
                             float* __restrict__ sums, float* __restrict__ sumsq) {
  int r0 = blockIdx.x * 64;
  int rend = r0 + 64; if (rend > Lrows) rend = Lrows;
  for (int c = threadIdx.x; c < C; c += 256) {
    float s = 0.f, ss = 0.f;
    for (int r = r0; r < rend; r++) {
      float v = X[(size_t)r * C + c];
      s += v; ss += v * v;
    }
    atomicAdd(&sums[c], s);
    atomicAdd(&sumsq[c], ss);
  }
}

__global__ void bnpool_kernel(const float* __restrict__ X, int Lin, int C, int kk, int ss,
                              int Lp, const float* __restrict__ sums,
                              const float* __restrict__ sumsq,
                              const void* __restrict__ g, const void* __restrict__ b,
                              const int* __restrict__ dflag, ushort_t* __restrict__ out) {
  const int f32 = *dflag;
  int i = blockIdx.x * 256 + threadIdx.x;
  if (i >= Lp * C) return;
  int p = i / C, c = i % C;
  float inv = 1.f / (float)Lin;
  float mu = sums[c] * inv;
  float var = sumsq[c] * inv - mu * mu; if (var < 0.f) var = 0.f;
  float scale = inval(g, c, f32) * rsqrtf(var + 1e-5f);
  float shift = inval(b, c, f32) - mu * scale;
  float m = -1e30f;
  int base = p * ss;
  for (int r = 0; r < kk; r++) {
    float v = X[(size_t)(base + r) * C + c] * scale + shift;
    if (v > m) m = v;
  }
  if (m < 0.f) m = 0.f;
  out[(size_t)p * C + c] = f2bf(m);
}

// ---------------------------------------------------------------- head (atomic-free)
__global__ __launch_bounds__(256) void final_kernel(
    const ushort_t* __restrict__ Y2, const ushort_t* __restrict__ Z2,
    const void* __restrict__ wy, const void* __restrict__ by,
    const void* __restrict__ wz, const void* __restrict__ bz,
    const int* __restrict__ dflag, float* __restrict__ pacc) {
  const int f32 = *dflag;
  __shared__ float bl[8];
  int g = threadIdx.x >> 6;
  int lane = threadIdx.x & 63;
  int row = blockIdx.x * 4 + g;
  float y0 = 0.f, y1 = 0.f, z0 = 0.f, z1 = 0.f;
  if (row < 12497) {
    for (int c = lane; c < 200; c += 64) {
      float v = bf2f(Y2[(size_t)row * 200 + c]);
      y0 += v * inval(wy, c, f32);
      y1 += v * inval(wy, 200 + c, f32);
    }
    for (int c = lane; c < 300; c += 64) {
      float v = bf2f(Z2[(size_t)row * 300 + c]);
      z0 += v * inval(wz, c, f32);
      z1 += v * inval(wz, 300 + c, f32);
    }
  }
  for (int off = 32; off > 0; off >>= 1) {
    y0 += __shfl_down(y0, off);
    y1 += __shfl_down(y1, off);
    z0 += __shfl_down(z0, off);
    z1 += __shfl_down(z1, off);
  }
  if (lane == 0) {
    float p0 = 0.f, p1 = 0.f;
    if (row < 12497) {
      p0 = (y0 + inval(by, 0, f32)) * (z0 + inval(bz, 0, f32));
      p1 = (y1 + inval(by, 1, f32)) * (z1 + inval(bz, 1, f32));
    }
    bl[g * 2] = p0; bl[g * 2 + 1] = p1;
  }
  __syncthreads();
  if (threadIdx.x == 0) {
    pacc[(size_t)blockIdx.x * 2]     = bl[0] + bl[2] + bl[4] + bl[6];
    pacc[(size_t)blockIdx.x * 2 + 1] = bl[1] + bl[3] + bl[5] + bl[7];
  }
}

__global__ __launch_bounds__(256) void finalize_kernel(
    const float* __restrict__ pacc, int nblk, const int* __restrict__ dflag,
    void* __restrict__ out) {
  const int f32 = *dflag;
  __shared__ float red[2][4];
  int t = threadIdx.x;
  float s0 = 0.f, s1 = 0.f;
  for (int i = t; i < nblk; i += 256) { s0 += pacc[2 * i]; s1 += pacc[2 * i + 1]; }
  for (int off = 32; off; off >>= 1) { s0 += __shfl_down(s0, off); s1 += __shfl_down(s1, off); }
  int w = t >> 6;
  if ((t & 63) == 0) { red[0][w] = s0; red[1][w] = s1; }
  __syncthreads();
  if (t == 0) {
    float a0 = (red[0][0] + red[0][1] + red[0][2] + red[0][3]) / 12497.f;
    float a1 = (red[1][0] + red[1][1] + red[1][2] + red[1][3]) / 12497.f;
    float mx = fmaxf(a0, a1);
    float e0 = expf(a0 - mx), e1 = expf(a1 - mx);
    float s = e0 + e1;
    if (f32) {
      ((float*)out)[0] = e0 / s;
      ((float*)out)[1] = e1 / s;
    } else {
      ((ushort_t*)out)[0] = f2bf(e0 / s);
      ((ushort_t*)out)[1] = f2bf(e1 / s);
    }
  }
}

// ---------------------------------------------------------------- launch
extern "C" void kernel_launch(void* const* d_in, const int* in_sizes, int n_in,
                              void* d_out, int out_size, void* d_ws, size_t ws_size,
                              hipStream_t stream) {
  const void* x        = d_in[0];
  const int*  edge     = (const int*)d_in[1];
  const void* ggnn_w   = d_in[2];
  const void* gru_wih  = d_in[3];
  const void* gru_whh  = d_in[4];
  const void* gru_bih  = d_in[5];
  const void* gru_bhh  = d_in[6];
  const void* conv1_w  = d_in[7];
  const void* conv1_b  = d_in[8];
  const void* conv2_w  = d_in[9];
  const void* conv2_b  = d_in[10];
  const void* conv1c_w = d_in[11];
  const void* conv1c_b = d_in[12];
  const void* conv2c_w = d_in[13];
  const void* conv2c_b = d_in[14];
  const void* bn_g     = d_in[15];
  const void* bn_b     = d_in[16];
  const void* bnc_g    = d_in[17];
  const void* bnc_b    = d_in[18];
  const void* mlpy_w   = d_in[19];
  const void* mlpy_b   = d_in[20];
  const void* mlpz_w   = d_in[21];
  const void* mlpz_b   = d_in[22];
  const int* srcv = edge;
  const int* dstv = edge + NEDGES;

  // ---- workspace layout (aliased; total ~177 MB) ----
  char* p = (char*)d_ws;
  auto alloc = [&](size_t bytes) -> char* {
    char* r = p; p += (bytes + 255) & ~(size_t)255; return r;
  };
  ushort_t* h    = (ushort_t*)alloc(((size_t)NNODES * FOUT + 64) * 2);
  ushort_t* Ag   = (ushort_t*)alloc(((size_t)NNODES * 400 + 64) * 2);
  ushort_t* cc   = Ag;  // cc[N,300] built AFTER GRU loop, Ag then dead
  char*     R    = alloc((size_t)98 * 1000 * 1000);
  float*    C1   = (float*)R;
  float*    C2   = (float*)R;
  float*    C1c  = (float*)R;
  float*    C2c  = (float*)R;
  ushort_t* pooled1 = (ushort_t*)(R + 60000000);
  ushort_t* pooledc = (ushort_t*)(R + 70000000);
  ushort_t* Y2      = (ushort_t*)(R + 85000000);
  ushort_t* Z2      = (ushort_t*)(R + 90000000);
  ushort_t* BtG  = (ushort_t*)alloc((size_t)8 * 896 * 416 * 2);
  ushort_t* Bt1  = (ushort_t*)alloc((size_t)256 * 800 * 2);
  ushort_t* Bt2  = (ushort_t*)alloc((size_t)256 * 416 * 2);
  ushort_t* Bt1c = (ushort_t*)alloc((size_t)384 * 1216 * 2);
  ushort_t* Bt2c = (ushort_t*)alloc((size_t)384 * 608 * 2);
  ushort_t* gwp  = (ushort_t*)alloc((size_t)1600 * 224 * 2);
  ushort_t* wihp = (ushort_t*)alloc((size_t)640 * 224 * 2);
  float*    Wp   = (float*)alloc((size_t)1600 * 600 * 4);
  int*   csr_src = (int*)alloc((size_t)NEDGES * 4);
  int*   row_ptr = (int*)alloc((size_t)(NNODES + 1) * 4);
  int*   cursor  = (int*)alloc((size_t)NNODES * 4);
  int*   cnt     = (int*)alloc((size_t)NNODES * 4);
  int*   bsum    = (int*)alloc((size_t)(NSCANB + 4) * 4);
  int*   boff    = (int*)alloc((size_t)(NSCANB + 4) * 4);
  float* pacc    = (float*)alloc((size_t)3125 * 2 * 4);
  float* sb      = (float*)alloc((size_t)4300 * 4);
  float *s1 = sb, *ss1 = sb + 200, *s2 = sb + 400, *ss2 = sb + 600;
  float *sc1 = sb + 800, *ssc1 = sb + 1100, *sc2 = sb + 1400, *ssc2 = sb + 1700;
  int*   dflag = (int*)(sb + 2002);
  float* b1f   = sb + 2010;
  float* b2f   = sb + 2210;
  float* b1cf  = sb + 2410;
  float* b2cf  = sb + 2710;
  float* gb    = sb + 3100;   // 800 fp32 gru bias combos

  size_t required = (size_t)(p - (char*)d_ws);
  if (required > ws_size) {
    sentinel_kernel<<<1, 64, 0, stream>>>((ushort_t*)d_out);
    return;
  }

  probe_kernel<<<1, 64, 0, stream>>>(x, dflag);
  zero_kernel<<<(NNODES + 255) / 256, 256, 0, stream>>>(cnt, NNODES);
  zero_kernel<<<(2000 + 255) / 256, 256, 0, stream>>>((int*)sb, 2000);
  hinit_kernel<<<(NNODES * FOUT + 255) / 256, 256, 0, stream>>>(x, dflag, h);

  // wp = ggnn_w @ wih^T as one MFMA GEMM
  pada_kernel<<<(1600 * 224 + 255) / 256, 256, 0, stream>>>(ggnn_w, dflag, gwp, 200, 224, 1600, 1600 * 224);
  pada_kernel<<<(640 * 224 + 255) / 256, 256, 0, stream>>>(gru_wih, dflag, wihp, 200, 224, 600, 640 * 224);
  gemm128<false><<<dim3(13, 5), 256, 0, stream>>>(gwp, 224, wihp, Wp, 600, 1600, 600, 224, nullptr);

  btgruq_kernel<<<(NSTEPS * 896 * 416 + 255) / 256, 256, 0, stream>>>(Wp, gru_whh, dflag, BtG);
  gbias_kernel<<<1, 256, 0, stream>>>(gru_bih, gru_bhh, dflag, gb);
  btconv_kernel<<<(256 * 800 + 255) / 256, 256, 0, stream>>>(conv1_w, dflag, Bt1, 200, 4, 800, 200, 256 * 800);
  btconv_kernel<<<(256 * 416 + 255) / 256, 256, 0, stream>>>(conv2_w, dflag, Bt2, 200, 2, 416, 200, 256 * 416);
  btconv_kernel<<<(384 * 1216 + 255) / 256, 256, 0, stream>>>(conv1c_w, dflag, Bt1c, 300, 4, 1216, 300, 384 * 1216);
  btconv_kernel<<<(384 * 608 + 255) / 256, 256, 0, stream>>>(conv2c_w, dflag, Bt2c, 300, 2, 608, 300, 384 * 608);
  bias_kernel<<<1, 256, 0, stream>>>(conv1_b, dflag, b1f, 200);
  bias_kernel<<<1, 256, 0, stream>>>(conv2_b, dflag, b2f, 200);
  bias_kernel<<<2, 256, 0, stream>>>(conv1c_b, dflag, b1cf, 300);
  bias_kernel<<<2, 256, 0, stream>>>(conv2c_b, dflag, b2cf, 300);

  hist_kernel<<<(NEDGES + 255) / 256, 256, 0, stream>>>(dstv, cnt);
  bsum_kernel<<<NSCANB, 256, 0, stream>>>(cnt, bsum);
  bscan_kernel<<<1, 256, 0, stream>>>(bsum, boff);
  rowptr_kernel<<<NSCANB, 256, 0, stream>>>(cnt, boff, row_ptr, cursor);
  fill_kernel<<<(NEDGES + 255) / 256, 256, 0, stream>>>(srcv, dstv, cursor, csr_src);

  for (int l = 0; l < NSTEPS; l++) {
    gather_kernel<<<(NNODES + 3) / 4, 256, 0, stream>>>(row_ptr, csr_src, h, Ag);
    gemm_gru<<<dim3(391, 7), 256, 0, stream>>>(Ag, 400, BtG + (size_t)l * 896 * 416,
                                               h, NNODES, 416, gb);
  }
  ccat_kernel<<<(NNODES * FCAT + 255) / 256, 256, 0, stream>>>(h, x, dflag, cc);

  // branch y
  gemm128<false><<<dim3(391, 2), 256, 0, stream>>>(h, 200, Bt1, C1, 200, 49997, 200, 800, b1f);
  stats_kernel<<<(49997 + 63) / 64, 256, 0, stream>>>(C1, 49997, 200, s1, ss1);
  bnpool_kernel<<<(24997 * 200 + 255) / 256, 256, 0, stream>>>(C1, 49997, 200, 4, 2, 24997,
                                                               s1, ss1, bn_g, bn_b, dflag, pooled1);
  gemm128<false><<<dim3(196, 2), 256, 0, stream>>>(pooled1, 200, Bt2, C2, 200, 24996, 200, 416, b2f);
  stats_kernel<<<(24996 + 63) / 64, 256, 0, stream>>>(C2, 24996, 200, s2, ss2);
  bnpool_kernel<<<(12497 * 200 + 255) / 256, 256, 0, stream>>>(C2, 24996, 200, 3, 2, 12497,
                                                               s2, ss2, bn_g, bn_b, dflag, Y2);
  // branch z
  gemm128<false><<<dim3(391, 3), 256, 0, stream>>>(cc, 300, Bt1c, C1c, 300, 49997, 300, 1216, b1cf);
  stats_kernel<<<(49997 + 63) / 64, 256, 0, stream>>>(C1c, 49997, 300, sc1, ssc1);
  bnpool_kernel<<<(24997 * 300 + 255) / 256, 256, 0, stream>>>(C1c, 49997, 300, 4, 2, 24997,
                                                               sc1, ssc1, bnc_g, bnc_b, dflag, pooledc);
  gemm128<false><<<dim3(196, 3), 256, 0, stream>>>(pooledc, 300, Bt2c, C2c, 300, 24996, 300, 608, b2cf);
  stats_kernel<<<(24996 + 63) / 64, 256, 0, stream>>>(C2c, 24996, 300, sc2, ssc2);
  bnpool_kernel<<<(12497 * 300 + 255) / 256, 256, 0, stream>>>(C2c, 24996, 300, 3, 2, 12497,
                                                               sc2, ssc2, bnc_g, bnc_b, dflag, Z2);

  final_kernel<<<3125, 256, 0, stream>>>(Y2, Z2, mlpy_w, mlpy_b, mlpz_w, mlpz_b, dflag, pacc);
  finalize_kernel<<<1, 256, 0, stream>>>(pacc, 3125, dflag, d_out);
}

// Round 11
// 1943.668 us; speedup vs baseline: 1.3275x; 1.0597x over previous
//
#include <hip/hip_runtime.h>
#include <cstdint>
#include <cstddef>

#define NNODES 50000
#define NEDGES 800000
#define FIN    100
#define FOUT   200
#define FCAT   300
#define NSTEPS 8
#define NSCANB 196

typedef unsigned short ushort_t;
typedef __bf16 bf16x8 __attribute__((ext_vector_type(8)));
typedef float  floatx4 __attribute__((ext_vector_type(4)));

__device__ __forceinline__ float bf2f(ushort_t u) {
  union { unsigned u; float f; } c; c.u = ((unsigned)u) << 16; return c.f;
}
__device__ __forceinline__ ushort_t f2bf(float f) {
  union { float f; unsigned u; } c; c.f = f;
  unsigned r = c.u + 0x7FFFu + ((c.u >> 16) & 1u);
  return (ushort_t)(r >> 16);
}
__device__ __forceinline__ float inval(const void* p, size_t i, int f32) {
  return f32 ? ((const float*)p)[i] : bf2f(((const ushort_t*)p)[i]);
}

// async global->LDS 16B
__device__ __forceinline__ void gl2lds16(const ushort_t* g, ushort_t* l) {
  typedef const __attribute__((address_space(1))) unsigned int gu32;
  typedef __attribute__((address_space(3))) unsigned int lu32;
  __builtin_amdgcn_global_load_lds((gu32*)(uintptr_t)g, (lu32*)(uintptr_t)l, 16, 0, 0);
}

// ---------------------------------------------------------------- dtype probe
__global__ void probe_kernel(const void* xraw, int* flag) {
  const ushort_t* u = (const ushort_t*)xraw;
  int t = threadIdx.x;
  int bad = 0;
  for (int i = t; i < 2048; i += 64) {
    int e = (u[2 * i] >> 7) & 0xFF;
    if (e >= 0x88) bad++;
  }
  for (int off = 32; off; off >>= 1) bad += __shfl_down(bad, off);
  if (t == 0) *flag = (bad > 128) ? 1 : 0;
}

// ---------------------------------------------------------------- utility
__global__ void zero_kernel(int* p, int n) {
  int i = blockIdx.x * 256 + threadIdx.x;
  if (i < n) p[i] = 0;
}

__global__ void sentinel_kernel(ushort_t* out) {
  if (threadIdx.x == 0 && blockIdx.x == 0) {
    out[0] = f2bf(0.123f);
    out[1] = f2bf(0.877f);
  }
}

__global__ void hinit_kernel(const void* __restrict__ x, const int* __restrict__ dflag,
                             ushort_t* __restrict__ h) {
  const int f32 = *dflag;
  int i = blockIdx.x * 256 + threadIdx.x;
  if (i >= NNODES * FOUT) return;
  int n = i / FOUT, c = i % FOUT;
  h[i] = (c < FIN) ? f2bf(inval(x, (size_t)n * FIN + c, f32)) : (ushort_t)0;
}

__global__ void ccat_kernel(const ushort_t* __restrict__ h, const void* __restrict__ x,
                            const int* __restrict__ dflag, ushort_t* __restrict__ cc) {
  const int f32 = *dflag;
  int i = blockIdx.x * 256 + threadIdx.x;
  if (i >= NNODES * FCAT) return;
  int n = i / FCAT, c = i % FCAT;
  cc[i] = (c < FOUT) ? h[n * FOUT + c] : f2bf(inval(x, (size_t)n * FIN + (c - FOUT), f32));
}

// ---------------------------------------------------------------- CSR build
__global__ void hist_kernel(const int* __restrict__ dst, int* __restrict__ cnt) {
  int e = blockIdx.x * 256 + threadIdx.x;
  if (e < NEDGES) atomicAdd(&cnt[dst[e]], 1);
}

__global__ void bsum_kernel(const int* __restrict__ cnt, int* __restrict__ bsum) {
  __shared__ int red[4];
  int i = blockIdx.x * 256 + threadIdx.x;
  int v = (i < NNODES) ? cnt[i] : 0;
  for (int off = 32; off; off >>= 1) v += __shfl_down(v, off);
  int w = threadIdx.x >> 6;
  if ((threadIdx.x & 63) == 0) red[w] = v;
  __syncthreads();
  if (threadIdx.x == 0) bsum[blockIdx.x] = red[0] + red[1] + red[2] + red[3];
}

__global__ void bscan_kernel(const int* __restrict__ bsum, int* __restrict__ boff) {
  __shared__ int s[256];
  int t = threadIdx.x;
  int v = (t < NSCANB) ? bsum[t] : 0;
  s[t] = v;
  __syncthreads();
  for (int off = 1; off < 256; off <<= 1) {
    int u = (t >= off) ? s[t - off] : 0;
    __syncthreads();
    s[t] += u;
    __syncthreads();
  }
  if (t < NSCANB) boff[t] = s[t] - v;   // exclusive
}

__global__ void rowptr_kernel(const int* __restrict__ cnt, const int* __restrict__ boff,
                              int* __restrict__ row_ptr, int* __restrict__ cursor) {
  __shared__ int s[256];
  int t = threadIdx.x;
  int i = blockIdx.x * 256 + t;
  int v = (i < NNODES) ? cnt[i] : 0;
  s[t] = v;
  __syncthreads();
  for (int off = 1; off < 256; off <<= 1) {
    int u = (t >= off) ? s[t - off] : 0;
    __syncthreads();
    s[t] += u;
    __syncthreads();
  }
  if (i < NNODES) {
    int e = boff[blockIdx.x] + s[t] - v;
    row_ptr[i] = e; cursor[i] = e;
    if (i == NNODES - 1) row_ptr[NNODES] = boff[blockIdx.x] + s[t];
  }
}

__global__ void fill_kernel(const int* __restrict__ srcv, const int* __restrict__ dstv,
                            int* __restrict__ cursor, int* __restrict__ csr_src) {
  int e = blockIdx.x * 256 + threadIdx.x;
  if (e >= NEDGES) return;
  int p = atomicAdd(&cursor[dstv[e]], 1);
  csr_src[p] = srcv[e];
}

// agg[n] = sum over in-edges of h[src]; writes A = [agg | h] row (400 wide, bf16)
__global__ __launch_bounds__(256) void gather_kernel(
    const int* __restrict__ row_ptr, const int* __restrict__ csr_src,
    const ushort_t* __restrict__ h, ushort_t* __restrict__ Ag) {
  int g = threadIdx.x >> 6;
  int lane = threadIdx.x & 63;
  int n = blockIdx.x * 4 + g;
  if (n >= NNODES) return;
  if (lane >= 50) return;
  int s0 = row_ptr[n], s1 = row_ptr[n + 1];
  float a0 = 0.f, a1 = 0.f, a2 = 0.f, a3 = 0.f;
  int i = s0;
  for (; i + 3 < s1; i += 4) {
    int sa = csr_src[i], sb = csr_src[i + 1], sc = csr_src[i + 2], sd = csr_src[i + 3];
    ushort4 va = *(const ushort4*)&h[(size_t)sa * FOUT + lane * 4];
    ushort4 vb = *(const ushort4*)&h[(size_t)sb * FOUT + lane * 4];
    ushort4 vc = *(const ushort4*)&h[(size_t)sc * FOUT + lane * 4];
    ushort4 vd = *(const ushort4*)&h[(size_t)sd * FOUT + lane * 4];
    a0 += (bf2f(va.x) + bf2f(vb.x)) + (bf2f(vc.x) + bf2f(vd.x));
    a1 += (bf2f(va.y) + bf2f(vb.y)) + (bf2f(vc.y) + bf2f(vd.y));
    a2 += (bf2f(va.z) + bf2f(vb.z)) + (bf2f(vc.z) + bf2f(vd.z));
    a3 += (bf2f(va.w) + bf2f(vb.w)) + (bf2f(vc.w) + bf2f(vd.w));
  }
  for (; i < s1; i++) {
    int sa = csr_src[i];
    ushort4 va = *(const ushort4*)&h[(size_t)sa * FOUT + lane * 4];
    a0 += bf2f(va.x); a1 += bf2f(va.y); a2 += bf2f(va.z); a3 += bf2f(va.w);
  }
  ushort4 o;
  o.x = f2bf(a0); o.y = f2bf(a1); o.z = f2bf(a2); o.w = f2bf(a3);
  *(ushort4*)&Ag[(size_t)n * 400 + lane * 4] = o;
  *(ushort4*)&Ag[(size_t)n * 400 + FOUT + lane * 4] =
      *(const ushort4*)&h[(size_t)n * FOUT + lane * 4];
}

// ---------------------------------------------------------------- padded bf16 copies
__global__ void pada_kernel(const void* __restrict__ src, const int* __restrict__ dflag,
                            ushort_t* __restrict__ dst, int K, int Kp, int rowsValid,
                            int total) {
  const int f32 = *dflag;
  int i = blockIdx.x * 256 + threadIdx.x;
  if (i >= total) return;
  int r = i / Kp, k = i % Kp;
  float v = (r < rowsValid && k < K) ? inval(src, (size_t)r * K + k, f32) : 0.f;
  dst[i] = f2bf(v);
}

// Bt_gru packed: [8][896 rows][416 k], row nn = 4*c + gate (r,z,ic,hc), c<200 valid.
__global__ void btgruq_kernel(const float* __restrict__ Wp, const void* __restrict__ whh,
                              const int* __restrict__ dflag, ushort_t* __restrict__ Bt) {
  const int f32 = *dflag;
  int i = blockIdx.x * 256 + threadIdx.x;
  if (i >= NSTEPS * 896 * 416) return;
  int l = i / (896 * 416);
  int rem = i % (896 * 416);
  int nn = rem / 416;
  int k = rem % 416;
  int c = nn >> 2, g = nn & 3;
  float v = 0.f;
  if (c < 200) {
    if (k < 200) {
      const float* wrow = Wp + ((size_t)l * 200 + k) * 600;
      if (g == 0) v = wrow[c];
      else if (g == 1) v = wrow[200 + c];
      else if (g == 2) v = wrow[400 + c];
    } else if (k < 400) {
      int kh = k - 200;
      if (g == 0) v = inval(whh, (size_t)c * 200 + kh, f32);
      else if (g == 1) v = inval(whh, (size_t)(200 + c) * 200 + kh, f32);
      else if (g == 3) v = inval(whh, (size_t)(400 + c) * 200 + kh, f32);
    }
  }
  Bt[((size_t)nn + 896 * (size_t)l) * 416 + k] = f2bf(v);
}

__global__ void btconv_kernel(const void* __restrict__ w, const int* __restrict__ dflag,
                              ushort_t* __restrict__ Bt, int C, int KT, int Kp,
                              int O, int total) {
  const int f32 = *dflag;
  int i = blockIdx.x * 256 + threadIdx.x;
  if (i >= total) return;
  int o = i / Kp, k = i % Kp;
  float v = 0.f;
  int K = C * KT;
  if (k < K && o < O) {
    int ktap = k / C; int ci = k % C;
    v = inval(w, ((size_t)o * C + ci) * KT + ktap, f32);
  }
  Bt[i] = f2bf(v);
}

// gru bias precombine
__global__ void gbias_kernel(const void* __restrict__ bih, const void* __restrict__ bhh,
                             const int* __restrict__ dflag, float* __restrict__ gb) {
  const int f32 = *dflag;
  int c = blockIdx.x * 256 + threadIdx.x;
  if (c >= 200) return;
  gb[c]       = inval(bih, c, f32)       + inval(bhh, c, f32);
  gb[200 + c] = inval(bih, 200 + c, f32) + inval(bhh, 200 + c, f32);
  gb[400 + c] = inval(bih, 400 + c, f32);
  gb[600 + c] = inval(bhh, 400 + c, f32);
}

// XCD-aware tile decode: all n-tiles of an m-tile land on one XCD (id%8).
// CH = ceil(MT/8) m-tiles per XCD. Returns false for pad blocks.
__device__ __forceinline__ bool xcd_tile(int id, int MT, int NT, int& mt, int& nt) {
  int xcd = id & 7;
  int slot = id >> 3;
  mt = xcd * ((MT + 7) >> 3) + slot / NT;
  nt = slot % NT;
  return mt < MT;
}

// ---------------------------------------------------------------- GEMM (MFMA, 128x128)
// 1D grid of 8*ceil(MT/8)*NT blocks, XCD-swizzled (A row-tile stays on one XCD's L2).
template <bool OUT_BF16>
__global__ __launch_bounds__(256) void gemm128(
    const ushort_t* __restrict__ A, int lda, const ushort_t* __restrict__ Bt,
    void* __restrict__ Cv, int ldc, int M, int N, int Kp,
    const float* __restrict__ bias) {
  __shared__ alignas(16) ushort_t As[128 * 32];
  __shared__ alignas(16) ushort_t Bs[128 * 32];
  const int MT = (M + 127) >> 7;
  const int NT = (N + 127) >> 7;
  int mt, nt;
  if (!xcd_tile(blockIdx.x, MT, NT, mt, nt)) return;
  const int m0 = mt * 128;
  const int n0 = nt * 128;
  const int tid = threadIdx.x;
  const int lane = tid & 63;
  const int wv = tid >> 6;
  const int wm = wv & 1;
  const int wn = wv >> 1;
  const int quad = lane >> 4;
  const int l15 = lane & 15;

  const int s0i = wv * 128 + lane;
  const int s1i = s0i + 64;
  const int r0 = s0i >> 2, c0 = (s0i & 3) ^ ((r0 >> 1) & 3);
  const int r1 = s1i >> 2, c1 = (s1i & 3) ^ ((r1 >> 1) & 3);
  int ar0 = m0 + r0; if (ar0 >= M) ar0 = M - 1;
  int ar1 = m0 + r1; if (ar1 >= M) ar1 = M - 1;
  const ushort_t* gA0 = A + (size_t)ar0 * lda + c0 * 8;
  const ushort_t* gA1 = A + (size_t)ar1 * lda + c1 * 8;
  const ushort_t* gB0 = Bt + (size_t)(n0 + r0) * Kp + c0 * 8;
  const ushort_t* gB1 = Bt + (size_t)(n0 + r1) * Kp + c1 * 8;
  ushort_t* lA0 = &As[(size_t)(wv * 128) * 8];
  ushort_t* lA1 = &As[(size_t)(wv * 128 + 64) * 8];
  ushort_t* lB0 = &Bs[(size_t)(wv * 128) * 8];
  ushort_t* lB1 = &Bs[(size_t)(wv * 128 + 64) * 8];

  floatx4 acc[4][4];
  #pragma unroll
  for (int a = 0; a < 4; a++)
    #pragma unroll
    for (int b = 0; b < 4; b++)
      acc[a][b] = (floatx4){0.f, 0.f, 0.f, 0.f};

  for (int k0 = 0; k0 < Kp; k0 += 32) {
    gl2lds16(gA0 + k0, lA0);
    gl2lds16(gA1 + k0, lA1);
    gl2lds16(gB0 + k0, lB0);
    gl2lds16(gB1 + k0, lB1);
    __syncthreads();
    bf16x8 af[4], bfr[4];
    #pragma unroll
    for (int t = 0; t < 4; t++) {
      int ra = wm * 64 + t * 16 + l15;
      int rb = wn * 64 + t * 16 + l15;
      af[t]  = *(const bf16x8*)&As[(ra * 4 + (quad ^ ((ra >> 1) & 3))) * 8];
      bfr[t] = *(const bf16x8*)&Bs[(rb * 4 + (quad ^ ((rb >> 1) & 3))) * 8];
    }
    #pragma unroll
    for (int tm = 0; tm < 4; tm++)
      #pragma unroll
      for (int tn = 0; tn < 4; tn++)
        acc[tm][tn] = __builtin_amdgcn_mfma_f32_16x16x32_bf16(af[tm], bfr[tn], acc[tm][tn], 0, 0, 0);
    __syncthreads();
  }

  #pragma unroll
  for (int tm = 0; tm < 4; tm++) {
    int row = m0 + wm * 64 + tm * 16 + quad * 4;
    #pragma unroll
    for (int tn = 0; tn < 4; tn++) {
      int col = n0 + wn * 64 + tn * 16 + l15;
      if (col < N) {
        float bb = bias ? bias[col] : 0.f;
        #pragma unroll
        for (int r = 0; r < 4; r++) {
          if (row + r < M) {
            float v = acc[tm][tn][r] + bb;
            if (OUT_BF16) ((ushort_t*)Cv)[(size_t)(row + r) * ldc + col] = f2bf(v);
            else          ((float*)Cv)[(size_t)(row + r) * ldc + col] = v;
          }
        }
      }
    }
  }
}

// ---------------------------------------------------------------- fused GRU GEMM
// Gate-packed B (col = 4*c+gate), in-register butterfly epilogue, XCD-swizzled
// 1D grid (NT=7).
__global__ __launch_bounds__(256) void gemm_gru(
    const ushort_t* __restrict__ A, int lda, const ushort_t* __restrict__ Bt,
    ushort_t* __restrict__ h, int M, int Kp, const float* __restrict__ gb) {
  __shared__ alignas(16) ushort_t As[128 * 32];
  __shared__ alignas(16) ushort_t Bs[128 * 32];
  const int MT = (M + 127) >> 7;
  int mt, nt;
  if (!xcd_tile(blockIdx.x, MT, 7, mt, nt)) return;
  const int m0 = mt * 128;
  const int n0 = nt * 128;
  const int tid = threadIdx.x;
  const int lane = tid & 63;
  const int wv = tid >> 6;
  const int wm = wv & 1;
  const int wn = wv >> 1;
  const int quad = lane >> 4;
  const int l15 = lane & 15;

  const int s0i = wv * 128 + lane;
  const int s1i = s0i + 64;
  const int r0 = s0i >> 2, c0 = (s0i & 3) ^ ((r0 >> 1) & 3);
  const int r1 = s1i >> 2, c1 = (s1i & 3) ^ ((r1 >> 1) & 3);
  int ar0 = m0 + r0; if (ar0 >= M) ar0 = M - 1;
  int ar1 = m0 + r1; if (ar1 >= M) ar1 = M - 1;
  const ushort_t* gA0 = A + (size_t)ar0 * lda + c0 * 8;
  const ushort_t* gA1 = A + (size_t)ar1 * lda + c1 * 8;
  const ushort_t* gB0 = Bt + (size_t)(n0 + r0) * Kp + c0 * 8;
  const ushort_t* gB1 = Bt + (size_t)(n0 + r1) * Kp + c1 * 8;
  ushort_t* lA0 = &As[(size_t)(wv * 128) * 8];
  ushort_t* lA1 = &As[(size_t)(wv * 128 + 64) * 8];
  ushort_t* lB0 = &Bs[(size_t)(wv * 128) * 8];
  ushort_t* lB1 = &Bs[(size_t)(wv * 128 + 64) * 8];

  floatx4 acc[4][4];
  #pragma unroll
  for (int a = 0; a < 4; a++)
    #pragma unroll
    for (int b = 0; b < 4; b++)
      acc[a][b] = (floatx4){0.f, 0.f, 0.f, 0.f};

  for (int k0 = 0; k0 < Kp; k0 += 32) {
    gl2lds16(gA0 + k0, lA0);
    gl2lds16(gA1 + k0, lA1);
    gl2lds16(gB0 + k0, lB0);
    gl2lds16(gB1 + k0, lB1);
    __syncthreads();
    bf16x8 af[4], bfr[4];
    #pragma unroll
    for (int t = 0; t < 4; t++) {
      int ra = wm * 64 + t * 16 + l15;
      int rb = wn * 64 + t * 16 + l15;
      af[t]  = *(const bf16x8*)&As[(ra * 4 + (quad ^ ((ra >> 1) & 3))) * 8];
      bfr[t] = *(const bf16x8*)&Bs[(rb * 4 + (quad ^ ((rb >> 1) & 3))) * 8];
    }
    #pragma unroll
    for (int tm = 0; tm < 4; tm++)
      #pragma unroll
      for (int tn = 0; tn < 4; tn++)
        acc[tm][tn] = __builtin_amdgcn_mfma_f32_16x16x32_bf16(af[tm], bfr[tn], acc[tm][tn], 0, 0, 0);
    __syncthreads();
  }

  // in-register epilogue
  const int sb0 = l15 & 1;
  const int sb1 = (l15 >> 1) & 1;
  const int jch = l15 >> 2;
  const int chb = nt * 32 + wn * 16;
  #pragma unroll
  for (int tm = 0; tm < 4; tm++) {
    #pragma unroll
    for (int tn = 0; tn < 4; tn++) {
      float v0 = acc[tm][tn][0], v1 = acc[tm][tn][1];
      float v2 = acc[tm][tn][2], v3 = acc[tm][tn][3];
      float t;
      t = __shfl_xor(sb0 ? v0 : v1, 1); if (sb0) v0 = t; else v1 = t;
      t = __shfl_xor(sb0 ? v2 : v3, 1); if (sb0) v2 = t; else v3 = t;
      t = __shfl_xor(sb1 ? v0 : v2, 2); if (sb1) v0 = t; else v2 = t;
      t = __shfl_xor(sb1 ? v1 : v3, 2); if (sb1) v1 = t; else v3 = t;
      int row = m0 + wm * 64 + tm * 16 + quad * 4 + (l15 & 3);
      int chan = chb + tn * 4 + jch;
      if (row < M && chan < 200) {
        float Sr = bf2f(f2bf(v0));
        float Sz = bf2f(f2bf(v1));
        float Si = bf2f(f2bf(v2));
        float Sh = bf2f(f2bf(v3));
        float r_ = 1.f / (1.f + expf(-(Sr + gb[chan])));
        float z_ = 1.f / (1.f + expf(-(Sz + gb[200 + chan])));
        float n_ = tanhf(Si + gb[400 + chan] + r_ * (Sh + gb[600 + chan]));
        float ho = bf2f(h[(size_t)row * 200 + chan]);
        h[(size_t)row * 200 + chan] = f2bf((1.f - z_) * n_ + z_ * ho);
      }
    }
  }
}

__global__ void bias_kernel(const void* __restrict__ b, const int* __restrict__ dflag,
                            float* __restrict__ out, int n) {
  const int f32 = *dflag;
  int i = blockIdx.x * 256 + threadIdx.x;
  if (i < n) out[i] = inval(b, i, f32);
}

// ---------------------------------------------------------------- BN stats + pool
__global__ void stats_kernel(const float* __restrict__ X, int Lrows, int C,
                             float* __restrict__ sums, float* __restrict__ sumsq) {
  int r0 = blockIdx.x * 64;
  int rend = r0 + 64; if (rend > Lrows) rend = Lrows;
  for (int c = threadIdx.x; c < C; c += 256) {
    float s = 0.f, ss = 0.f;
    for (int r = r0; r < rend; r++) {
      float v = X[(size_t)r * C + c];
      s += v; ss += v * v;
    }
    atomicAdd(&sums[c], s);
    atomicAdd(&sumsq[c], ss);
  }
}

__global__ void bnpool_kernel(const float* __restrict__ X, int Lin, int C, int kk, int ss,
                              int Lp, const float* __restrict__ sums,
                              const float* __restrict__ sumsq,
                              const void* __restrict__ g, const void* __restrict__ b,
                              const int* __restrict__ dflag, ushort_t* __restrict__ out) {
  const int f32 = *dflag;
  int i = blockIdx.x * 256 + threadIdx.x;
  if (i >= Lp * C) return;
  int p = i / C, c = i % C;
  float inv = 1.f / (float)Lin;
  float mu = sums[c] * inv;
  float var = sumsq[c] * inv - mu * mu; if (var < 0.f) var = 0.f;
  float scale = inval(g, c, f32) * rsqrtf(var + 1e-5f);
  float shift = inval(b, c, f32) - mu * scale;
  float m = -1e30f;
  int base = p * ss;
  for (int r = 0; r < kk; r++) {
    float v = X[(size_t)(base + r) * C + c] * scale + shift;
    if (v > m) m = v;
  }
  if (m < 0.f) m = 0.f;
  out[(size_t)p * C + c] = f2bf(m);
}

// ---------------------------------------------------------------- head (atomic-free)
__global__ __launch_bounds__(256) void final_kernel(
    const ushort_t* __restrict__ Y2, const ushort_t* __restrict__ Z2,
    const void* __restrict__ wy, const void* __restrict__ by,
    const void* __restrict__ wz, const void* __restrict__ bz,
    const int* __restrict__ dflag, float* __restrict__ pacc) {
  const int f32 = *dflag;
  __shared__ float bl[8];
  int g = threadIdx.x >> 6;
  int lane = threadIdx.x & 63;
  int row = blockIdx.x * 4 + g;
  float y0 = 0.f, y1 = 0.f, z0 = 0.f, z1 = 0.f;
  if (row < 12497) {
    for (int c = lane; c < 200; c += 64) {
      float v = bf2f(Y2[(size_t)row * 200 + c]);
      y0 += v * inval(wy, c, f32);
      y1 += v * inval(wy, 200 + c, f32);
    }
    for (int c = lane; c < 300; c += 64) {
      float v = bf2f(Z2[(size_t)row * 300 + c]);
      z0 += v * inval(wz, c, f32);
      z1 += v * inval(wz, 300 + c, f32);
    }
  }
  for (int off = 32; off > 0; off >>= 1) {
    y0 += __shfl_down(y0, off);
    y1 += __shfl_down(y1, off);
    z0 += __shfl_down(z0, off);
    z1 += __shfl_down(z1, off);
  }
  if (lane == 0) {
    float p0 = 0.f, p1 = 0.f;
    if (row < 12497) {
      p0 = (y0 + inval(by, 0, f32)) * (z0 + inval(bz, 0, f32));
      p1 = (y1 + inval(by, 1, f32)) * (z1 + inval(bz, 1, f32));
    }
    bl[g * 2] = p0; bl[g * 2 + 1] = p1;
  }
  __syncthreads();
  if (threadIdx.x == 0) {
    pacc[(size_t)blockIdx.x * 2]     = bl[0] + bl[2] + bl[4] + bl[6];
    pacc[(size_t)blockIdx.x * 2 + 1] = bl[1] + bl[3] + bl[5] + bl[7];
  }
}

__global__ __launch_bounds__(256) void finalize_kernel(
    const float* __restrict__ pacc, int nblk, const int* __restrict__ dflag,
    void* __restrict__ out) {
  const int f32 = *dflag;
  __shared__ float red[2][4];
  int t = threadIdx.x;
  float s0 = 0.f, s1 = 0.f;
  for (int i = t; i < nblk; i += 256) { s0 += pacc[2 * i]; s1 += pacc[2 * i + 1]; }
  for (int off = 32; off; off >>= 1) { s0 += __shfl_down(s0, off); s1 += __shfl_down(s1, off); }
  int w = t >> 6;
  if ((t & 63) == 0) { red[0][w] = s0; red[1][w] = s1; }
  __syncthreads();
  if (t == 0) {
    float a0 = (red[0][0] + red[0][1] + red[0][2] + red[0][3]) / 12497.f;
    float a1 = (red[1][0] + red[1][1] + red[1][2] + red[1][3]) / 12497.f;
    float mx = fmaxf(a0, a1);
    float e0 = expf(a0 - mx), e1 = expf(a1 - mx);
    float s = e0 + e1;
    if (f32) {
      ((float*)out)[0] = e0 / s;
      ((float*)out)[1] = e1 / s;
    } else {
      ((ushort_t*)out)[0] = f2bf(e0 / s);
      ((ushort_t*)out)[1] = f2bf(e1 / s);
    }
  }
}

// ---------------------------------------------------------------- launch
static inline int xcd_grid(int M, int NT) {
  int MT = (M + 127) >> 7;
  int CH = (MT + 7) >> 3;
  return 8 * CH * NT;
}

extern "C" void kernel_launch(void* const* d_in, const int* in_sizes, int n_in,
                              void* d_out, int out_size, void* d_ws, size_t ws_size,
                              hipStream_t stream) {
  const void* x        = d_in[0];
  const int*  edge     = (const int*)d_in[1];
  const void* ggnn_w   = d_in[2];
  const void* gru_wih  = d_in[3];
  const void* gru_whh  = d_in[4];
  const void* gru_bih  = d_in[5];
  const void* gru_bhh  = d_in[6];
  const void* conv1_w  = d_in[7];
  const void* conv1_b  = d_in[8];
  const void* conv2_w  = d_in[9];
  const void* conv2_b  = d_in[10];
  const void* conv1c_w = d_in[11];
  const void* conv1c_b = d_in[12];
  const void* conv2c_w = d_in[13];
  const void* conv2c_b = d_in[14];
  const void* bn_g     = d_in[15];
  const void* bn_b     = d_in[16];
  const void* bnc_g    = d_in[17];
  const void* bnc_b    = d_in[18];
  const void* mlpy_w   = d_in[19];
  const void* mlpy_b   = d_in[20];
  const void* mlpz_w   = d_in[21];
  const void* mlpz_b   = d_in[22];
  const int* srcv = edge;
  const int* dstv = edge + NEDGES;

  // ---- workspace layout (aliased; total ~177 MB) ----
  char* p = (char*)d_ws;
  auto alloc = [&](size_t bytes) -> char* {
    char* r = p; p += (bytes + 255) & ~(size_t)255; return r;
  };
  ushort_t* h    = (ushort_t*)alloc(((size_t)NNODES * FOUT + 64) * 2);
  ushort_t* Ag   = (ushort_t*)alloc(((size_t)NNODES * 400 + 64) * 2);
  ushort_t* cc   = Ag;  // cc[N,300] built AFTER GRU loop, Ag then dead
  char*     R    = alloc((size_t)98 * 1000 * 1000);
  float*    C1   = (float*)R;
  float*    C2   = (float*)R;
  float*    C1c  = (float*)R;
  float*    C2c  = (float*)R;
  ushort_t* pooled1 = (ushort_t*)(R + 60000000);
  ushort_t* pooledc = (ushort_t*)(R + 70000000);
  ushort_t* Y2      = (ushort_t*)(R + 85000000);
  ushort_t* Z2      = (ushort_t*)(R + 90000000);
  ushort_t* BtG  = (ushort_t*)alloc((size_t)8 * 896 * 416 * 2);
  ushort_t* Bt1  = (ushort_t*)alloc((size_t)256 * 800 * 2);
  ushort_t* Bt2  = (ushort_t*)alloc((size_t)256 * 416 * 2);
  ushort_t* Bt1c = (ushort_t*)alloc((size_t)384 * 1216 * 2);
  ushort_t* Bt2c = (ushort_t*)alloc((size_t)384 * 608 * 2);
  ushort_t* gwp  = (ushort_t*)alloc((size_t)1600 * 224 * 2);
  ushort_t* wihp = (ushort_t*)alloc((size_t)640 * 224 * 2);
  float*    Wp   = (float*)alloc((size_t)1600 * 600 * 4);
  int*   csr_src = (int*)alloc((size_t)NEDGES * 4);
  int*   row_ptr = (int*)alloc((size_t)(NNODES + 1) * 4);
  int*   cursor  = (int*)alloc((size_t)NNODES * 4);
  int*   cnt     = (int*)alloc((size_t)NNODES * 4);
  int*   bsum    = (int*)alloc((size_t)(NSCANB + 4) * 4);
  int*   boff    = (int*)alloc((size_t)(NSCANB + 4) * 4);
  float* pacc    = (float*)alloc((size_t)3125 * 2 * 4);
  float* sb      = (float*)alloc((size_t)4300 * 4);
  float *s1 = sb, *ss1 = sb + 200, *s2 = sb + 400, *ss2 = sb + 600;
  float *sc1 = sb + 800, *ssc1 = sb + 1100, *sc2 = sb + 1400, *ssc2 = sb + 1700;
  int*   dflag = (int*)(sb + 2002);
  float* b1f   = sb + 2010;
  float* b2f   = sb + 2210;
  float* b1cf  = sb + 2410;
  float* b2cf  = sb + 2710;
  float* gb    = sb + 3100;   // 800 fp32 gru bias combos

  size_t required = (size_t)(p - (char*)d_ws);
  if (required > ws_size) {
    sentinel_kernel<<<1, 64, 0, stream>>>((ushort_t*)d_out);
    return;
  }

  probe_kernel<<<1, 64, 0, stream>>>(x, dflag);
  zero_kernel<<<(NNODES + 255) / 256, 256, 0, stream>>>(cnt, NNODES);
  zero_kernel<<<(2000 + 255) / 256, 256, 0, stream>>>((int*)sb, 2000);
  hinit_kernel<<<(NNODES * FOUT + 255) / 256, 256, 0, stream>>>(x, dflag, h);

  // wp = ggnn_w @ wih^T as one MFMA GEMM
  pada_kernel<<<(1600 * 224 + 255) / 256, 256, 0, stream>>>(ggnn_w, dflag, gwp, 200, 224, 1600, 1600 * 224);
  pada_kernel<<<(640 * 224 + 255) / 256, 256, 0, stream>>>(gru_wih, dflag, wihp, 200, 224, 600, 640 * 224);
  gemm128<false><<<xcd_grid(1600, 5), 256, 0, stream>>>(gwp, 224, wihp, Wp, 600, 1600, 600, 224, nullptr);

  btgruq_kernel<<<(NSTEPS * 896 * 416 + 255) / 256, 256, 0, stream>>>(Wp, gru_whh, dflag, BtG);
  gbias_kernel<<<1, 256, 0, stream>>>(gru_bih, gru_bhh, dflag, gb);
  btconv_kernel<<<(256 * 800 + 255) / 256, 256, 0, stream>>>(conv1_w, dflag, Bt1, 200, 4, 800, 200, 256 * 800);
  btconv_kernel<<<(256 * 416 + 255) / 256, 256, 0, stream>>>(conv2_w, dflag, Bt2, 200, 2, 416, 200, 256 * 416);
  btconv_kernel<<<(384 * 1216 + 255) / 256, 256, 0, stream>>>(conv1c_w, dflag, Bt1c, 300, 4, 1216, 300, 384 * 1216);
  btconv_kernel<<<(384 * 608 + 255) / 256, 256, 0, stream>>>(conv2c_w, dflag, Bt2c, 300, 2, 608, 300, 384 * 608);
  bias_kernel<<<1, 256, 0, stream>>>(conv1_b, dflag, b1f, 200);
  bias_kernel<<<1, 256, 0, stream>>>(conv2_b, dflag, b2f, 200);
  bias_kernel<<<2, 256, 0, stream>>>(conv1c_b, dflag, b1cf, 300);
  bias_kernel<<<2, 256, 0, stream>>>(conv2c_b, dflag, b2cf, 300);

  hist_kernel<<<(NEDGES + 255) / 256, 256, 0, stream>>>(dstv, cnt);
  bsum_kernel<<<NSCANB, 256, 0, stream>>>(cnt, bsum);
  bscan_kernel<<<1, 256, 0, stream>>>(bsum, boff);
  rowptr_kernel<<<NSCANB, 256, 0, stream>>>(cnt, boff, row_ptr, cursor);
  fill_kernel<<<(NEDGES + 255) / 256, 256, 0, stream>>>(srcv, dstv, cursor, csr_src);

  for (int l = 0; l < NSTEPS; l++) {
    gather_kernel<<<(NNODES + 3) / 4, 256, 0, stream>>>(row_ptr, csr_src, h, Ag);
    gemm_gru<<<xcd_grid(NNODES, 7), 256, 0, stream>>>(Ag, 400, BtG + (size_t)l * 896 * 416,
                                                      h, NNODES, 416, gb);
  }
  ccat_kernel<<<(NNODES * FCAT + 255) / 256, 256, 0, stream>>>(h, x, dflag, cc);

  // branch y
  gemm128<false><<<xcd_grid(49997, 2), 256, 0, stream>>>(h, 200, Bt1, C1, 200, 49997, 200, 800, b1f);
  stats_kernel<<<(49997 + 63) / 64, 256, 0, stream>>>(C1, 49997, 200, s1, ss1);
  bnpool_kernel<<<(24997 * 200 + 255) / 256, 256, 0, stream>>>(C1, 49997, 200, 4, 2, 24997,
                                                               s1, ss1, bn_g, bn_b, dflag, pooled1);
  gemm128<false><<<xcd_grid(24996, 2), 256, 0, stream>>>(pooled1, 200, Bt2, C2, 200, 24996, 200, 416, b2f);
  stats_kernel<<<(24996 + 63) / 64, 256, 0, stream>>>(C2, 24996, 200, s2, ss2);
  bnpool_kernel<<<(12497 * 200 + 255) / 256, 256, 0, stream>>>(C2, 24996, 200, 3, 2, 12497,
                                                               s2, ss2, bn_g, bn_b, dflag, Y2);
  // branch z
  gemm128<false><<<xcd_grid(49997, 3), 256, 0, stream>>>(cc, 300, Bt1c, C1c, 300, 49997, 300, 1216, b1cf);
  stats_kernel<<<(49997 + 63) / 64, 256, 0, stream>>>(C1c, 49997, 300, sc1, ssc1);
  bnpool_kernel<<<(24997 * 300 + 255) / 256, 256, 0, stream>>>(C1c, 49997, 300, 4, 2, 24997,
                                                               sc1, ssc1, bnc_g, bnc_b, dflag, pooledc);
  gemm128<false><<<xcd_grid(24996, 3), 256, 0, stream>>>(pooledc, 300, Bt2c, C2c, 300, 24996, 300, 608, b2cf);
  stats_kernel<<<(24996 + 63) / 64, 256, 0, stream>>>(C2c, 24996, 300, sc2, ssc2);
  bnpool_kernel<<<(12497 * 300 + 255) / 256, 256, 0, stream>>>(C2c, 24996, 300, 3, 2, 12497,
                                                               sc2, ssc2, bnc_g, bnc_b, dflag, Z2);

  final_kernel<<<3125, 256, 0, stream>>>(Y2, Z2, mlpy_w, mlpy_b, mlpz_w, mlpz_b, dflag, pacc);
  finalize_kernel<<<1, 256, 0, stream>>>(pacc, 3125, dflag, d_out);
}

// Round 12
// 1796.680 us; speedup vs baseline: 1.4361x; 1.0818x over previous
//
#include <hip/hip_runtime.h>
#include <cstdint>
#include <cstddef>

#define NNODES 50000
#define NEDGES 800000
#define FIN    100
#define FOUT   200
#define FCAT   300
#define NSTEPS 8
#define NSCANB 196

typedef unsigned short ushort_t;
typedef __bf16 bf16x8 __attribute__((ext_vector_type(8)));
typedef float  floatx4 __attribute__((ext_vector_type(4)));

__device__ __forceinline__ float bf2f(ushort_t u) {
  union { unsigned u; float f; } c; c.u = ((unsigned)u) << 16; return c.f;
}
__device__ __forceinline__ ushort_t f2bf(float f) {
  union { float f; unsigned u; } c; c.f = f;
  unsigned r = c.u + 0x7FFFu + ((c.u >> 16) & 1u);
  return (ushort_t)(r >> 16);
}
__device__ __forceinline__ float inval(const void* p, size_t i, int f32) {
  return f32 ? ((const float*)p)[i] : bf2f(((const ushort_t*)p)[i]);
}

// async global->LDS 16B
__device__ __forceinline__ void gl2lds16(const ushort_t* g, ushort_t* l) {
  typedef const __attribute__((address_space(1))) unsigned int gu32;
  typedef __attribute__((address_space(3))) unsigned int lu32;
  __builtin_amdgcn_global_load_lds((gu32*)(uintptr_t)g, (lu32*)(uintptr_t)l, 16, 0, 0);
}

#define LOG2E 1.44269504f
// fast sigmoid/tanh on native v_exp_f32 (exp2) + v_rcp_f32; saturation-exact.
__device__ __forceinline__ float fsigmoid(float x) {
  return __builtin_amdgcn_rcpf(1.f + __builtin_amdgcn_exp2f(-x * LOG2E));
}
__device__ __forceinline__ float ftanh(float a) {
  return 1.f - 2.f * __builtin_amdgcn_rcpf(1.f + __builtin_amdgcn_exp2f(2.f * LOG2E * a));
}

// ---------------------------------------------------------------- dtype probe
__global__ void probe_kernel(const void* xraw, int* flag) {
  const ushort_t* u = (const ushort_t*)xraw;
  int t = threadIdx.x;
  int bad = 0;
  for (int i = t; i < 2048; i += 64) {
    int e = (u[2 * i] >> 7) & 0xFF;
    if (e >= 0x88) bad++;
  }
  for (int off = 32; off; off >>= 1) bad += __shfl_down(bad, off);
  if (t == 0) *flag = (bad > 128) ? 1 : 0;
}

// ---------------------------------------------------------------- utility
__global__ void zero_kernel(int* p, int n) {
  int i = blockIdx.x * 256 + threadIdx.x;
  if (i < n) p[i] = 0;
}

__global__ void sentinel_kernel(ushort_t* out) {
  if (threadIdx.x == 0 && blockIdx.x == 0) {
    out[0] = f2bf(0.123f);
    out[1] = f2bf(0.877f);
  }
}

__global__ void hinit_kernel(const void* __restrict__ x, const int* __restrict__ dflag,
                             ushort_t* __restrict__ h) {
  const int f32 = *dflag;
  int i = blockIdx.x * 256 + threadIdx.x;
  if (i >= NNODES * FOUT) return;
  int n = i / FOUT, c = i % FOUT;
  h[i] = (c < FIN) ? f2bf(inval(x, (size_t)n * FIN + c, f32)) : (ushort_t)0;
}

__global__ void ccat_kernel(const ushort_t* __restrict__ h, const void* __restrict__ x,
                            const int* __restrict__ dflag, ushort_t* __restrict__ cc) {
  const int f32 = *dflag;
  int i = blockIdx.x * 256 + threadIdx.x;
  if (i >= NNODES * FCAT) return;
  int n = i / FCAT, c = i % FCAT;
  cc[i] = (c < FOUT) ? h[n * FOUT + c] : f2bf(inval(x, (size_t)n * FIN + (c - FOUT), f32));
}

// ---------------------------------------------------------------- CSR build
__global__ void hist_kernel(const int* __restrict__ dst, int* __restrict__ cnt) {
  int e = blockIdx.x * 256 + threadIdx.x;
  if (e < NEDGES) atomicAdd(&cnt[dst[e]], 1);
}

__global__ void bsum_kernel(const int* __restrict__ cnt, int* __restrict__ bsum) {
  __shared__ int red[4];
  int i = blockIdx.x * 256 + threadIdx.x;
  int v = (i < NNODES) ? cnt[i] : 0;
  for (int off = 32; off; off >>= 1) v += __shfl_down(v, off);
  int w = threadIdx.x >> 6;
  if ((threadIdx.x & 63) == 0) red[w] = v;
  __syncthreads();
  if (threadIdx.x == 0) bsum[blockIdx.x] = red[0] + red[1] + red[2] + red[3];
}

__global__ void bscan_kernel(const int* __restrict__ bsum, int* __restrict__ boff) {
  __shared__ int s[256];
  int t = threadIdx.x;
  int v = (t < NSCANB) ? bsum[t] : 0;
  s[t] = v;
  __syncthreads();
  for (int off = 1; off < 256; off <<= 1) {
    int u = (t >= off) ? s[t - off] : 0;
    __syncthreads();
    s[t] += u;
    __syncthreads();
  }
  if (t < NSCANB) boff[t] = s[t] - v;   // exclusive
}

__global__ void rowptr_kernel(const int* __restrict__ cnt, const int* __restrict__ boff,
                              int* __restrict__ row_ptr, int* __restrict__ cursor) {
  __shared__ int s[256];
  int t = threadIdx.x;
  int i = blockIdx.x * 256 + t;
  int v = (i < NNODES) ? cnt[i] : 0;
  s[t] = v;
  __syncthreads();
  for (int off = 1; off < 256; off <<= 1) {
    int u = (t >= off) ? s[t - off] : 0;
    __syncthreads();
    s[t] += u;
    __syncthreads();
  }
  if (i < NNODES) {
    int e = boff[blockIdx.x] + s[t] - v;
    row_ptr[i] = e; cursor[i] = e;
    if (i == NNODES - 1) row_ptr[NNODES] = boff[blockIdx.x] + s[t];
  }
}

__global__ void fill_kernel(const int* __restrict__ srcv, const int* __restrict__ dstv,
                            int* __restrict__ cursor, int* __restrict__ csr_src) {
  int e = blockIdx.x * 256 + threadIdx.x;
  if (e >= NEDGES) return;
  int p = atomicAdd(&cursor[dstv[e]], 1);
  csr_src[p] = srcv[e];
}

// agg[n] = sum over in-edges of h[src]; writes A = [agg | h] row (400 wide, bf16)
__global__ __launch_bounds__(256) void gather_kernel(
    const int* __restrict__ row_ptr, const int* __restrict__ csr_src,
    const ushort_t* __restrict__ h, ushort_t* __restrict__ Ag) {
  int g = threadIdx.x >> 6;
  int lane = threadIdx.x & 63;
  int n = blockIdx.x * 4 + g;
  if (n >= NNODES) return;
  if (lane >= 50) return;
  int s0 = row_ptr[n], s1 = row_ptr[n + 1];
  float a0 = 0.f, a1 = 0.f, a2 = 0.f, a3 = 0.f;
  int i = s0;
  for (; i + 3 < s1; i += 4) {
    int sa = csr_src[i], sb = csr_src[i + 1], sc = csr_src[i + 2], sd = csr_src[i + 3];
    ushort4 va = *(const ushort4*)&h[(size_t)sa * FOUT + lane * 4];
    ushort4 vb = *(const ushort4*)&h[(size_t)sb * FOUT + lane * 4];
    ushort4 vc = *(const ushort4*)&h[(size_t)sc * FOUT + lane * 4];
    ushort4 vd = *(const ushort4*)&h[(size_t)sd * FOUT + lane * 4];
    a0 += (bf2f(va.x) + bf2f(vb.x)) + (bf2f(vc.x) + bf2f(vd.x));
    a1 += (bf2f(va.y) + bf2f(vb.y)) + (bf2f(vc.y) + bf2f(vd.y));
    a2 += (bf2f(va.z) + bf2f(vb.z)) + (bf2f(vc.z) + bf2f(vd.z));
    a3 += (bf2f(va.w) + bf2f(vb.w)) + (bf2f(vc.w) + bf2f(vd.w));
  }
  for (; i < s1; i++) {
    int sa = csr_src[i];
    ushort4 va = *(const ushort4*)&h[(size_t)sa * FOUT + lane * 4];
    a0 += bf2f(va.x); a1 += bf2f(va.y); a2 += bf2f(va.z); a3 += bf2f(va.w);
  }
  ushort4 o;
  o.x = f2bf(a0); o.y = f2bf(a1); o.z = f2bf(a2); o.w = f2bf(a3);
  *(ushort4*)&Ag[(size_t)n * 400 + lane * 4] = o;
  *(ushort4*)&Ag[(size_t)n * 400 + FOUT + lane * 4] =
      *(const ushort4*)&h[(size_t)n * FOUT + lane * 4];
}

// ---------------------------------------------------------------- padded bf16 copies
__global__ void pada_kernel(const void* __restrict__ src, const int* __restrict__ dflag,
                            ushort_t* __restrict__ dst, int K, int Kp, int rowsValid,
                            int total) {
  const int f32 = *dflag;
  int i = blockIdx.x * 256 + threadIdx.x;
  if (i >= total) return;
  int r = i / Kp, k = i % Kp;
  float v = (r < rowsValid && k < K) ? inval(src, (size_t)r * K + k, f32) : 0.f;
  dst[i] = f2bf(v);
}

// Bt_gru packed: [8][896 rows][416 k], row nn = 4*c + gate (r,z,ic,hc), c<200 valid.
__global__ void btgruq_kernel(const float* __restrict__ Wp, const void* __restrict__ whh,
                              const int* __restrict__ dflag, ushort_t* __restrict__ Bt) {
  const int f32 = *dflag;
  int i = blockIdx.x * 256 + threadIdx.x;
  if (i >= NSTEPS * 896 * 416) return;
  int l = i / (896 * 416);
  int rem = i % (896 * 416);
  int nn = rem / 416;
  int k = rem % 416;
  int c = nn >> 2, g = nn & 3;
  float v = 0.f;
  if (c < 200) {
    if (k < 200) {
      const float* wrow = Wp + ((size_t)l * 200 + k) * 600;
      if (g == 0) v = wrow[c];
      else if (g == 1) v = wrow[200 + c];
      else if (g == 2) v = wrow[400 + c];
    } else if (k < 400) {
      int kh = k - 200;
      if (g == 0) v = inval(whh, (size_t)c * 200 + kh, f32);
      else if (g == 1) v = inval(whh, (size_t)(200 + c) * 200 + kh, f32);
      else if (g == 3) v = inval(whh, (size_t)(400 + c) * 200 + kh, f32);
    }
  }
  Bt[((size_t)nn + 896 * (size_t)l) * 416 + k] = f2bf(v);
}

__global__ void btconv_kernel(const void* __restrict__ w, const int* __restrict__ dflag,
                              ushort_t* __restrict__ Bt, int C, int KT, int Kp,
                              int O, int total) {
  const int f32 = *dflag;
  int i = blockIdx.x * 256 + threadIdx.x;
  if (i >= total) return;
  int o = i / Kp, k = i % Kp;
  float v = 0.f;
  int K = C * KT;
  if (k < K && o < O) {
    int ktap = k / C; int ci = k % C;
    v = inval(w, ((size_t)o * C + ci) * KT + ktap, f32);
  }
  Bt[i] = f2bf(v);
}

// gru bias precombine
__global__ void gbias_kernel(const void* __restrict__ bih, const void* __restrict__ bhh,
                             const int* __restrict__ dflag, float* __restrict__ gb) {
  const int f32 = *dflag;
  int c = blockIdx.x * 256 + threadIdx.x;
  if (c >= 200) return;
  gb[c]       = inval(bih, c, f32)       + inval(bhh, c, f32);
  gb[200 + c] = inval(bih, 200 + c, f32) + inval(bhh, 200 + c, f32);
  gb[400 + c] = inval(bih, 400 + c, f32);
  gb[600 + c] = inval(bhh, 400 + c, f32);
}

// XCD-aware tile decode: all n-tiles of an m-tile land on one XCD (id%8).
__device__ __forceinline__ bool xcd_tile(int id, int MT, int NT, int& mt, int& nt) {
  int xcd = id & 7;
  int slot = id >> 3;
  mt = xcd * ((MT + 7) >> 3) + slot / NT;
  nt = slot % NT;
  return mt < MT;
}

// ---------------------------------------------------------------- GEMM (MFMA, 128x128)
template <bool OUT_BF16>
__global__ __launch_bounds__(256) void gemm128(
    const ushort_t* __restrict__ A, int lda, const ushort_t* __restrict__ Bt,
    void* __restrict__ Cv, int ldc, int M, int N, int Kp,
    const float* __restrict__ bias) {
  __shared__ alignas(16) ushort_t As[128 * 32];
  __shared__ alignas(16) ushort_t Bs[128 * 32];
  const int MT = (M + 127) >> 7;
  const int NT = (N + 127) >> 7;
  int mt, nt;
  if (!xcd_tile(blockIdx.x, MT, NT, mt, nt)) return;
  const int m0 = mt * 128;
  const int n0 = nt * 128;
  const int tid = threadIdx.x;
  const int lane = tid & 63;
  const int wv = tid >> 6;
  const int wm = wv & 1;
  const int wn = wv >> 1;
  const int quad = lane >> 4;
  const int l15 = lane & 15;

  const int s0i = wv * 128 + lane;
  const int s1i = s0i + 64;
  const int r0 = s0i >> 2, c0 = (s0i & 3) ^ ((r0 >> 1) & 3);
  const int r1 = s1i >> 2, c1 = (s1i & 3) ^ ((r1 >> 1) & 3);
  int ar0 = m0 + r0; if (ar0 >= M) ar0 = M - 1;
  int ar1 = m0 + r1; if (ar1 >= M) ar1 = M - 1;
  const ushort_t* gA0 = A + (size_t)ar0 * lda + c0 * 8;
  const ushort_t* gA1 = A + (size_t)ar1 * lda + c1 * 8;
  const ushort_t* gB0 = Bt + (size_t)(n0 + r0) * Kp + c0 * 8;
  const ushort_t* gB1 = Bt + (size_t)(n0 + r1) * Kp + c1 * 8;
  ushort_t* lA0 = &As[(size_t)(wv * 128) * 8];
  ushort_t* lA1 = &As[(size_t)(wv * 128 + 64) * 8];
  ushort_t* lB0 = &Bs[(size_t)(wv * 128) * 8];
  ushort_t* lB1 = &Bs[(size_t)(wv * 128 + 64) * 8];

  floatx4 acc[4][4];
  #pragma unroll
  for (int a = 0; a < 4; a++)
    #pragma unroll
    for (int b = 0; b < 4; b++)
      acc[a][b] = (floatx4){0.f, 0.f, 0.f, 0.f};

  for (int k0 = 0; k0 < Kp; k0 += 32) {
    gl2lds16(gA0 + k0, lA0);
    gl2lds16(gA1 + k0, lA1);
    gl2lds16(gB0 + k0, lB0);
    gl2lds16(gB1 + k0, lB1);
    __syncthreads();
    bf16x8 af[4], bfr[4];
    #pragma unroll
    for (int t = 0; t < 4; t++) {
      int ra = wm * 64 + t * 16 + l15;
      int rb = wn * 64 + t * 16 + l15;
      af[t]  = *(const bf16x8*)&As[(ra * 4 + (quad ^ ((ra >> 1) & 3))) * 8];
      bfr[t] = *(const bf16x8*)&Bs[(rb * 4 + (quad ^ ((rb >> 1) & 3))) * 8];
    }
    #pragma unroll
    for (int tm = 0; tm < 4; tm++)
      #pragma unroll
      for (int tn = 0; tn < 4; tn++)
        acc[tm][tn] = __builtin_amdgcn_mfma_f32_16x16x32_bf16(af[tm], bfr[tn], acc[tm][tn], 0, 0, 0);
    __syncthreads();
  }

  #pragma unroll
  for (int tm = 0; tm < 4; tm++) {
    int row = m0 + wm * 64 + tm * 16 + quad * 4;
    #pragma unroll
    for (int tn = 0; tn < 4; tn++) {
      int col = n0 + wn * 64 + tn * 16 + l15;
      if (col < N) {
        float bb = bias ? bias[col] : 0.f;
        #pragma unroll
        for (int r = 0; r < 4; r++) {
          if (row + r < M) {
            float v = acc[tm][tn][r] + bb;
            if (OUT_BF16) ((ushort_t*)Cv)[(size_t)(row + r) * ldc + col] = f2bf(v);
            else          ((float*)Cv)[(size_t)(row + r) * ldc + col] = v;
          }
        }
      }
    }
  }
}

// ---------------------------------------------------------------- fused GRU GEMM
// Gate-packed B (col = 4*c+gate), in-register butterfly epilogue with native
// exp2-based sigmoid/tanh, XCD-swizzled 1D grid (NT=7).
__global__ __launch_bounds__(256) void gemm_gru(
    const ushort_t* __restrict__ A, int lda, const ushort_t* __restrict__ Bt,
    ushort_t* __restrict__ h, int M, int Kp, const float* __restrict__ gb) {
  __shared__ alignas(16) ushort_t As[128 * 32];
  __shared__ alignas(16) ushort_t Bs[128 * 32];
  const int MT = (M + 127) >> 7;
  int mt, nt;
  if (!xcd_tile(blockIdx.x, MT, 7, mt, nt)) return;
  const int m0 = mt * 128;
  const int n0 = nt * 128;
  const int tid = threadIdx.x;
  const int lane = tid & 63;
  const int wv = tid >> 6;
  const int wm = wv & 1;
  const int wn = wv >> 1;
  const int quad = lane >> 4;
  const int l15 = lane & 15;

  const int s0i = wv * 128 + lane;
  const int s1i = s0i + 64;
  const int r0 = s0i >> 2, c0 = (s0i & 3) ^ ((r0 >> 1) & 3);
  const int r1 = s1i >> 2, c1 = (s1i & 3) ^ ((r1 >> 1) & 3);
  int ar0 = m0 + r0; if (ar0 >= M) ar0 = M - 1;
  int ar1 = m0 + r1; if (ar1 >= M) ar1 = M - 1;
  const ushort_t* gA0 = A + (size_t)ar0 * lda + c0 * 8;
  const ushort_t* gA1 = A + (size_t)ar1 * lda + c1 * 8;
  const ushort_t* gB0 = Bt + (size_t)(n0 + r0) * Kp + c0 * 8;
  const ushort_t* gB1 = Bt + (size_t)(n0 + r1) * Kp + c1 * 8;
  ushort_t* lA0 = &As[(size_t)(wv * 128) * 8];
  ushort_t* lA1 = &As[(size_t)(wv * 128 + 64) * 8];
  ushort_t* lB0 = &Bs[(size_t)(wv * 128) * 8];
  ushort_t* lB1 = &Bs[(size_t)(wv * 128 + 64) * 8];

  floatx4 acc[4][4];
  #pragma unroll
  for (int a = 0; a < 4; a++)
    #pragma unroll
    for (int b = 0; b < 4; b++)
      acc[a][b] = (floatx4){0.f, 0.f, 0.f, 0.f};

  for (int k0 = 0; k0 < Kp; k0 += 32) {
    gl2lds16(gA0 + k0, lA0);
    gl2lds16(gA1 + k0, lA1);
    gl2lds16(gB0 + k0, lB0);
    gl2lds16(gB1 + k0, lB1);
    __syncthreads();
    bf16x8 af[4], bfr[4];
    #pragma unroll
    for (int t = 0; t < 4; t++) {
      int ra = wm * 64 + t * 16 + l15;
      int rb = wn * 64 + t * 16 + l15;
      af[t]  = *(const bf16x8*)&As[(ra * 4 + (quad ^ ((ra >> 1) & 3))) * 8];
      bfr[t] = *(const bf16x8*)&Bs[(rb * 4 + (quad ^ ((rb >> 1) & 3))) * 8];
    }
    #pragma unroll
    for (int tm = 0; tm < 4; tm++)
      #pragma unroll
      for (int tn = 0; tn < 4; tn++)
        acc[tm][tn] = __builtin_amdgcn_mfma_f32_16x16x32_bf16(af[tm], bfr[tn], acc[tm][tn], 0, 0, 0);
    __syncthreads();
  }

  // in-register epilogue (tn-outer: bias loads hoisted per channel)
  const int sb0 = l15 & 1;
  const int sb1 = (l15 >> 1) & 1;
  const int jch = l15 >> 2;
  const int chb = nt * 32 + wn * 16;
  #pragma unroll
  for (int tn = 0; tn < 4; tn++) {
    int chan = chb + tn * 4 + jch;
    bool chok = (chan < 200);
    float rb = 0.f, zb = 0.f, ib = 0.f, hb = 0.f;
    if (chok) {
      rb = gb[chan]; zb = gb[200 + chan]; ib = gb[400 + chan]; hb = gb[600 + chan];
    }
    #pragma unroll
    for (int tm = 0; tm < 4; tm++) {
      float v0 = acc[tm][tn][0], v1 = acc[tm][tn][1];
      float v2 = acc[tm][tn][2], v3 = acc[tm][tn][3];
      float t;
      t = __shfl_xor(sb0 ? v0 : v1, 1); if (sb0) v0 = t; else v1 = t;
      t = __shfl_xor(sb0 ? v2 : v3, 1); if (sb0) v2 = t; else v3 = t;
      t = __shfl_xor(sb1 ? v0 : v2, 2); if (sb1) v0 = t; else v2 = t;
      t = __shfl_xor(sb1 ? v1 : v3, 2); if (sb1) v1 = t; else v3 = t;
      int row = m0 + wm * 64 + tm * 16 + quad * 4 + (l15 & 3);
      if (row < M && chok) {
        float r_ = fsigmoid(v0 + rb);
        float z_ = fsigmoid(v1 + zb);
        float n_ = ftanh(v2 + ib + r_ * (v3 + hb));
        float ho = bf2f(h[(size_t)row * 200 + chan]);
        h[(size_t)row * 200 + chan] = f2bf((1.f - z_) * n_ + z_ * ho);
      }
    }
  }
}

__global__ void bias_kernel(const void* __restrict__ b, const int* __restrict__ dflag,
                            float* __restrict__ out, int n) {
  const int f32 = *dflag;
  int i = blockIdx.x * 256 + threadIdx.x;
  if (i < n) out[i] = inval(b, i, f32);
}

// ---------------------------------------------------------------- BN stats + pool
__global__ void stats_kernel(const float* __restrict__ X, int Lrows, int C,
                             float* __restrict__ sums, float* __restrict__ sumsq) {
  int r0 = blockIdx.x * 64;
  int rend = r0 + 64; if (rend > Lrows) rend = Lrows;
  for (int c = threadIdx.x; c < C; c += 256) {
    float s = 0.f, ss = 0.f;
    for (int r = r0; r < rend; r++) {
      float v = X[(size_t)r * C + c];
      s += v; ss += v * v;
    }
    atomicAdd(&sums[c], s);
    atomicAdd(&sumsq[c], ss);
  }
}

__global__ void bnpool_kernel(const float* __restrict__ X, int Lin, int C, int kk, int ss,
                              int Lp, const float* __restrict__ sums,
                              const float* __restrict__ sumsq,
                              const void* __restrict__ g, const void* __restrict__ b,
                              const int* __restrict__ dflag, ushort_t* __restrict__ out) {
  const int f32 = *dflag;
  int i = blockIdx.x * 256 + threadIdx.x;
  if (i >= Lp * C) return;
  int p = i / C, c = i % C;
  float inv = 1.f / (float)Lin;
  float mu = sums[c] * inv;
  float var = sumsq[c] * inv - mu * mu; if (var < 0.f) var = 0.f;
  float scale = inval(g, c, f32) * rsqrtf(var + 1e-5f);
  float shift = inval(b, c, f32) - mu * scale;
  float m = -1e30f;
  int base = p * ss;
  for (int r = 0; r < kk; r++) {
    float v = X[(size_t)(base + r) * C + c] * scale + shift;
    if (v > m) m = v;
  }
  if (m < 0.f) m = 0.f;
  out[(size_t)p * C + c] = f2bf(m);
}

// ---------------------------------------------------------------- head (atomic-free)
__global__ __launch_bounds__(256) void final_kernel(
    const ushort_t* __restrict__ Y2, const ushort_t* __restrict__ Z2,
    const void* __restrict__ wy, const void* __restrict__ by,
    const void* __restrict__ wz, const void* __restrict__ bz,
    const int* __restrict__ dflag, float* __restrict__ pacc) {
  const int f32 = *dflag;
  __shared__ float bl[8];
  int g = threadIdx.x >> 6;
  int lane = threadIdx.x & 63;
  int row = blockIdx.x * 4 + g;
  float y0 = 0.f, y1 = 0.f, z0 = 0.f, z1 = 0.f;
  if (row < 12497) {
    for (int c = lane; c < 200; c += 64) {
      float v = bf2f(Y2[(size_t)row * 200 + c]);
      y0 += v * inval(wy, c, f32);
      y1 += v * inval(wy, 200 + c, f32);
    }
    for (int c = lane; c < 300; c += 64) {
      float v = bf2f(Z2[(size_t)row * 300 + c]);
      z0 += v * inval(wz, c, f32);
      z1 += v * inval(wz, 300 + c, f32);
    }
  }
  for (int off = 32; off > 0; off >>= 1) {
    y0 += __shfl_down(y0, off);
    y1 += __shfl_down(y1, off);
    z0 += __shfl_down(z0, off);
    z1 += __shfl_down(z1, off);
  }
  if (lane == 0) {
    float p0 = 0.f, p1 = 0.f;
    if (row < 12497) {
      p0 = (y0 + inval(by, 0, f32)) * (z0 + inval(bz, 0, f32));
      p1 = (y1 + inval(by, 1, f32)) * (z1 + inval(bz, 1, f32));
    }
    bl[g * 2] = p0; bl[g * 2 + 1] = p1;
  }
  __syncthreads();
  if (threadIdx.x == 0) {
    pacc[(size_t)blockIdx.x * 2]     = bl[0] + bl[2] + bl[4] + bl[6];
    pacc[(size_t)blockIdx.x * 2 + 1] = bl[1] + bl[3] + bl[5] + bl[7];
  }
}

__global__ __launch_bounds__(256) void finalize_kernel(
    const float* __restrict__ pacc, int nblk, const int* __restrict__ dflag,
    void* __restrict__ out) {
  const int f32 = *dflag;
  __shared__ float red[2][4];
  int t = threadIdx.x;
  float s0 = 0.f, s1 = 0.f;
  for (int i = t; i < nblk; i += 256) { s0 += pacc[2 * i]; s1 += pacc[2 * i + 1]; }
  for (int off = 32; off; off >>= 1) { s0 += __shfl_down(s0, off); s1 += __shfl_down(s1, off); }
  int w = t >> 6;
  if ((t & 63) == 0) { red[0][w] = s0; red[1][w] = s1; }
  __syncthreads();
  if (t == 0) {
    float a0 = (red[0][0] + red[0][1] + red[0][2] + red[0][3]) / 12497.f;
    float a1 = (red[1][0] + red[1][1] + red[1][2] + red[1][3]) / 12497.f;
    float mx = fmaxf(a0, a1);
    float e0 = expf(a0 - mx), e1 = expf(a1 - mx);
    float s = e0 + e1;
    if (f32) {
      ((float*)out)[0] = e0 / s;
      ((float*)out)[1] = e1 / s;
    } else {
      ((ushort_t*)out)[0] = f2bf(e0 / s);
      ((ushort_t*)out)[1] = f2bf(e1 / s);
    }
  }
}

// ---------------------------------------------------------------- launch
static inline int xcd_grid(int M, int NT) {
  int MT = (M + 127) >> 7;
  int CH = (MT + 7) >> 3;
  return 8 * CH * NT;
}

extern "C" void kernel_launch(void* const* d_in, const int* in_sizes, int n_in,
                              void* d_out, int out_size, void* d_ws, size_t ws_size,
                              hipStream_t stream) {
  const void* x        = d_in[0];
  const int*  edge     = (const int*)d_in[1];
  const void* ggnn_w   = d_in[2];
  const void* gru_wih  = d_in[3];
  const void* gru_whh  = d_in[4];
  const void* gru_bih  = d_in[5];
  const void* gru_bhh  = d_in[6];
  const void* conv1_w  = d_in[7];
  const void* conv1_b  = d_in[8];
  const void* conv2_w  = d_in[9];
  const void* conv2_b  = d_in[10];
  const void* conv1c_w = d_in[11];
  const void* conv1c_b = d_in[12];
  const void* conv2c_w = d_in[13];
  const void* conv2c_b = d_in[14];
  const void* bn_g     = d_in[15];
  const void* bn_b     = d_in[16];
  const void* bnc_g    = d_in[17];
  const void* bnc_b    = d_in[18];
  const void* mlpy_w   = d_in[19];
  const void* mlpy_b   = d_in[20];
  const void* mlpz_w   = d_in[21];
  const void* mlpz_b   = d_in[22];
  const int* srcv = edge;
  const int* dstv = edge + NEDGES;

  // ---- workspace layout (aliased; total ~177 MB) ----
  char* p = (char*)d_ws;
  auto alloc = [&](size_t bytes) -> char* {
    char* r = p; p += (bytes + 255) & ~(size_t)255; return r;
  };
  ushort_t* h    = (ushort_t*)alloc(((size_t)NNODES * FOUT + 64) * 2);
  ushort_t* Ag   = (ushort_t*)alloc(((size_t)NNODES * 400 + 64) * 2);
  ushort_t* cc   = Ag;  // cc[N,300] built AFTER GRU loop, Ag then dead
  char*     R    = alloc((size_t)98 * 1000 * 1000);
  float*    C1   = (float*)R;
  float*    C2   = (float*)R;
  float*    C1c  = (float*)R;
  float*    C2c  = (float*)R;
  ushort_t* pooled1 = (ushort_t*)(R + 60000000);
  ushort_t* pooledc = (ushort_t*)(R + 70000000);
  ushort_t* Y2      = (ushort_t*)(R + 85000000);
  ushort_t* Z2      = (ushort_t*)(R + 90000000);
  ushort_t* BtG  = (ushort_t*)alloc((size_t)8 * 896 * 416 * 2);
  ushort_t* Bt1  = (ushort_t*)alloc((size_t)256 * 800 * 2);
  ushort_t* Bt2  = (ushort_t*)alloc((size_t)256 * 416 * 2);
  ushort_t* Bt1c = (ushort_t*)alloc((size_t)384 * 1216 * 2);
  ushort_t* Bt2c = (ushort_t*)alloc((size_t)384 * 608 * 2);
  ushort_t* gwp  = (ushort_t*)alloc((size_t)1600 * 224 * 2);
  ushort_t* wihp = (ushort_t*)alloc((size_t)640 * 224 * 2);
  float*    Wp   = (float*)alloc((size_t)1600 * 600 * 4);
  int*   csr_src = (int*)alloc((size_t)NEDGES * 4);
  int*   row_ptr = (int*)alloc((size_t)(NNODES + 1) * 4);
  int*   cursor  = (int*)alloc((size_t)NNODES * 4);
  int*   cnt     = (int*)alloc((size_t)NNODES * 4);
  int*   bsum    = (int*)alloc((size_t)(NSCANB + 4) * 4);
  int*   boff    = (int*)alloc((size_t)(NSCANB + 4) * 4);
  float* pacc    = (float*)alloc((size_t)3125 * 2 * 4);
  float* sb      = (float*)alloc((size_t)4300 * 4);
  float *s1 = sb, *ss1 = sb + 200, *s2 = sb + 400, *ss2 = sb + 600;
  float *sc1 = sb + 800, *ssc1 = sb + 1100, *sc2 = sb + 1400, *ssc2 = sb + 1700;
  int*   dflag = (int*)(sb + 2002);
  float* b1f   = sb + 2010;
  float* b2f   = sb + 2210;
  float* b1cf  = sb + 2410;
  float* b2cf  = sb + 2710;
  float* gb    = sb + 3100;   // 800 fp32 gru bias combos

  size_t required = (size_t)(p - (char*)d_ws);
  if (required > ws_size) {
    sentinel_kernel<<<1, 64, 0, stream>>>((ushort_t*)d_out);
    return;
  }

  probe_kernel<<<1, 64, 0, stream>>>(x, dflag);
  zero_kernel<<<(NNODES + 255) / 256, 256, 0, stream>>>(cnt, NNODES);
  zero_kernel<<<(2000 + 255) / 256, 256, 0, stream>>>((int*)sb, 2000);
  hinit_kernel<<<(NNODES * FOUT + 255) / 256, 256, 0, stream>>>(x, dflag, h);

  // wp = ggnn_w @ wih^T as one MFMA GEMM
  pada_kernel<<<(1600 * 224 + 255) / 256, 256, 0, stream>>>(ggnn_w, dflag, gwp, 200, 224, 1600, 1600 * 224);
  pada_kernel<<<(640 * 224 + 255) / 256, 256, 0, stream>>>(gru_wih, dflag, wihp, 200, 224, 600, 640 * 224);
  gemm128<false><<<xcd_grid(1600, 5), 256, 0, stream>>>(gwp, 224, wihp, Wp, 600, 1600, 600, 224, nullptr);

  btgruq_kernel<<<(NSTEPS * 896 * 416 + 255) / 256, 256, 0, stream>>>(Wp, gru_whh, dflag, BtG);
  gbias_kernel<<<1, 256, 0, stream>>>(gru_bih, gru_bhh, dflag, gb);
  btconv_kernel<<<(256 * 800 + 255) / 256, 256, 0, stream>>>(conv1_w, dflag, Bt1, 200, 4, 800, 200, 256 * 800);
  btconv_kernel<<<(256 * 416 + 255) / 256, 256, 0, stream>>>(conv2_w, dflag, Bt2, 200, 2, 416, 200, 256 * 416);
  btconv_kernel<<<(384 * 1216 + 255) / 256, 256, 0, stream>>>(conv1c_w, dflag, Bt1c, 300, 4, 1216, 300, 384 * 1216);
  btconv_kernel<<<(384 * 608 + 255) / 256, 256, 0, stream>>>(conv2c_w, dflag, Bt2c, 300, 2, 608, 300, 384 * 608);
  bias_kernel<<<1, 256, 0, stream>>>(conv1_b, dflag, b1f, 200);
  bias_kernel<<<1, 256, 0, stream>>>(conv2_b, dflag, b2f, 200);
  bias_kernel<<<2, 256, 0, stream>>>(conv1c_b, dflag, b1cf, 300);
  bias_kernel<<<2, 256, 0, stream>>>(conv2c_b, dflag, b2cf, 300);

  hist_kernel<<<(NEDGES + 255) / 256, 256, 0, stream>>>(dstv, cnt);
  bsum_kernel<<<NSCANB, 256, 0, stream>>>(cnt, bsum);
  bscan_kernel<<<1, 256, 0, stream>>>(bsum, boff);
  rowptr_kernel<<<NSCANB, 256, 0, stream>>>(cnt, boff, row_ptr, cursor);
  fill_kernel<<<(NEDGES + 255) / 256, 256, 0, stream>>>(srcv, dstv, cursor, csr_src);

  for (int l = 0; l < NSTEPS; l++) {
    gather_kernel<<<(NNODES + 3) / 4, 256, 0, stream>>>(row_ptr, csr_src, h, Ag);
    gemm_gru<<<xcd_grid(NNODES, 7), 256, 0, stream>>>(Ag, 400, BtG + (size_t)l * 896 * 416,
                                                      h, NNODES, 416, gb);
  }
  ccat_kernel<<<(NNODES * FCAT + 255) / 256, 256, 0, stream>>>(h, x, dflag, cc);

  // branch y
  gemm128<false><<<xcd_grid(49997, 2), 256, 0, stream>>>(h, 200, Bt1, C1, 200, 49997, 200, 800, b1f);
  stats_kernel<<<(49997 + 63) / 64, 256, 0, stream>>>(C1, 49997, 200, s1, ss1);
  bnpool_kernel<<<(24997 * 200 + 255) / 256, 256, 0, stream>>>(C1, 49997, 200, 4, 2, 24997,
                                                               s1, ss1, bn_g, bn_b, dflag, pooled1);
  gemm128<false><<<xcd_grid(24996, 2), 256, 0, stream>>>(pooled1, 200, Bt2, C2, 200, 24996, 200, 416, b2f);
  stats_kernel<<<(24996 + 63) / 64, 256, 0, stream>>>(C2, 24996, 200, s2, ss2);
  bnpool_kernel<<<(12497 * 200 + 255) / 256, 256, 0, stream>>>(C2, 24996, 200, 3, 2, 12497,
                                                               s2, ss2, bn_g, bn_b, dflag, Y2);
  // branch z
  gemm128<false><<<xcd_grid(49997, 3), 256, 0, stream>>>(cc, 300, Bt1c, C1c, 300, 49997, 300, 1216, b1cf);
  stats_kernel<<<(49997 + 63) / 64, 256, 0, stream>>>(C1c, 49997, 300, sc1, ssc1);
  bnpool_kernel<<<(24997 * 300 + 255) / 256, 256, 0, stream>>>(C1c, 49997, 300, 4, 2, 24997,
                                                               sc1, ssc1, bnc_g, bnc_b, dflag, pooledc);
  gemm128<false><<<xcd_grid(24996, 3), 256, 0, stream>>>(pooledc, 300, Bt2c, C2c, 300, 24996, 300, 608, b2cf);
  stats_kernel<<<(24996 + 63) / 64, 256, 0, stream>>>(C2c, 24996, 300, sc2, ssc2);
  bnpool_kernel<<<(12497 * 300 + 255) / 256, 256, 0, stream>>>(C2c, 24996, 300, 3, 2, 12497,
                                                               sc2, ssc2, bnc_g, bnc_b, dflag, Z2);

  final_kernel<<<3125, 256, 0, stream>>>(Y2, Z2, mlpy_w, mlpy_b, mlpz_w, mlpz_b, dflag, pacc);
  finalize_kernel<<<1, 256, 0, stream>>>(pacc, 3125, dflag, d_out);
}